// Round 2
// baseline (10643.339 us; speedup 1.0000x reference)
//
#include <hip/hip_runtime.h>
#include <math.h>

#define T_ 8
#define N_ 50000
#define F0_ 128
#define H0_ 128
#define H1_ 64
#define NNZ_ 800000
#define E_ 1000000
#define K_ 128
#define CAP_ 3072

// ---------- helpers ----------
__device__ inline unsigned ford(float f) {
    unsigned b = __float_as_uint(f);
    return (b & 0x80000000u) ? ~b : (b | 0x80000000u);
}
__device__ inline float funord(unsigned u) {
    unsigned b = (u & 0x80000000u) ? (u & 0x7fffffffu) : ~u;
    return __uint_as_float(b);
}

// ---------- p_hat = p / ||p|| ----------
__global__ void k_phat(const float* p, float* p_hat) {
    __shared__ float s[128];
    int i = threadIdx.x;
    float v = p[i];
    s[i] = v * v;
    __syncthreads();
    for (int off = 64; off > 0; off >>= 1) {
        if (i < off) s[i] += s[i + off];
        __syncthreads();
    }
    p_hat[i] = v / sqrtf(s[0]);
}

// ---------- y[t][n] = dot(X[t][n], p_hat), wave per row ----------
__global__ void k_y(const float* __restrict__ X, const float* __restrict__ p_hat,
                    float* __restrict__ y) {
    int gid = blockIdx.x * 256 + threadIdx.x;
    int wave = gid >> 6, lane = gid & 63;
    if (wave >= T_ * N_) return;
    const float2* xr = (const float2*)(X + (size_t)wave * F0_);
    float2 a = xr[lane];
    float2 ph = ((const float2*)p_hat)[lane];
    float acc = a.x * ph.x + a.y * ph.y;
#pragma unroll
    for (int off = 32; off > 0; off >>= 1) acc += __shfl_down(acc, off);
    if (lane == 0) y[wave] = acc;
}

// ---------- exact top-128 per t: 2-level radix select + exact rank ----------
__global__ __launch_bounds__(1024) void k_topk(const float* __restrict__ y,
                                               float* __restrict__ topv,
                                               int* __restrict__ topidx) {
    int t = blockIdx.x;
    const float* yt = y + (size_t)t * N_;
    __shared__ int hist[256];
    __shared__ int sb1, sAbove, sP, scand;
    __shared__ unsigned cu[CAP_];
    __shared__ int cidx[CAP_];
    int tid = threadIdx.x;

    if (tid < 256) hist[tid] = 0;
    __syncthreads();
    for (int i = tid; i < N_; i += 1024) {
        unsigned u = ford(yt[i]);
        atomicAdd(&hist[u >> 24], 1);
    }
    __syncthreads();
    if (tid == 0) {
        int acc = 0, b = 255;
        for (; b >= 0; b--) { acc += hist[b]; if (acc >= K_) break; }
        sb1 = b;
        sAbove = acc - hist[b];
    }
    __syncthreads();
    int b1 = sb1;
    if (tid < 256) hist[tid] = 0;
    __syncthreads();
    for (int i = tid; i < N_; i += 1024) {
        unsigned u = ford(yt[i]);
        if ((int)(u >> 24) == b1) atomicAdd(&hist[(u >> 16) & 255], 1);
    }
    __syncthreads();
    if (tid == 0) {
        int acc = sAbove, b = 255;
        for (; b >= 0; b--) { acc += hist[b]; if (acc >= K_) break; }
        sP = (b1 << 8) | b;
        scand = 0;
    }
    __syncthreads();
    unsigned P = (unsigned)sP;
    for (int i = tid; i < N_; i += 1024) {
        unsigned u = ford(yt[i]);
        if ((u >> 16) >= P) {
            int pos = atomicAdd(&scand, 1);
            if (pos < CAP_) { cu[pos] = u; cidx[pos] = i; }
        }
    }
    __syncthreads();
    int C = min(scand, CAP_);
    for (int c = tid; c < C; c += 1024) {
        unsigned uc = cu[c];
        int ic = cidx[c];
        int rank = 0;
        for (int o = 0; o < C; o++) {
            unsigned uo = cu[o];
            rank += (uo > uc) || (uo == uc && cidx[o] < ic);
        }
        if (rank < K_) {
            topv[t * K_ + rank] = funord(uc);
            topidx[t * K_ + rank] = ic;
        }
    }
}

// ---------- Z[t][f][j] = X[t][idx[j]][f] * topv[j] ----------
__global__ void k_z(const float* __restrict__ X, const float* __restrict__ topv,
                    const int* __restrict__ topidx, float* __restrict__ Z) {
    int gid = blockIdx.x * 256 + threadIdx.x;  // t*16384 + f*128 + j
    if (gid >= T_ * F0_ * K_) return;
    int j = gid & 127;
    int f = (gid >> 7) & 127;
    int t = gid >> 14;
    int idx = topidx[t * K_ + j];
    float v = topv[t * K_ + j];
    Z[gid] = X[((size_t)(t * N_ + idx)) * F0_ + f] * v;
}

// ---------- A_g[t] = W_g @ Z_t + B_g  (g in {Z,R,H}, all t parallel) ----------
__global__ void k_az(const float* __restrict__ WZ, const float* __restrict__ WR,
                     const float* __restrict__ WH, const float* __restrict__ BZ,
                     const float* __restrict__ BR, const float* __restrict__ BH,
                     const float* __restrict__ Z, float* __restrict__ AZ,
                     float* __restrict__ AR, float* __restrict__ AHo) {
    int gid = blockIdx.x * 256 + threadIdx.x;  // g*131072 + t*16384 + i*128 + j
    int j = gid & 127;
    int i = (gid >> 7) & 127;
    int t = (gid >> 14) & 7;
    int g = gid >> 17;
    const float* W = (g == 0) ? WZ : (g == 1) ? WR : WH;
    const float* B = (g == 0) ? BZ : (g == 1) ? BR : BH;
    float* Ao = (g == 0) ? AZ : (g == 1) ? AR : AHo;
    const float* Zt = Z + (size_t)t * 16384;
    float acc = B[i * 128 + j];
    for (int k = 0; k < 128; k++) acc += W[i * 128 + k] * Zt[k * 128 + j];
    Ao[(size_t)(t * 128 + i) * 128 + j] = acc;
}

// ---------- CSR build ----------
__global__ void k_hist(const int* __restrict__ A_rows, int* __restrict__ cnt) {
    int gid = blockIdx.x * 256 + threadIdx.x;
    if (gid >= T_ * NNZ_) return;
    int t = gid / NNZ_;
    atomicAdd(&cnt[t * N_ + A_rows[gid]], 1);
}

__global__ __launch_bounds__(1024) void k_scan(const int* __restrict__ cnt,
                                               int* __restrict__ row_ptr) {
    int t = blockIdx.x;
    __shared__ int buf[1024];
    __shared__ int base_s;
    int tid = threadIdx.x;
    if (tid == 0) base_s = 0;
    __syncthreads();
    const int* c = cnt + (size_t)t * N_;
    int* rp = row_ptr + (size_t)t * (N_ + 1);
    for (int start = 0; start < N_; start += 1024) {
        int i = start + tid;
        int v = (i < N_) ? c[i] : 0;
        buf[tid] = v;
        __syncthreads();
        for (int off = 1; off < 1024; off <<= 1) {
            int x = (tid >= off) ? buf[tid - off] : 0;
            __syncthreads();
            buf[tid] += x;
            __syncthreads();
        }
        int incl = buf[tid];
        int total = buf[1023];
        int b = base_s;
        if (i < N_) rp[i] = b + incl - v;
        __syncthreads();
        if (tid == 0) base_s = b + total;
        __syncthreads();
    }
    if (tid == 0) rp[N_] = base_s;
}

__global__ void k_scatter(const int* __restrict__ A_rows, const int* __restrict__ A_cols,
                          const float* __restrict__ A_val, const int* __restrict__ row_ptr,
                          int* __restrict__ fill, int* __restrict__ e_col,
                          float* __restrict__ e_val) {
    int gid = blockIdx.x * 256 + threadIdx.x;
    if (gid >= T_ * NNZ_) return;
    int t = gid / NNZ_;
    int r = A_rows[gid];
    int pos = row_ptr[(size_t)t * (N_ + 1) + r] + atomicAdd(&fill[t * N_ + r], 1);
    e_col[(size_t)t * NNZ_ + pos] = A_cols[gid];
    e_val[(size_t)t * NNZ_ + pos] = A_val[gid];
}

// ---------- SpMM: AH[t][r] = sum_e val*X[t][col], wave per row ----------
__global__ void k_spmm(const float* __restrict__ X, const int* __restrict__ row_ptr,
                       const int* __restrict__ e_col, const float* __restrict__ e_val,
                       float* __restrict__ AH) {
    int gid = blockIdx.x * 256 + threadIdx.x;
    int wave = gid >> 6, lane = gid & 63;
    if (wave >= T_ * N_) return;
    int t = wave / N_;
    int r = wave - t * N_;
    int s = row_ptr[(size_t)t * (N_ + 1) + r];
    int e = row_ptr[(size_t)t * (N_ + 1) + r + 1];
    const float2* Xt = (const float2*)(X + (size_t)t * N_ * F0_);
    const int* ec = e_col + (size_t)t * NNZ_;
    const float* ev = e_val + (size_t)t * NNZ_;
    float2 acc = {0.f, 0.f};
    for (int q = s; q < e; q++) {
        int c = ec[q];
        float v = ev[q];
        float2 x = Xt[(size_t)c * 64 + lane];
        acc.x += v * x.x;
        acc.y += v * x.y;
    }
    ((float2*)AH)[(size_t)wave * 64 + lane] = acc;
}

// ---------- GRU sequential parts ----------
__global__ void k_gru_a(const float* __restrict__ AZt, const float* __restrict__ ARt,
                        const float* __restrict__ UZ, const float* __restrict__ UR,
                        const float* __restrict__ Wprev, float* __restrict__ Zg,
                        float* __restrict__ Rg) {
    int gid = blockIdx.x * 256 + threadIdx.x;  // i*128 + j
    int j = gid & 127, i = gid >> 7;
    float az = AZt[gid], ar = ARt[gid];
    for (int k = 0; k < 128; k++) {
        float w = Wprev[k * 128 + j];
        az += UZ[i * 128 + k] * w;
        ar += UR[i * 128 + k] * w;
    }
    Zg[gid] = 1.f / (1.f + expf(-az));
    Rg[gid] = 1.f / (1.f + expf(-ar));
}

__global__ void k_gru_b(const float* __restrict__ AHt, const float* __restrict__ UH,
                        const float* __restrict__ Wprev, const float* __restrict__ Zg,
                        const float* __restrict__ Rg, float* __restrict__ Wnew) {
    int gid = blockIdx.x * 256 + threadIdx.x;
    int j = gid & 127, i = gid >> 7;
    float acc = AHt[gid];
    for (int k = 0; k < 128; k++)
        acc += UH[i * 128 + k] * (Rg[k * 128 + j] * Wprev[k * 128 + j]);
    float ht = tanhf(acc);
    float w = Wprev[gid], z = Zg[gid];
    Wnew[gid] = (1.f - z) * w + z * ht;
}

// ---------- WU[t][k][h2] = sum_m W_t[k][m] * U[(h2<64? m : 128+m)][h2&63] ----------
__global__ void k_wu(const float* __restrict__ W_seq, const float* __restrict__ U,
                     float* __restrict__ WU) {
    int blk = blockIdx.x;  // t*128 + k
    int t = blk >> 7, k = blk & 127;
    int h2 = threadIdx.x;
    const float* Wt = W_seq + (size_t)t * 16384;
    int h = h2 & 63;
    const float* Ub = U + (h2 < 64 ? 0 : 128 * 64);
    float acc = 0.f;
    for (int m = 0; m < 128; m++) acc += Wt[k * 128 + m] * Ub[m * 64 + h];
    WU[((size_t)t * 128 + k) * 128 + h2] = acc;
}

// ---------- PQ = AH @ WU[t] (in place), LDS-tiled register-blocked GEMM ----------
// grid (782, T_): block owns 64 rows x 128 cols of one t; 256 thr, 8x4 out/thr.
__global__ __launch_bounds__(256) void k_pq(float* __restrict__ AH,
                                            const float* __restrict__ WU) {
    __shared__ float AT[32][72];    // transposed AH chunk [k][row], pitch 72 (16B-aligned)
    __shared__ float WUc[32][128];  // WU chunk [k][col]
    int t = blockIdx.y;
    int rbase = blockIdx.x * 64;
    int tid = threadIdx.x;
    const float* wu = WU + (size_t)t * 16384;
    float* AHt = AH + (size_t)t * N_ * F0_;
    int cg = tid & 31;   // 4 cols at cg*4
    int rg = tid >> 5;   // 8 rows at rg*8
    float acc[8][4] = {{0.f}};
#pragma unroll
    for (int kc = 0; kc < 128; kc += 32) {
        // stage AH[rbase..rbase+63][kc..kc+31] transposed
        for (int q = tid; q < 512; q += 256) {
            int row = q >> 3, k4 = (q & 7) * 4;
            float4 v = {0.f, 0.f, 0.f, 0.f};
            int r = rbase + row;
            if (r < N_) v = *(const float4*)(AHt + (size_t)r * F0_ + kc + k4);
            AT[k4 + 0][row] = v.x;
            AT[k4 + 1][row] = v.y;
            AT[k4 + 2][row] = v.z;
            AT[k4 + 3][row] = v.w;
        }
        // stage WU[kc..kc+31][:] linear (16 KB contiguous)
        for (int q = tid; q < 1024; q += 256)
            *((float4*)&WUc[0][0] + q) = *((const float4*)(wu + (size_t)kc * 128) + q);
        __syncthreads();
#pragma unroll
        for (int kk = 0; kk < 32; kk++) {
            float4 a01 = *(const float4*)&AT[kk][rg * 8];
            float4 a23 = *(const float4*)&AT[kk][rg * 8 + 4];
            float4 w = *(const float4*)&WUc[kk][cg * 4];
            float a[8] = {a01.x, a01.y, a01.z, a01.w, a23.x, a23.y, a23.z, a23.w};
            float wv[4] = {w.x, w.y, w.z, w.w};
#pragma unroll
            for (int i = 0; i < 8; i++)
#pragma unroll
                for (int j = 0; j < 4; j++) acc[i][j] += a[i] * wv[j];
        }
        __syncthreads();
    }
#pragma unroll
    for (int i = 0; i < 8; i++) {
        int r = rbase + rg * 8 + i;
        if (r < N_) {
            float4 o = {acc[i][0], acc[i][1], acc[i][2], acc[i][3]};
            *(float4*)(AHt + (size_t)r * F0_ + cg * 4) = o;
        }
    }
}

// ---------- out[e] = P[flat_src] + Q[flat_trg] ----------
__global__ void k_final(const float* __restrict__ PQ, const int* __restrict__ et,
                        const int* __restrict__ es, const int* __restrict__ eg,
                        float* __restrict__ out) {
    int gid = blockIdx.x * 256 + threadIdx.x;  // e*16 + q
    if (gid >= E_ * 16) return;
    int e = gid >> 4, q = gid & 15;
    int t = et[e];
    const float4 a = *(const float4*)(PQ + ((size_t)(t * N_ + es[e])) * 128 + q * 4);
    const float4 b = *(const float4*)(PQ + ((size_t)(t * N_ + eg[e])) * 128 + 64 + q * 4);
    float4 o = {a.x + b.x, a.y + b.y, a.z + b.z, a.w + b.w};
    *(float4*)(out + (size_t)e * 64 + q * 4) = o;
}

__global__ void k_wfin(const float* __restrict__ W_seq, float* __restrict__ out) {
    int gid = blockIdx.x * 256 + threadIdx.x;
    out[(size_t)E_ * 64 + gid] = W_seq[(size_t)7 * 16384 + gid];
}

// ---------- launch ----------
extern "C" void kernel_launch(void* const* d_in, const int* in_sizes, int n_in,
                              void* d_out, int out_size, void* d_ws, size_t ws_size,
                              hipStream_t stream) {
    const float* X = (const float*)d_in[0];
    const int* A_rows = (const int*)d_in[1];
    const int* A_cols = (const int*)d_in[2];
    const float* A_val = (const float*)d_in[3];
    const int* edge_time = (const int*)d_in[4];
    const int* edge_src = (const int*)d_in[5];
    const int* edge_trg = (const int*)d_in[6];
    const float* p = (const float*)d_in[7];
    const float* W_Z = (const float*)d_in[8];
    const float* U_Z = (const float*)d_in[9];
    const float* B_Z = (const float*)d_in[10];
    const float* W_R = (const float*)d_in[11];
    const float* U_R = (const float*)d_in[12];
    const float* B_R = (const float*)d_in[13];
    const float* W_H = (const float*)d_in[14];
    const float* U_H = (const float*)d_in[15];
    const float* B_H = (const float*)d_in[16];
    const float* W_init = (const float*)d_in[17];
    const float* U = (const float*)d_in[18];
    float* out = (float*)d_out;

    char* ws = (char*)d_ws;
    size_t off = 0;
    auto take = [&](size_t bytes) {
        char* ptr = ws + off;
        off = (off + bytes + 255) & ~(size_t)255;
        return (void*)ptr;
    };
    float* AH = (float*)take((size_t)T_ * N_ * F0_ * 4);      // 204.8 MB, becomes PQ in place
    int* e_col = (int*)take((size_t)T_ * NNZ_ * 4);           // 25.6 MB
    float* e_val = (float*)take((size_t)T_ * NNZ_ * 4);       // 25.6 MB
    float* yv = (float*)take((size_t)T_ * N_ * 4);
    int* row_ptr = (int*)take((size_t)T_ * (N_ + 1) * 4);
    int* cnt = (int*)take((size_t)T_ * N_ * 4);
    int* fill = (int*)take((size_t)T_ * N_ * 4);
    float* p_hat = (float*)take(512);
    float* topv = (float*)take((size_t)T_ * K_ * 4);
    int* topidx = (int*)take((size_t)T_ * K_ * 4);
    float* Z = (float*)take((size_t)T_ * F0_ * K_ * 4);
    float* AZb = (float*)take((size_t)T_ * 16384 * 4);
    float* ARb = (float*)take((size_t)T_ * 16384 * 4);
    float* AHb = (float*)take((size_t)T_ * 16384 * 4);
    float* Zg = (float*)take(16384 * 4);
    float* Rg = (float*)take(16384 * 4);
    float* W_seq = (float*)take((size_t)T_ * 16384 * 4);
    float* WU = (float*)take((size_t)T_ * 16384 * 4);

    hipMemsetAsync(cnt, 0, (size_t)T_ * N_ * 4, stream);
    hipMemsetAsync(fill, 0, (size_t)T_ * N_ * 4, stream);

    k_phat<<<1, 128, 0, stream>>>(p, p_hat);
    k_y<<<(T_ * N_ * 64) / 256, 256, 0, stream>>>(X, p_hat, yv);
    k_topk<<<T_, 1024, 0, stream>>>(yv, topv, topidx);
    k_z<<<(T_ * F0_ * K_) / 256, 256, 0, stream>>>(X, topv, topidx, Z);
    k_az<<<(3 * T_ * 16384) / 256, 256, 0, stream>>>(W_Z, W_R, W_H, B_Z, B_R, B_H, Z,
                                                     AZb, ARb, AHb);
    k_hist<<<(T_ * NNZ_ + 255) / 256, 256, 0, stream>>>(A_rows, cnt);
    k_scan<<<T_, 1024, 0, stream>>>(cnt, row_ptr);
    k_scatter<<<(T_ * NNZ_ + 255) / 256, 256, 0, stream>>>(A_rows, A_cols, A_val, row_ptr,
                                                           fill, e_col, e_val);
    k_spmm<<<(T_ * N_ * 64) / 256, 256, 0, stream>>>(X, row_ptr, e_col, e_val, AH);
    for (int t = 0; t < T_; t++) {
        const float* Wprev = (t == 0) ? W_init : (W_seq + (size_t)(t - 1) * 16384);
        k_gru_a<<<64, 256, 0, stream>>>(AZb + (size_t)t * 16384, ARb + (size_t)t * 16384,
                                        U_Z, U_R, Wprev, Zg, Rg);
        k_gru_b<<<64, 256, 0, stream>>>(AHb + (size_t)t * 16384, U_H, Wprev, Zg, Rg,
                                        W_seq + (size_t)t * 16384);
    }
    k_wu<<<T_ * 128, 128, 0, stream>>>(W_seq, U, WU);
    {
        dim3 g((N_ + 63) / 64, T_);
        k_pq<<<g, 256, 0, stream>>>(AH, WU);
    }
    k_final<<<(E_ * 16) / 256, 256, 0, stream>>>(AH, edge_time, edge_src, edge_trg, out);
    k_wfin<<<(F0_ * H0_) / 256, 256, 0, stream>>>(W_seq, out);
}

// Round 3
// 1937.924 us; speedup vs baseline: 5.4921x; 5.4921x over previous
//
#include <hip/hip_runtime.h>
#include <math.h>

#define T_ 8
#define N_ 50000
#define F0_ 128
#define H0_ 128
#define H1_ 64
#define NNZ_ 800000
#define E_ 1000000
#define K_ 128
#define CAP_ 3072

// ---------- helpers ----------
__device__ inline unsigned ford(float f) {
    unsigned b = __float_as_uint(f);
    return (b & 0x80000000u) ? ~b : (b | 0x80000000u);
}
__device__ inline float funord(unsigned u) {
    unsigned b = (u & 0x80000000u) ? (u & 0x7fffffffu) : ~u;
    return __uint_as_float(b);
}

// ---------- p_hat = p / ||p|| ----------
__global__ void k_phat(const float* p, float* p_hat) {
    __shared__ float s[128];
    int i = threadIdx.x;
    float v = p[i];
    s[i] = v * v;
    __syncthreads();
    for (int off = 64; off > 0; off >>= 1) {
        if (i < off) s[i] += s[i + off];
        __syncthreads();
    }
    p_hat[i] = v / sqrtf(s[0]);
}

// ---------- y[t][n] = dot(X[t][n], p_hat), wave per row ----------
__global__ void k_y(const float* __restrict__ X, const float* __restrict__ p_hat,
                    float* __restrict__ y) {
    int gid = blockIdx.x * 256 + threadIdx.x;
    int wave = gid >> 6, lane = gid & 63;
    if (wave >= T_ * N_) return;
    const float2* xr = (const float2*)(X + (size_t)wave * F0_);
    float2 a = xr[lane];
    float2 ph = ((const float2*)p_hat)[lane];
    float acc = a.x * ph.x + a.y * ph.y;
#pragma unroll
    for (int off = 32; off > 0; off >>= 1) acc += __shfl_down(acc, off);
    if (lane == 0) y[wave] = acc;
}

// ---------- exact top-128 per t: 2-level radix select + exact rank ----------
__global__ __launch_bounds__(1024) void k_topk(const float* __restrict__ y,
                                               float* __restrict__ topv,
                                               int* __restrict__ topidx) {
    int t = blockIdx.x;
    const float* yt = y + (size_t)t * N_;
    __shared__ int hist[256];
    __shared__ int sb1, sAbove, sP, scand;
    __shared__ unsigned cu[CAP_];
    __shared__ int cidx[CAP_];
    int tid = threadIdx.x;

    if (tid < 256) hist[tid] = 0;
    __syncthreads();
    for (int i = tid; i < N_; i += 1024) {
        unsigned u = ford(yt[i]);
        atomicAdd(&hist[u >> 24], 1);
    }
    __syncthreads();
    if (tid == 0) {
        int acc = 0, b = 255;
        for (; b >= 0; b--) { acc += hist[b]; if (acc >= K_) break; }
        sb1 = b;
        sAbove = acc - hist[b];
    }
    __syncthreads();
    int b1 = sb1;
    if (tid < 256) hist[tid] = 0;
    __syncthreads();
    for (int i = tid; i < N_; i += 1024) {
        unsigned u = ford(yt[i]);
        if ((int)(u >> 24) == b1) atomicAdd(&hist[(u >> 16) & 255], 1);
    }
    __syncthreads();
    if (tid == 0) {
        int acc = sAbove, b = 255;
        for (; b >= 0; b--) { acc += hist[b]; if (acc >= K_) break; }
        sP = (b1 << 8) | b;
        scand = 0;
    }
    __syncthreads();
    unsigned P = (unsigned)sP;
    for (int i = tid; i < N_; i += 1024) {
        unsigned u = ford(yt[i]);
        if ((u >> 16) >= P) {
            int pos = atomicAdd(&scand, 1);
            if (pos < CAP_) { cu[pos] = u; cidx[pos] = i; }
        }
    }
    __syncthreads();
    int C = min(scand, CAP_);
    for (int c = tid; c < C; c += 1024) {
        unsigned uc = cu[c];
        int ic = cidx[c];
        int rank = 0;
        for (int o = 0; o < C; o++) {
            unsigned uo = cu[o];
            rank += (uo > uc) || (uo == uc && cidx[o] < ic);
        }
        if (rank < K_) {
            topv[t * K_ + rank] = funord(uc);
            topidx[t * K_ + rank] = ic;
        }
    }
}

// ---------- Z[t][f][j] = X[t][idx[j]][f] * topv[j] ----------
__global__ void k_z(const float* __restrict__ X, const float* __restrict__ topv,
                    const int* __restrict__ topidx, float* __restrict__ Z) {
    int gid = blockIdx.x * 256 + threadIdx.x;  // t*16384 + f*128 + j
    if (gid >= T_ * F0_ * K_) return;
    int j = gid & 127;
    int f = (gid >> 7) & 127;
    int t = gid >> 14;
    int idx = topidx[t * K_ + j];
    float v = topv[t * K_ + j];
    Z[gid] = X[((size_t)(t * N_ + idx)) * F0_ + f] * v;
}

// ---------- A_g[t] = W_g @ Z_t + B_g  (g in {Z,R,H}, all t parallel) ----------
__global__ void k_az(const float* __restrict__ WZ, const float* __restrict__ WR,
                     const float* __restrict__ WH, const float* __restrict__ BZ,
                     const float* __restrict__ BR, const float* __restrict__ BH,
                     const float* __restrict__ Z, float* __restrict__ AZ,
                     float* __restrict__ AR, float* __restrict__ AHo) {
    int gid = blockIdx.x * 256 + threadIdx.x;  // g*131072 + t*16384 + i*128 + j
    int j = gid & 127;
    int i = (gid >> 7) & 127;
    int t = (gid >> 14) & 7;
    int g = gid >> 17;
    const float* W = (g == 0) ? WZ : (g == 1) ? WR : WH;
    const float* B = (g == 0) ? BZ : (g == 1) ? BR : BH;
    float* Ao = (g == 0) ? AZ : (g == 1) ? AR : AHo;
    const float* Zt = Z + (size_t)t * 16384;
    float acc = B[i * 128 + j];
    for (int k = 0; k < 128; k++) acc += W[i * 128 + k] * Zt[k * 128 + j];
    Ao[(size_t)(t * 128 + i) * 128 + j] = acc;
}

// ---------- CSR build ----------
__global__ void k_hist(const int* __restrict__ A_rows, int* __restrict__ cnt) {
    int gid = blockIdx.x * 256 + threadIdx.x;
    if (gid >= T_ * NNZ_) return;
    int t = gid / NNZ_;
    atomicAdd(&cnt[t * N_ + A_rows[gid]], 1);
}

__global__ __launch_bounds__(1024) void k_scan(const int* __restrict__ cnt,
                                               int* __restrict__ row_ptr) {
    int t = blockIdx.x;
    __shared__ int buf[1024];
    __shared__ int base_s;
    int tid = threadIdx.x;
    if (tid == 0) base_s = 0;
    __syncthreads();
    const int* c = cnt + (size_t)t * N_;
    int* rp = row_ptr + (size_t)t * (N_ + 1);
    for (int start = 0; start < N_; start += 1024) {
        int i = start + tid;
        int v = (i < N_) ? c[i] : 0;
        buf[tid] = v;
        __syncthreads();
        for (int off = 1; off < 1024; off <<= 1) {
            int x = (tid >= off) ? buf[tid - off] : 0;
            __syncthreads();
            buf[tid] += x;
            __syncthreads();
        }
        int incl = buf[tid];
        int total = buf[1023];
        int b = base_s;
        if (i < N_) rp[i] = b + incl - v;
        __syncthreads();
        if (tid == 0) base_s = b + total;
        __syncthreads();
    }
    if (tid == 0) rp[N_] = base_s;
}

__global__ void k_scatter(const int* __restrict__ A_rows, const int* __restrict__ A_cols,
                          const float* __restrict__ A_val, const int* __restrict__ row_ptr,
                          int* __restrict__ fill, int* __restrict__ e_col,
                          float* __restrict__ e_val) {
    int gid = blockIdx.x * 256 + threadIdx.x;
    if (gid >= T_ * NNZ_) return;
    int t = gid / NNZ_;
    int r = A_rows[gid];
    int pos = row_ptr[(size_t)t * (N_ + 1) + r] + atomicAdd(&fill[t * N_ + r], 1);
    e_col[(size_t)t * NNZ_ + pos] = A_cols[gid];
    e_val[(size_t)t * NNZ_ + pos] = A_val[gid];
}

// ---------- SpMM: AH[t][r] = sum_e val*X[t][col], wave per row ----------
__global__ void k_spmm(const float* __restrict__ X, const int* __restrict__ row_ptr,
                       const int* __restrict__ e_col, const float* __restrict__ e_val,
                       float* __restrict__ AH) {
    int gid = blockIdx.x * 256 + threadIdx.x;
    int wave = gid >> 6, lane = gid & 63;
    if (wave >= T_ * N_) return;
    int t = wave / N_;
    int r = wave - t * N_;
    int s = row_ptr[(size_t)t * (N_ + 1) + r];
    int e = row_ptr[(size_t)t * (N_ + 1) + r + 1];
    const float2* Xt = (const float2*)(X + (size_t)t * N_ * F0_);
    const int* ec = e_col + (size_t)t * NNZ_;
    const float* ev = e_val + (size_t)t * NNZ_;
    float2 acc = {0.f, 0.f};
    for (int q = s; q < e; q++) {
        int c = ec[q];
        float v = ev[q];
        float2 x = Xt[(size_t)c * 64 + lane];
        acc.x += v * x.x;
        acc.y += v * x.y;
    }
    ((float2*)AH)[(size_t)wave * 64 + lane] = acc;
}

// ---------- GRU sequential parts ----------
__global__ void k_gru_a(const float* __restrict__ AZt, const float* __restrict__ ARt,
                        const float* __restrict__ UZ, const float* __restrict__ UR,
                        const float* __restrict__ Wprev, float* __restrict__ Zg,
                        float* __restrict__ Rg) {
    int gid = blockIdx.x * 256 + threadIdx.x;  // i*128 + j
    int j = gid & 127, i = gid >> 7;
    float az = AZt[gid], ar = ARt[gid];
    for (int k = 0; k < 128; k++) {
        float w = Wprev[k * 128 + j];
        az += UZ[i * 128 + k] * w;
        ar += UR[i * 128 + k] * w;
    }
    Zg[gid] = 1.f / (1.f + expf(-az));
    Rg[gid] = 1.f / (1.f + expf(-ar));
}

__global__ void k_gru_b(const float* __restrict__ AHt, const float* __restrict__ UH,
                        const float* __restrict__ Wprev, const float* __restrict__ Zg,
                        const float* __restrict__ Rg, float* __restrict__ Wnew) {
    int gid = blockIdx.x * 256 + threadIdx.x;
    int j = gid & 127, i = gid >> 7;
    float acc = AHt[gid];
    for (int k = 0; k < 128; k++)
        acc += UH[i * 128 + k] * (Rg[k * 128 + j] * Wprev[k * 128 + j]);
    float ht = tanhf(acc);
    float w = Wprev[gid], z = Zg[gid];
    Wnew[gid] = (1.f - z) * w + z * ht;
}

// ---------- WU[t][k][h2] = sum_m W_t[k][m] * U[(h2<64? m : 128+m)][h2&63] ----------
__global__ void k_wu(const float* __restrict__ W_seq, const float* __restrict__ U,
                     float* __restrict__ WU) {
    int blk = blockIdx.x;  // t*128 + k
    int t = blk >> 7, k = blk & 127;
    int h2 = threadIdx.x;
    const float* Wt = W_seq + (size_t)t * 16384;
    int h = h2 & 63;
    const float* Ub = U + (h2 < 64 ? 0 : 128 * 64);
    float acc = 0.f;
    for (int m = 0; m < 128; m++) acc += Wt[k * 128 + m] * Ub[m * 64 + h];
    WU[((size_t)t * 128 + k) * 128 + h2] = acc;
}

// ---------- PQ = AH @ WU[t] (in place), LDS-tiled GEMM, register-disciplined ----------
// grid (1563, T_): block = 32 rows x 128 cols of one t; 256 thr; 4x4 out/thr in
// 4 named float4 accumulators (NO indexable arrays -> no scratch spill).
__global__ __launch_bounds__(256) void k_pq(float* __restrict__ AH,
                                            const float* __restrict__ WU) {
    __shared__ float AT[32][36];    // A chunk transposed [k][row], pitch 36 (16B-aligned)
    __shared__ float WUc[32][128];  // WU chunk [k][col]
    int t = blockIdx.y;
    int rbase = blockIdx.x * 32;
    int tid = threadIdx.x;
    const float* wu = WU + (size_t)t * 16384;
    float* AHt = AH + (size_t)t * N_ * F0_;
    int cg = tid & 31;   // 4 cols at cg*4
    int rg = tid >> 5;   // 4 rows at rg*4
    float4 acc0 = {0.f, 0.f, 0.f, 0.f};
    float4 acc1 = {0.f, 0.f, 0.f, 0.f};
    float4 acc2 = {0.f, 0.f, 0.f, 0.f};
    float4 acc3 = {0.f, 0.f, 0.f, 0.f};
    int srow = tid >> 3;          // staging: row 0..31
    int sk4 = (tid & 7) * 4;      // staging: k offset 0,4,...,28
    for (int kc = 0; kc < 128; kc += 32) {
        // stage A[rbase..+31][kc..+31] transposed: one float4 per thread
        {
            float4 v = {0.f, 0.f, 0.f, 0.f};
            int r = rbase + srow;
            if (r < N_) v = *(const float4*)(AHt + (size_t)r * F0_ + kc + sk4);
            AT[sk4 + 0][srow] = v.x;
            AT[sk4 + 1][srow] = v.y;
            AT[sk4 + 2][srow] = v.z;
            AT[sk4 + 3][srow] = v.w;
        }
        // stage WU[kc..+31][:] linear: 4 float4 per thread
        {
            const float4* src = (const float4*)(wu + (size_t)kc * 128);
            float4* dst = (float4*)&WUc[0][0];
            dst[tid] = src[tid];
            dst[tid + 256] = src[tid + 256];
            dst[tid + 512] = src[tid + 512];
            dst[tid + 768] = src[tid + 768];
        }
        __syncthreads();
#pragma unroll 4
        for (int kk = 0; kk < 32; kk++) {
            float4 a = *(const float4*)&AT[kk][rg * 4];   // wave-broadcast read
            float4 w = *(const float4*)&WUc[kk][cg * 4];
            acc0.x += a.x * w.x; acc0.y += a.x * w.y; acc0.z += a.x * w.z; acc0.w += a.x * w.w;
            acc1.x += a.y * w.x; acc1.y += a.y * w.y; acc1.z += a.y * w.z; acc1.w += a.y * w.w;
            acc2.x += a.z * w.x; acc2.y += a.z * w.y; acc2.z += a.z * w.z; acc2.w += a.z * w.w;
            acc3.x += a.w * w.x; acc3.y += a.w * w.y; acc3.z += a.w * w.z; acc3.w += a.w * w.w;
        }
        __syncthreads();
    }
    int r0 = rbase + rg * 4;
    if (r0 + 0 < N_) *(float4*)(AHt + (size_t)(r0 + 0) * F0_ + cg * 4) = acc0;
    if (r0 + 1 < N_) *(float4*)(AHt + (size_t)(r0 + 1) * F0_ + cg * 4) = acc1;
    if (r0 + 2 < N_) *(float4*)(AHt + (size_t)(r0 + 2) * F0_ + cg * 4) = acc2;
    if (r0 + 3 < N_) *(float4*)(AHt + (size_t)(r0 + 3) * F0_ + cg * 4) = acc3;
}

// ---------- out[e] = P[flat_src] + Q[flat_trg] ----------
__global__ void k_final(const float* __restrict__ PQ, const int* __restrict__ et,
                        const int* __restrict__ es, const int* __restrict__ eg,
                        float* __restrict__ out) {
    int gid = blockIdx.x * 256 + threadIdx.x;  // e*16 + q
    if (gid >= E_ * 16) return;
    int e = gid >> 4, q = gid & 15;
    int t = et[e];
    const float4 a = *(const float4*)(PQ + ((size_t)(t * N_ + es[e])) * 128 + q * 4);
    const float4 b = *(const float4*)(PQ + ((size_t)(t * N_ + eg[e])) * 128 + 64 + q * 4);
    float4 o = {a.x + b.x, a.y + b.y, a.z + b.z, a.w + b.w};
    *(float4*)(out + (size_t)e * 64 + q * 4) = o;
}

__global__ void k_wfin(const float* __restrict__ W_seq, float* __restrict__ out) {
    int gid = blockIdx.x * 256 + threadIdx.x;
    out[(size_t)E_ * 64 + gid] = W_seq[(size_t)7 * 16384 + gid];
}

// ---------- launch ----------
extern "C" void kernel_launch(void* const* d_in, const int* in_sizes, int n_in,
                              void* d_out, int out_size, void* d_ws, size_t ws_size,
                              hipStream_t stream) {
    const float* X = (const float*)d_in[0];
    const int* A_rows = (const int*)d_in[1];
    const int* A_cols = (const int*)d_in[2];
    const float* A_val = (const float*)d_in[3];
    const int* edge_time = (const int*)d_in[4];
    const int* edge_src = (const int*)d_in[5];
    const int* edge_trg = (const int*)d_in[6];
    const float* p = (const float*)d_in[7];
    const float* W_Z = (const float*)d_in[8];
    const float* U_Z = (const float*)d_in[9];
    const float* B_Z = (const float*)d_in[10];
    const float* W_R = (const float*)d_in[11];
    const float* U_R = (const float*)d_in[12];
    const float* B_R = (const float*)d_in[13];
    const float* W_H = (const float*)d_in[14];
    const float* U_H = (const float*)d_in[15];
    const float* B_H = (const float*)d_in[16];
    const float* W_init = (const float*)d_in[17];
    const float* U = (const float*)d_in[18];
    float* out = (float*)d_out;

    char* ws = (char*)d_ws;
    size_t off = 0;
    auto take = [&](size_t bytes) {
        char* ptr = ws + off;
        off = (off + bytes + 255) & ~(size_t)255;
        return (void*)ptr;
    };
    float* AH = (float*)take((size_t)T_ * N_ * F0_ * 4);      // 204.8 MB, becomes PQ in place
    int* e_col = (int*)take((size_t)T_ * NNZ_ * 4);           // 25.6 MB
    float* e_val = (float*)take((size_t)T_ * NNZ_ * 4);       // 25.6 MB
    float* yv = (float*)take((size_t)T_ * N_ * 4);
    int* row_ptr = (int*)take((size_t)T_ * (N_ + 1) * 4);
    int* cnt = (int*)take((size_t)T_ * N_ * 4);
    int* fill = (int*)take((size_t)T_ * N_ * 4);
    float* p_hat = (float*)take(512);
    float* topv = (float*)take((size_t)T_ * K_ * 4);
    int* topidx = (int*)take((size_t)T_ * K_ * 4);
    float* Z = (float*)take((size_t)T_ * F0_ * K_ * 4);
    float* AZb = (float*)take((size_t)T_ * 16384 * 4);
    float* ARb = (float*)take((size_t)T_ * 16384 * 4);
    float* AHb = (float*)take((size_t)T_ * 16384 * 4);
    float* Zg = (float*)take(16384 * 4);
    float* Rg = (float*)take(16384 * 4);
    float* W_seq = (float*)take((size_t)T_ * 16384 * 4);
    float* WU = (float*)take((size_t)T_ * 16384 * 4);

    hipMemsetAsync(cnt, 0, (size_t)T_ * N_ * 4, stream);
    hipMemsetAsync(fill, 0, (size_t)T_ * N_ * 4, stream);

    k_phat<<<1, 128, 0, stream>>>(p, p_hat);
    k_y<<<(T_ * N_ * 64) / 256, 256, 0, stream>>>(X, p_hat, yv);
    k_topk<<<T_, 1024, 0, stream>>>(yv, topv, topidx);
    k_z<<<(T_ * F0_ * K_) / 256, 256, 0, stream>>>(X, topv, topidx, Z);
    k_az<<<(3 * T_ * 16384) / 256, 256, 0, stream>>>(W_Z, W_R, W_H, B_Z, B_R, B_H, Z,
                                                     AZb, ARb, AHb);
    k_hist<<<(T_ * NNZ_ + 255) / 256, 256, 0, stream>>>(A_rows, cnt);
    k_scan<<<T_, 1024, 0, stream>>>(cnt, row_ptr);
    k_scatter<<<(T_ * NNZ_ + 255) / 256, 256, 0, stream>>>(A_rows, A_cols, A_val, row_ptr,
                                                           fill, e_col, e_val);
    k_spmm<<<(T_ * N_ * 64) / 256, 256, 0, stream>>>(X, row_ptr, e_col, e_val, AH);
    for (int t = 0; t < T_; t++) {
        const float* Wprev = (t == 0) ? W_init : (W_seq + (size_t)(t - 1) * 16384);
        k_gru_a<<<64, 256, 0, stream>>>(AZb + (size_t)t * 16384, ARb + (size_t)t * 16384,
                                        U_Z, U_R, Wprev, Zg, Rg);
        k_gru_b<<<64, 256, 0, stream>>>(AHb + (size_t)t * 16384, U_H, Wprev, Zg, Rg,
                                        W_seq + (size_t)t * 16384);
    }
    k_wu<<<T_ * 128, 128, 0, stream>>>(W_seq, U, WU);
    {
        dim3 g((N_ + 31) / 32, T_);
        k_pq<<<g, 256, 0, stream>>>(AH, WU);
    }
    k_final<<<(E_ * 16) / 256, 256, 0, stream>>>(AH, edge_time, edge_src, edge_trg, out);
    k_wfin<<<(F0_ * H0_) / 256, 256, 0, stream>>>(W_seq, out);
}

// Round 4
// 1575.035 us; speedup vs baseline: 6.7575x; 1.2304x over previous
//
#include <hip/hip_runtime.h>
#include <math.h>

#define T_ 8
#define N_ 50000
#define F0_ 128
#define H0_ 128
#define H1_ 64
#define NNZ_ 800000
#define E_ 1000000
#define K_ 128
#define CAP_ 3072
#define SCB 49  // ceil(N_/1024)

// ---------- helpers ----------
__device__ inline unsigned ford(float f) {
    unsigned b = __float_as_uint(f);
    return (b & 0x80000000u) ? ~b : (b | 0x80000000u);
}
__device__ inline float funord(unsigned u) {
    unsigned b = (u & 0x80000000u) ? (u & 0x7fffffffu) : ~u;
    return __uint_as_float(b);
}
__device__ inline unsigned bfr(float f) {  // fp32 -> bf16 bits (RNE)
    unsigned u = __float_as_uint(f);
    return (u + 0x7fffu + ((u >> 16) & 1u)) >> 16;
}
__device__ inline unsigned bfpack(float lo, float hi) { return bfr(lo) | (bfr(hi) << 16); }

// ---------- p_hat = p / ||p|| ----------
__global__ void k_phat(const float* p, float* p_hat) {
    __shared__ float s[128];
    int i = threadIdx.x;
    float v = p[i];
    s[i] = v * v;
    __syncthreads();
    for (int off = 64; off > 0; off >>= 1) {
        if (i < off) s[i] += s[i + off];
        __syncthreads();
    }
    p_hat[i] = v / sqrtf(s[0]);
}

// ---------- y = X @ p_hat (wave/row) + optional bf16 copy of X ----------
__global__ void k_y(const float* __restrict__ X, const float* __restrict__ p_hat,
                    float* __restrict__ y, unsigned* __restrict__ Xh) {
    int gid = blockIdx.x * 256 + threadIdx.x;
    int wave = gid >> 6, lane = gid & 63;
    if (wave >= T_ * N_) return;
    const float2* xr = (const float2*)(X + (size_t)wave * F0_);
    float2 a = xr[lane];
    if (Xh) Xh[(size_t)wave * 64 + lane] = bfpack(a.x, a.y);
    float2 ph = ((const float2*)p_hat)[lane];
    float acc = a.x * ph.x + a.y * ph.y;
#pragma unroll
    for (int off = 32; off > 0; off >>= 1) acc += __shfl_down(acc, off);
    if (lane == 0) y[wave] = acc;
}

// ---------- exact top-128 per t: 2-level radix select + exact rank ----------
__global__ __launch_bounds__(1024) void k_topk(const float* __restrict__ y,
                                               float* __restrict__ topv,
                                               int* __restrict__ topidx) {
    int t = blockIdx.x;
    const float* yt = y + (size_t)t * N_;
    __shared__ int hist[256];
    __shared__ int sb1, sAbove, sP, scand;
    __shared__ unsigned cu[CAP_];
    __shared__ int cidx[CAP_];
    int tid = threadIdx.x;

    if (tid < 256) hist[tid] = 0;
    __syncthreads();
    for (int i = tid; i < N_; i += 1024) {
        unsigned u = ford(yt[i]);
        atomicAdd(&hist[u >> 24], 1);
    }
    __syncthreads();
    if (tid == 0) {
        int acc = 0, b = 255;
        for (; b >= 0; b--) { acc += hist[b]; if (acc >= K_) break; }
        sb1 = b;
        sAbove = acc - hist[b];
    }
    __syncthreads();
    int b1 = sb1;
    if (tid < 256) hist[tid] = 0;
    __syncthreads();
    for (int i = tid; i < N_; i += 1024) {
        unsigned u = ford(yt[i]);
        if ((int)(u >> 24) == b1) atomicAdd(&hist[(u >> 16) & 255], 1);
    }
    __syncthreads();
    if (tid == 0) {
        int acc = sAbove, b = 255;
        for (; b >= 0; b--) { acc += hist[b]; if (acc >= K_) break; }
        sP = (b1 << 8) | b;
        scand = 0;
    }
    __syncthreads();
    unsigned P = (unsigned)sP;
    for (int i = tid; i < N_; i += 1024) {
        unsigned u = ford(yt[i]);
        if ((u >> 16) >= P) {
            int pos = atomicAdd(&scand, 1);
            if (pos < CAP_) { cu[pos] = u; cidx[pos] = i; }
        }
    }
    __syncthreads();
    int C = min(scand, CAP_);
    for (int c = tid; c < C; c += 1024) {
        unsigned uc = cu[c];
        int ic = cidx[c];
        int rank = 0;
        for (int o = 0; o < C; o++) {
            unsigned uo = cu[o];
            rank += (uo > uc) || (uo == uc && cidx[o] < ic);
        }
        if (rank < K_) {
            topv[t * K_ + rank] = funord(uc);
            topidx[t * K_ + rank] = ic;
        }
    }
}

// ---------- Z[t][f][j] = X[t][idx[j]][f] * topv[j] ----------
__global__ void k_z(const float* __restrict__ X, const float* __restrict__ topv,
                    const int* __restrict__ topidx, float* __restrict__ Z) {
    int gid = blockIdx.x * 256 + threadIdx.x;  // t*16384 + f*128 + j
    if (gid >= T_ * F0_ * K_) return;
    int j = gid & 127;
    int f = (gid >> 7) & 127;
    int t = gid >> 14;
    int idx = topidx[t * K_ + j];
    float v = topv[t * K_ + j];
    Z[gid] = X[((size_t)(t * N_ + idx)) * F0_ + f] * v;
}

// ---------- A_g[t] = W_g @ Z_t + B_g  (g in {Z,R,H}, all t parallel) ----------
__global__ void k_az(const float* __restrict__ WZ, const float* __restrict__ WR,
                     const float* __restrict__ WH, const float* __restrict__ BZ,
                     const float* __restrict__ BR, const float* __restrict__ BH,
                     const float* __restrict__ Z, float* __restrict__ AZ,
                     float* __restrict__ AR, float* __restrict__ AHo) {
    int gid = blockIdx.x * 256 + threadIdx.x;  // g*131072 + t*16384 + i*128 + j
    int j = gid & 127;
    int i = (gid >> 7) & 127;
    int t = (gid >> 14) & 7;
    int g = gid >> 17;
    const float* W = (g == 0) ? WZ : (g == 1) ? WR : WH;
    const float* B = (g == 0) ? BZ : (g == 1) ? BR : BH;
    float* Ao = (g == 0) ? AZ : (g == 1) ? AR : AHo;
    const float* Zt = Z + (size_t)t * 16384;
    float acc = B[i * 128 + j];
    for (int k = 0; k < 128; k++) acc += W[i * 128 + k] * Zt[k * 128 + j];
    Ao[(size_t)(t * 128 + i) * 128 + j] = acc;
}

// ---------- CSR build ----------
__global__ void k_hist(const int* __restrict__ A_rows, int* __restrict__ cnt) {
    int gid = blockIdx.x * 256 + threadIdx.x;
    if (gid >= T_ * NNZ_) return;
    int t = gid / NNZ_;
    atomicAdd(&cnt[t * N_ + A_rows[gid]], 1);
}

// 3-phase scan: per-block scan -> block-sum scan -> add offsets
__global__ __launch_bounds__(1024) void k_s1(const int* __restrict__ cnt,
                                             int* __restrict__ row_ptr,
                                             int* __restrict__ bsum) {
    int t = blockIdx.y, b = blockIdx.x;
    int tid = threadIdx.x;
    int i = b * 1024 + tid;
    __shared__ int buf[1024];
    int v = (i < N_) ? cnt[(size_t)t * N_ + i] : 0;
    buf[tid] = v;
    __syncthreads();
    for (int off = 1; off < 1024; off <<= 1) {
        int x = (tid >= off) ? buf[tid - off] : 0;
        __syncthreads();
        buf[tid] += x;
        __syncthreads();
    }
    if (i < N_) row_ptr[(size_t)t * (N_ + 1) + i] = buf[tid] - v;  // block-local exclusive
    if (tid == 1023) bsum[t * SCB + b] = buf[1023];
}

__global__ void k_s2(int* __restrict__ bsum, int* __restrict__ row_ptr) {
    int w = threadIdx.x >> 6, lane = threadIdx.x & 63;  // 8 waves, one per t
    int orig = (lane < SCB) ? bsum[w * SCB + lane] : 0;
    int v = orig;
#pragma unroll
    for (int off = 1; off < 64; off <<= 1) {
        int x = __shfl_up(v, off);
        if (lane >= off) v += x;
    }
    if (lane < SCB) bsum[w * SCB + lane] = v - orig;  // exclusive block offset
    if (lane == 63) row_ptr[(size_t)w * (N_ + 1) + N_] = v;  // total
}

__global__ __launch_bounds__(1024) void k_s3(int* __restrict__ row_ptr,
                                             const int* __restrict__ bsum) {
    int t = blockIdx.y, b = blockIdx.x;
    int i = b * 1024 + threadIdx.x;
    if (i < N_) row_ptr[(size_t)t * (N_ + 1) + i] += bsum[t * SCB + b];
}

__global__ void k_scatter(const int* __restrict__ A_rows, const int* __restrict__ A_cols,
                          const float* __restrict__ A_val, const int* __restrict__ row_ptr,
                          int* __restrict__ fill, int2* __restrict__ ecv) {
    int gid = blockIdx.x * 256 + threadIdx.x;
    if (gid >= T_ * NNZ_) return;
    int t = gid / NNZ_;
    int r = A_rows[gid];
    int pos = row_ptr[(size_t)t * (N_ + 1) + r] + atomicAdd(&fill[t * N_ + r], 1);
    ecv[(size_t)t * NNZ_ + pos] = make_int2(A_cols[gid], __float_as_int(A_val[gid]));
}

// ---------- SpMM (bf16 gather): AH[t][r] = sum val*Xh[t][col] ----------
__global__ void k_spmm(const unsigned* __restrict__ Xh, const int* __restrict__ row_ptr,
                       const int2* __restrict__ ecv, float* __restrict__ AH) {
    int gid = blockIdx.x * 256 + threadIdx.x;
    int wave = gid >> 6, lane = gid & 63;
    if (wave >= T_ * N_) return;
    int t = wave / N_;
    int r = wave - t * N_;
    int s = row_ptr[(size_t)t * (N_ + 1) + r];
    int len = row_ptr[(size_t)t * (N_ + 1) + r + 1] - s;
    const unsigned* Xt = Xh + (size_t)t * N_ * 64;
    const int2* ev = ecv + (size_t)t * NNZ_;
    float2 acc = {0.f, 0.f};
    for (int base = 0; base < len; base += 64) {
        int nn = min(64, len - base);
        int2 my = {0, 0};
        if (base + lane < len) my = ev[s + base + lane];
        for (int q = 0; q < nn; q++) {
            int c = __shfl(my.x, q);
            float v = __int_as_float(__shfl(my.y, q));
            unsigned xp = Xt[(size_t)c * 64 + lane];
            acc.x += v * __uint_as_float(xp << 16);
            acc.y += v * __uint_as_float(xp & 0xffff0000u);
        }
    }
    ((float2*)AH)[(size_t)wave * 64 + lane] = acc;
}

// fallback (fp32 gather) if workspace can't hold Xh
__global__ void k_spmm_f32(const float* __restrict__ X, const int* __restrict__ row_ptr,
                           const int2* __restrict__ ecv, float* __restrict__ AH) {
    int gid = blockIdx.x * 256 + threadIdx.x;
    int wave = gid >> 6, lane = gid & 63;
    if (wave >= T_ * N_) return;
    int t = wave / N_;
    int r = wave - t * N_;
    int s = row_ptr[(size_t)t * (N_ + 1) + r];
    int len = row_ptr[(size_t)t * (N_ + 1) + r + 1] - s;
    const float2* Xt = (const float2*)(X + (size_t)t * N_ * F0_);
    const int2* ev = ecv + (size_t)t * NNZ_;
    float2 acc = {0.f, 0.f};
    for (int base = 0; base < len; base += 64) {
        int nn = min(64, len - base);
        int2 my = {0, 0};
        if (base + lane < len) my = ev[s + base + lane];
        for (int q = 0; q < nn; q++) {
            int c = __shfl(my.x, q);
            float v = __int_as_float(__shfl(my.y, q));
            float2 x = Xt[(size_t)c * 64 + lane];
            acc.x += v * x.x;
            acc.y += v * x.y;
        }
    }
    ((float2*)AH)[(size_t)wave * 64 + lane] = acc;
}

// ---------- fused GRU step (column-separable): one launch per t ----------
// grid 64 x 256: block owns 2 columns x all 128 rows. Bit-identical to split version.
__global__ __launch_bounds__(256) void k_gru(const float* __restrict__ AZt,
                                             const float* __restrict__ ARt,
                                             const float* __restrict__ AHt,
                                             const float* __restrict__ UZ,
                                             const float* __restrict__ UR,
                                             const float* __restrict__ UH,
                                             const float* __restrict__ Wprev,
                                             float* __restrict__ Wnew) {
    __shared__ float RWs[128][2];
    int jl = threadIdx.x >> 7;  // 0..1
    int i = threadIdx.x & 127;
    int j = blockIdx.x * 2 + jl;
    int gid = i * 128 + j;
    float az = AZt[gid], ar = ARt[gid];
    for (int k = 0; k < 128; k++) {
        float w = Wprev[k * 128 + j];  // wave-uniform broadcast
        az += UZ[i * 128 + k] * w;
        ar += UR[i * 128 + k] * w;
    }
    float zg = 1.f / (1.f + expf(-az));
    float rg = 1.f / (1.f + expf(-ar));
    RWs[i][jl] = rg * Wprev[gid];
    __syncthreads();
    float acc = AHt[gid];
    for (int k = 0; k < 128; k++) acc += UH[i * 128 + k] * RWs[k][jl];
    float ht = tanhf(acc);
    float w0 = Wprev[gid];
    Wnew[gid] = (1.f - zg) * w0 + zg * ht;
}

// ---------- WU[t][k][h2] = sum_m W_t[k][m] * U[(h2<64? m : 128+m)][h2&63] ----------
__global__ void k_wu(const float* __restrict__ W_seq, const float* __restrict__ U,
                     float* __restrict__ WU) {
    int blk = blockIdx.x;  // t*128 + k
    int t = blk >> 7, k = blk & 127;
    int h2 = threadIdx.x;
    const float* Wt = W_seq + (size_t)t * 16384;
    int h = h2 & 63;
    const float* Ub = U + (h2 < 64 ? 0 : 128 * 64);
    float acc = 0.f;
    for (int m = 0; m < 128; m++) acc += Wt[k * 128 + m] * Ub[m * 64 + h];
    WU[((size_t)t * 128 + k) * 128 + h2] = acc;
}

// ---------- PQ = AH @ WU[t] (in place), LDS-tiled, register-disciplined ----------
__global__ __launch_bounds__(256) void k_pq(float* __restrict__ AH,
                                            const float* __restrict__ WU) {
    __shared__ float AT[32][36];
    __shared__ float WUc[32][128];
    int t = blockIdx.y;
    int rbase = blockIdx.x * 32;
    int tid = threadIdx.x;
    const float* wu = WU + (size_t)t * 16384;
    float* AHt = AH + (size_t)t * N_ * F0_;
    int cg = tid & 31;
    int rg = tid >> 5;
    float4 acc0 = {0.f, 0.f, 0.f, 0.f};
    float4 acc1 = {0.f, 0.f, 0.f, 0.f};
    float4 acc2 = {0.f, 0.f, 0.f, 0.f};
    float4 acc3 = {0.f, 0.f, 0.f, 0.f};
    int srow = tid >> 3;
    int sk4 = (tid & 7) * 4;
    for (int kc = 0; kc < 128; kc += 32) {
        {
            float4 v = {0.f, 0.f, 0.f, 0.f};
            int r = rbase + srow;
            if (r < N_) v = *(const float4*)(AHt + (size_t)r * F0_ + kc + sk4);
            AT[sk4 + 0][srow] = v.x;
            AT[sk4 + 1][srow] = v.y;
            AT[sk4 + 2][srow] = v.z;
            AT[sk4 + 3][srow] = v.w;
        }
        {
            const float4* src = (const float4*)(wu + (size_t)kc * 128);
            float4* dst = (float4*)&WUc[0][0];
            dst[tid] = src[tid];
            dst[tid + 256] = src[tid + 256];
            dst[tid + 512] = src[tid + 512];
            dst[tid + 768] = src[tid + 768];
        }
        __syncthreads();
#pragma unroll 4
        for (int kk = 0; kk < 32; kk++) {
            float4 a = *(const float4*)&AT[kk][rg * 4];
            float4 w = *(const float4*)&WUc[kk][cg * 4];
            acc0.x += a.x * w.x; acc0.y += a.x * w.y; acc0.z += a.x * w.z; acc0.w += a.x * w.w;
            acc1.x += a.y * w.x; acc1.y += a.y * w.y; acc1.z += a.y * w.z; acc1.w += a.y * w.w;
            acc2.x += a.z * w.x; acc2.y += a.z * w.y; acc2.z += a.z * w.z; acc2.w += a.z * w.w;
            acc3.x += a.w * w.x; acc3.y += a.w * w.y; acc3.z += a.w * w.z; acc3.w += a.w * w.w;
        }
        __syncthreads();
    }
    int r0 = rbase + rg * 4;
    if (r0 + 0 < N_) *(float4*)(AHt + (size_t)(r0 + 0) * F0_ + cg * 4) = acc0;
    if (r0 + 1 < N_) *(float4*)(AHt + (size_t)(r0 + 1) * F0_ + cg * 4) = acc1;
    if (r0 + 2 < N_) *(float4*)(AHt + (size_t)(r0 + 2) * F0_ + cg * 4) = acc2;
    if (r0 + 3 < N_) *(float4*)(AHt + (size_t)(r0 + 3) * F0_ + cg * 4) = acc3;
}

// ---------- out[e] = P[flat_src] + Q[flat_trg] ----------
__global__ void k_final(const float* __restrict__ PQ, const int* __restrict__ et,
                        const int* __restrict__ es, const int* __restrict__ eg,
                        float* __restrict__ out) {
    int gid = blockIdx.x * 256 + threadIdx.x;  // e*16 + q
    if (gid >= E_ * 16) return;
    int e = gid >> 4, q = gid & 15;
    int t = et[e];
    const float4 a = *(const float4*)(PQ + ((size_t)(t * N_ + es[e])) * 128 + q * 4);
    const float4 b = *(const float4*)(PQ + ((size_t)(t * N_ + eg[e])) * 128 + 64 + q * 4);
    float4 o = {a.x + b.x, a.y + b.y, a.z + b.z, a.w + b.w};
    *(float4*)(out + (size_t)e * 64 + q * 4) = o;
}

__global__ void k_wfin(const float* __restrict__ W_seq, float* __restrict__ out) {
    int gid = blockIdx.x * 256 + threadIdx.x;
    out[(size_t)E_ * 64 + gid] = W_seq[(size_t)7 * 16384 + gid];
}

// ---------- launch ----------
extern "C" void kernel_launch(void* const* d_in, const int* in_sizes, int n_in,
                              void* d_out, int out_size, void* d_ws, size_t ws_size,
                              hipStream_t stream) {
    const float* X = (const float*)d_in[0];
    const int* A_rows = (const int*)d_in[1];
    const int* A_cols = (const int*)d_in[2];
    const float* A_val = (const float*)d_in[3];
    const int* edge_time = (const int*)d_in[4];
    const int* edge_src = (const int*)d_in[5];
    const int* edge_trg = (const int*)d_in[6];
    const float* p = (const float*)d_in[7];
    const float* W_Z = (const float*)d_in[8];
    const float* U_Z = (const float*)d_in[9];
    const float* B_Z = (const float*)d_in[10];
    const float* W_R = (const float*)d_in[11];
    const float* U_R = (const float*)d_in[12];
    const float* B_R = (const float*)d_in[13];
    const float* W_H = (const float*)d_in[14];
    const float* U_H = (const float*)d_in[15];
    const float* B_H = (const float*)d_in[16];
    const float* W_init = (const float*)d_in[17];
    const float* U = (const float*)d_in[18];
    float* out = (float*)d_out;

    char* ws = (char*)d_ws;
    size_t off = 0;
    auto take = [&](size_t bytes) {
        char* ptr = ws + off;
        off = (off + bytes + 255) & ~(size_t)255;
        return (void*)ptr;
    };
    float* AH = (float*)take((size_t)T_ * N_ * F0_ * 4);   // 204.8 MB, becomes PQ in place
    int2* ecv = (int2*)take((size_t)T_ * NNZ_ * 8);        // 51.2 MB
    float* yv = (float*)take((size_t)T_ * N_ * 4);
    int* row_ptr = (int*)take((size_t)T_ * (N_ + 1) * 4);
    int* cnt = (int*)take((size_t)T_ * N_ * 4);
    int* fill = (int*)take((size_t)T_ * N_ * 4);
    int* bsum = (int*)take((size_t)T_ * SCB * 4);
    float* p_hat = (float*)take(512);
    float* topv = (float*)take((size_t)T_ * K_ * 4);
    int* topidx = (int*)take((size_t)T_ * K_ * 4);
    float* Z = (float*)take((size_t)T_ * F0_ * K_ * 4);
    float* AZb = (float*)take((size_t)T_ * 16384 * 4);
    float* ARb = (float*)take((size_t)T_ * 16384 * 4);
    float* AHb = (float*)take((size_t)T_ * 16384 * 4);
    float* W_seq = (float*)take((size_t)T_ * 16384 * 4);
    float* WU = (float*)take((size_t)T_ * 16384 * 4);
    unsigned* Xh = (unsigned*)take((size_t)T_ * N_ * 64 * 4);  // 102.4 MB bf16 X (last!)
    bool use_bf16 = (off <= ws_size);

    hipMemsetAsync(cnt, 0, (size_t)T_ * N_ * 4, stream);
    hipMemsetAsync(fill, 0, (size_t)T_ * N_ * 4, stream);

    k_phat<<<1, 128, 0, stream>>>(p, p_hat);
    k_y<<<(T_ * N_ * 64) / 256, 256, 0, stream>>>(X, p_hat, yv, use_bf16 ? Xh : nullptr);
    k_topk<<<T_, 1024, 0, stream>>>(yv, topv, topidx);
    k_z<<<(T_ * F0_ * K_) / 256, 256, 0, stream>>>(X, topv, topidx, Z);
    k_az<<<(3 * T_ * 16384) / 256, 256, 0, stream>>>(W_Z, W_R, W_H, B_Z, B_R, B_H, Z,
                                                     AZb, ARb, AHb);
    k_hist<<<(T_ * NNZ_ + 255) / 256, 256, 0, stream>>>(A_rows, cnt);
    {
        dim3 g(SCB, T_);
        k_s1<<<g, 1024, 0, stream>>>(cnt, row_ptr, bsum);
        k_s2<<<1, 512, 0, stream>>>(bsum, row_ptr);
        k_s3<<<g, 1024, 0, stream>>>(row_ptr, bsum);
    }
    k_scatter<<<(T_ * NNZ_ + 255) / 256, 256, 0, stream>>>(A_rows, A_cols, A_val, row_ptr,
                                                           fill, ecv);
    if (use_bf16)
        k_spmm<<<(T_ * N_ * 64) / 256, 256, 0, stream>>>(Xh, row_ptr, ecv, AH);
    else
        k_spmm_f32<<<(T_ * N_ * 64) / 256, 256, 0, stream>>>(X, row_ptr, ecv, AH);
    for (int t = 0; t < T_; t++) {
        const float* Wprev = (t == 0) ? W_init : (W_seq + (size_t)(t - 1) * 16384);
        k_gru<<<64, 256, 0, stream>>>(AZb + (size_t)t * 16384, ARb + (size_t)t * 16384,
                                      AHb + (size_t)t * 16384, U_Z, U_R, U_H, Wprev,
                                      W_seq + (size_t)t * 16384);
    }
    k_wu<<<T_ * 128, 128, 0, stream>>>(W_seq, U, WU);
    {
        dim3 g((N_ + 31) / 32, T_);
        k_pq<<<g, 256, 0, stream>>>(AH, WU);
    }
    k_final<<<(E_ * 16) / 256, 256, 0, stream>>>(AH, edge_time, edge_src, edge_trg, out);
    k_wfin<<<(F0_ * H0_) / 256, 256, 0, stream>>>(W_seq, out);
}

// Round 5
// 1371.050 us; speedup vs baseline: 7.7629x; 1.1488x over previous
//
#include <hip/hip_runtime.h>
#include <math.h>

#define T_ 8
#define N_ 50000
#define F0_ 128
#define H0_ 128
#define H1_ 64
#define NNZ_ 800000
#define E_ 1000000
#define K_ 128
#define CAP_ 3072
#define SCB 49  // ceil(N_/1024)

// ---------- helpers ----------
__device__ inline unsigned ford(float f) {
    unsigned b = __float_as_uint(f);
    return (b & 0x80000000u) ? ~b : (b | 0x80000000u);
}
__device__ inline float funord(unsigned u) {
    unsigned b = (u & 0x80000000u) ? (u & 0x7fffffffu) : ~u;
    return __uint_as_float(b);
}
__device__ inline unsigned bfr(float f) {  // fp32 -> bf16 bits (RNE)
    unsigned u = __float_as_uint(f);
    return (u + 0x7fffu + ((u >> 16) & 1u)) >> 16;
}
__device__ inline unsigned bfpack(float lo, float hi) { return bfr(lo) | (bfr(hi) << 16); }
__device__ inline float bflo(unsigned u) { return __uint_as_float(u << 16); }
__device__ inline float bfhi(unsigned u) { return __uint_as_float(u & 0xffff0000u); }

// ---------- p_hat = p / ||p|| ----------
__global__ void k_phat(const float* p, float* p_hat) {
    __shared__ float s[128];
    int i = threadIdx.x;
    float v = p[i];
    s[i] = v * v;
    __syncthreads();
    for (int off = 64; off > 0; off >>= 1) {
        if (i < off) s[i] += s[i + off];
        __syncthreads();
    }
    p_hat[i] = v / sqrtf(s[0]);
}

// ---------- y = X @ p_hat (wave/row) + optional bf16 copy of X ----------
__global__ void k_y(const float* __restrict__ X, const float* __restrict__ p_hat,
                    float* __restrict__ y, unsigned* __restrict__ Xh) {
    int gid = blockIdx.x * 256 + threadIdx.x;
    int wave = gid >> 6, lane = gid & 63;
    if (wave >= T_ * N_) return;
    const float2* xr = (const float2*)(X + (size_t)wave * F0_);
    float2 a = xr[lane];
    if (Xh) Xh[(size_t)wave * 64 + lane] = bfpack(a.x, a.y);
    float2 ph = ((const float2*)p_hat)[lane];
    float acc = a.x * ph.x + a.y * ph.y;
#pragma unroll
    for (int off = 32; off > 0; off >>= 1) acc += __shfl_down(acc, off);
    if (lane == 0) y[wave] = acc;
}

// ---------- exact top-128 per t: 2-level radix select + exact rank ----------
__global__ __launch_bounds__(1024) void k_topk(const float* __restrict__ y,
                                               float* __restrict__ topv,
                                               int* __restrict__ topidx) {
    int t = blockIdx.x;
    const float* yt = y + (size_t)t * N_;
    __shared__ int hist[256];
    __shared__ int sb1, sAbove, sP, scand;
    __shared__ unsigned cu[CAP_];
    __shared__ int cidx[CAP_];
    int tid = threadIdx.x;

    if (tid < 256) hist[tid] = 0;
    __syncthreads();
    for (int i = tid; i < N_; i += 1024) {
        unsigned u = ford(yt[i]);
        atomicAdd(&hist[u >> 24], 1);
    }
    __syncthreads();
    if (tid == 0) {
        int acc = 0, b = 255;
        for (; b >= 0; b--) { acc += hist[b]; if (acc >= K_) break; }
        sb1 = b;
        sAbove = acc - hist[b];
    }
    __syncthreads();
    int b1 = sb1;
    if (tid < 256) hist[tid] = 0;
    __syncthreads();
    for (int i = tid; i < N_; i += 1024) {
        unsigned u = ford(yt[i]);
        if ((int)(u >> 24) == b1) atomicAdd(&hist[(u >> 16) & 255], 1);
    }
    __syncthreads();
    if (tid == 0) {
        int acc = sAbove, b = 255;
        for (; b >= 0; b--) { acc += hist[b]; if (acc >= K_) break; }
        sP = (b1 << 8) | b;
        scand = 0;
    }
    __syncthreads();
    unsigned P = (unsigned)sP;
    for (int i = tid; i < N_; i += 1024) {
        unsigned u = ford(yt[i]);
        if ((u >> 16) >= P) {
            int pos = atomicAdd(&scand, 1);
            if (pos < CAP_) { cu[pos] = u; cidx[pos] = i; }
        }
    }
    __syncthreads();
    int C = min(scand, CAP_);
    for (int c = tid; c < C; c += 1024) {
        unsigned uc = cu[c];
        int ic = cidx[c];
        int rank = 0;
        for (int o = 0; o < C; o++) {
            unsigned uo = cu[o];
            rank += (uo > uc) || (uo == uc && cidx[o] < ic);
        }
        if (rank < K_) {
            topv[t * K_ + rank] = funord(uc);
            topidx[t * K_ + rank] = ic;
        }
    }
}

// ---------- Z[t][f][j] = X[t][idx[j]][f] * topv[j] ----------
__global__ void k_z(const float* __restrict__ X, const float* __restrict__ topv,
                    const int* __restrict__ topidx, float* __restrict__ Z) {
    int gid = blockIdx.x * 256 + threadIdx.x;  // t*16384 + f*128 + j
    if (gid >= T_ * F0_ * K_) return;
    int j = gid & 127;
    int f = (gid >> 7) & 127;
    int t = gid >> 14;
    int idx = topidx[t * K_ + j];
    float v = topv[t * K_ + j];
    Z[gid] = X[((size_t)(t * N_ + idx)) * F0_ + f] * v;
}

// ---------- A_g[t] = W_g @ Z_t + B_g  (g in {Z,R,H}, all t parallel) ----------
__global__ void k_az(const float* __restrict__ WZ, const float* __restrict__ WR,
                     const float* __restrict__ WH, const float* __restrict__ BZ,
                     const float* __restrict__ BR, const float* __restrict__ BH,
                     const float* __restrict__ Z, float* __restrict__ AZ,
                     float* __restrict__ AR, float* __restrict__ AHo) {
    int gid = blockIdx.x * 256 + threadIdx.x;  // g*131072 + t*16384 + i*128 + j
    int j = gid & 127;
    int i = (gid >> 7) & 127;
    int t = (gid >> 14) & 7;
    int g = gid >> 17;
    const float* W = (g == 0) ? WZ : (g == 1) ? WR : WH;
    const float* B = (g == 0) ? BZ : (g == 1) ? BR : BH;
    float* Ao = (g == 0) ? AZ : (g == 1) ? AR : AHo;
    const float* Zt = Z + (size_t)t * 16384;
    float acc = B[i * 128 + j];
    for (int k = 0; k < 128; k++) acc += W[i * 128 + k] * Zt[k * 128 + j];
    Ao[(size_t)(t * 128 + i) * 128 + j] = acc;
}

// ---------- CSR build ----------
__global__ void k_hist(const int* __restrict__ A_rows, int* __restrict__ cnt) {
    int gid = blockIdx.x * 256 + threadIdx.x;
    if (gid >= T_ * NNZ_) return;
    int t = gid / NNZ_;
    atomicAdd(&cnt[t * N_ + A_rows[gid]], 1);
}

// 3-phase scan: per-block scan -> block-sum scan -> add offsets
__global__ __launch_bounds__(1024) void k_s1(const int* __restrict__ cnt,
                                             int* __restrict__ row_ptr,
                                             int* __restrict__ bsum) {
    int t = blockIdx.y, b = blockIdx.x;
    int tid = threadIdx.x;
    int i = b * 1024 + tid;
    __shared__ int buf[1024];
    int v = (i < N_) ? cnt[(size_t)t * N_ + i] : 0;
    buf[tid] = v;
    __syncthreads();
    for (int off = 1; off < 1024; off <<= 1) {
        int x = (tid >= off) ? buf[tid - off] : 0;
        __syncthreads();
        buf[tid] += x;
        __syncthreads();
    }
    if (i < N_) row_ptr[(size_t)t * (N_ + 1) + i] = buf[tid] - v;  // block-local exclusive
    if (tid == 1023) bsum[t * SCB + b] = buf[1023];
}

__global__ void k_s2(int* __restrict__ bsum, int* __restrict__ row_ptr) {
    int w = threadIdx.x >> 6, lane = threadIdx.x & 63;  // 8 waves, one per t
    int orig = (lane < SCB) ? bsum[w * SCB + lane] : 0;
    int v = orig;
#pragma unroll
    for (int off = 1; off < 64; off <<= 1) {
        int x = __shfl_up(v, off);
        if (lane >= off) v += x;
    }
    if (lane < SCB) bsum[w * SCB + lane] = v - orig;  // exclusive block offset
    if (lane == 63) row_ptr[(size_t)w * (N_ + 1) + N_] = v;  // total
}

__global__ __launch_bounds__(1024) void k_s3(int* __restrict__ row_ptr,
                                             const int* __restrict__ bsum) {
    int t = blockIdx.y, b = blockIdx.x;
    int i = b * 1024 + threadIdx.x;
    if (i < N_) row_ptr[(size_t)t * (N_ + 1) + i] += bsum[t * SCB + b];
}

__global__ void k_scatter(const int* __restrict__ A_rows, const int* __restrict__ A_cols,
                          const float* __restrict__ A_val, const int* __restrict__ row_ptr,
                          int* __restrict__ fill, int2* __restrict__ ecv) {
    int gid = blockIdx.x * 256 + threadIdx.x;
    if (gid >= T_ * NNZ_) return;
    int t = gid / NNZ_;
    int r = A_rows[gid];
    int pos = row_ptr[(size_t)t * (N_ + 1) + r] + atomicAdd(&fill[t * N_ + r], 1);
    ecv[(size_t)t * NNZ_ + pos] = make_int2(A_cols[gid], __float_as_int(A_val[gid]));
}

// ---------- SpMM (bf16 gather, 8 loads in flight): AH[t][r] = sum val*Xh[t][col] ----------
__global__ void k_spmm(const unsigned* __restrict__ Xh, const int* __restrict__ row_ptr,
                       const int2* __restrict__ ecv, float* __restrict__ AH) {
    int gid = blockIdx.x * 256 + threadIdx.x;
    int wave = gid >> 6, lane = gid & 63;
    if (wave >= T_ * N_) return;
    int t = wave / N_;
    int r = wave - t * N_;
    int s = row_ptr[(size_t)t * (N_ + 1) + r];
    int len = row_ptr[(size_t)t * (N_ + 1) + r + 1] - s;
    const unsigned* Xt = Xh + (size_t)t * N_ * 64 + lane;
    const int2* ev = ecv + (size_t)t * NNZ_;
    float2 acc = {0.f, 0.f};
    for (int base = 0; base < len; base += 64) {
        int nn = min(64, len - base);
        int2 my = {0, 0};
        if (base + lane < len) my = ev[s + base + lane];
        int q = 0;
        for (; q + 8 <= nn; q += 8) {
            int c0 = __shfl(my.x, q + 0); float v0 = __int_as_float(__shfl(my.y, q + 0));
            int c1 = __shfl(my.x, q + 1); float v1 = __int_as_float(__shfl(my.y, q + 1));
            int c2 = __shfl(my.x, q + 2); float v2 = __int_as_float(__shfl(my.y, q + 2));
            int c3 = __shfl(my.x, q + 3); float v3 = __int_as_float(__shfl(my.y, q + 3));
            int c4 = __shfl(my.x, q + 4); float v4 = __int_as_float(__shfl(my.y, q + 4));
            int c5 = __shfl(my.x, q + 5); float v5 = __int_as_float(__shfl(my.y, q + 5));
            int c6 = __shfl(my.x, q + 6); float v6 = __int_as_float(__shfl(my.y, q + 6));
            int c7 = __shfl(my.x, q + 7); float v7 = __int_as_float(__shfl(my.y, q + 7));
            unsigned x0 = Xt[(size_t)c0 * 64];
            unsigned x1 = Xt[(size_t)c1 * 64];
            unsigned x2 = Xt[(size_t)c2 * 64];
            unsigned x3 = Xt[(size_t)c3 * 64];
            unsigned x4 = Xt[(size_t)c4 * 64];
            unsigned x5 = Xt[(size_t)c5 * 64];
            unsigned x6 = Xt[(size_t)c6 * 64];
            unsigned x7 = Xt[(size_t)c7 * 64];
            acc.x += v0 * bflo(x0); acc.y += v0 * bfhi(x0);
            acc.x += v1 * bflo(x1); acc.y += v1 * bfhi(x1);
            acc.x += v2 * bflo(x2); acc.y += v2 * bfhi(x2);
            acc.x += v3 * bflo(x3); acc.y += v3 * bfhi(x3);
            acc.x += v4 * bflo(x4); acc.y += v4 * bfhi(x4);
            acc.x += v5 * bflo(x5); acc.y += v5 * bfhi(x5);
            acc.x += v6 * bflo(x6); acc.y += v6 * bfhi(x6);
            acc.x += v7 * bflo(x7); acc.y += v7 * bfhi(x7);
        }
        for (; q < nn; q++) {
            int c = __shfl(my.x, q);
            float v = __int_as_float(__shfl(my.y, q));
            unsigned xp = Xt[(size_t)c * 64];
            acc.x += v * bflo(xp);
            acc.y += v * bfhi(xp);
        }
    }
    ((float2*)AH)[(size_t)wave * 64 + lane] = acc;
}

// fallback (fp32 gather) if workspace can't hold Xh
__global__ void k_spmm_f32(const float* __restrict__ X, const int* __restrict__ row_ptr,
                           const int2* __restrict__ ecv, float* __restrict__ AH) {
    int gid = blockIdx.x * 256 + threadIdx.x;
    int wave = gid >> 6, lane = gid & 63;
    if (wave >= T_ * N_) return;
    int t = wave / N_;
    int r = wave - t * N_;
    int s = row_ptr[(size_t)t * (N_ + 1) + r];
    int len = row_ptr[(size_t)t * (N_ + 1) + r + 1] - s;
    const float2* Xt = (const float2*)(X + (size_t)t * N_ * F0_);
    const int2* ev = ecv + (size_t)t * NNZ_;
    float2 acc = {0.f, 0.f};
    for (int base = 0; base < len; base += 64) {
        int nn = min(64, len - base);
        int2 my = {0, 0};
        if (base + lane < len) my = ev[s + base + lane];
        for (int q = 0; q < nn; q++) {
            int c = __shfl(my.x, q);
            float v = __int_as_float(__shfl(my.y, q));
            float2 x = Xt[(size_t)c * 64 + lane];
            acc.x += v * x.x;
            acc.y += v * x.y;
        }
    }
    ((float2*)AH)[(size_t)wave * 64 + lane] = acc;
}

// ---------- fused GRU step (column-separable): one launch per t ----------
__global__ __launch_bounds__(256) void k_gru(const float* __restrict__ AZt,
                                             const float* __restrict__ ARt,
                                             const float* __restrict__ AHt,
                                             const float* __restrict__ UZ,
                                             const float* __restrict__ UR,
                                             const float* __restrict__ UH,
                                             const float* __restrict__ Wprev,
                                             float* __restrict__ Wnew) {
    __shared__ float RWs[128][2];
    int jl = threadIdx.x >> 7;  // 0..1
    int i = threadIdx.x & 127;
    int j = blockIdx.x * 2 + jl;
    int gid = i * 128 + j;
    float az = AZt[gid], ar = ARt[gid];
    for (int k = 0; k < 128; k++) {
        float w = Wprev[k * 128 + j];  // wave-uniform broadcast
        az += UZ[i * 128 + k] * w;
        ar += UR[i * 128 + k] * w;
    }
    float zg = 1.f / (1.f + expf(-az));
    float rg = 1.f / (1.f + expf(-ar));
    RWs[i][jl] = rg * Wprev[gid];
    __syncthreads();
    float acc = AHt[gid];
    for (int k = 0; k < 128; k++) acc += UH[i * 128 + k] * RWs[k][jl];
    float ht = tanhf(acc);
    float w0 = Wprev[gid];
    Wnew[gid] = (1.f - zg) * w0 + zg * ht;
}

// ---------- WU[t][k][h2] = sum_m W_t[k][m] * U[(h2<64? m : 128+m)][h2&63] ----------
__global__ void k_wu(const float* __restrict__ W_seq, const float* __restrict__ U,
                     float* __restrict__ WU) {
    int blk = blockIdx.x;  // t*128 + k
    int t = blk >> 7, k = blk & 127;
    int h2 = threadIdx.x;
    const float* Wt = W_seq + (size_t)t * 16384;
    int h = h2 & 63;
    const float* Ub = U + (h2 < 64 ? 0 : 128 * 64);
    float acc = 0.f;
    for (int m = 0; m < 128; m++) acc += Wt[k * 128 + m] * Ub[m * 64 + h];
    WU[((size_t)t * 128 + k) * 128 + h2] = acc;
}

// ---------- PQ = AH @ WU[t], bf16-packed into PQh (reuses Xh buffer) ----------
__global__ __launch_bounds__(256) void k_pq(const float* __restrict__ AH,
                                            const float* __restrict__ WU,
                                            unsigned* __restrict__ PQh) {
    __shared__ float AT[32][36];
    __shared__ float WUc[32][128];
    int t = blockIdx.y;
    int rbase = blockIdx.x * 32;
    int tid = threadIdx.x;
    const float* wu = WU + (size_t)t * 16384;
    const float* AHt = AH + (size_t)t * N_ * F0_;
    unsigned* PQt = PQh + (size_t)t * N_ * 64;
    int cg = tid & 31;
    int rg = tid >> 5;
    float4 acc0 = {0.f, 0.f, 0.f, 0.f};
    float4 acc1 = {0.f, 0.f, 0.f, 0.f};
    float4 acc2 = {0.f, 0.f, 0.f, 0.f};
    float4 acc3 = {0.f, 0.f, 0.f, 0.f};
    int srow = tid >> 3;
    int sk4 = (tid & 7) * 4;
    for (int kc = 0; kc < 128; kc += 32) {
        {
            float4 v = {0.f, 0.f, 0.f, 0.f};
            int r = rbase + srow;
            if (r < N_) v = *(const float4*)(AHt + (size_t)r * F0_ + kc + sk4);
            AT[sk4 + 0][srow] = v.x;
            AT[sk4 + 1][srow] = v.y;
            AT[sk4 + 2][srow] = v.z;
            AT[sk4 + 3][srow] = v.w;
        }
        {
            const float4* src = (const float4*)(wu + (size_t)kc * 128);
            float4* dst = (float4*)&WUc[0][0];
            dst[tid] = src[tid];
            dst[tid + 256] = src[tid + 256];
            dst[tid + 512] = src[tid + 512];
            dst[tid + 768] = src[tid + 768];
        }
        __syncthreads();
#pragma unroll 4
        for (int kk = 0; kk < 32; kk++) {
            float4 a = *(const float4*)&AT[kk][rg * 4];
            float4 w = *(const float4*)&WUc[kk][cg * 4];
            acc0.x += a.x * w.x; acc0.y += a.x * w.y; acc0.z += a.x * w.z; acc0.w += a.x * w.w;
            acc1.x += a.y * w.x; acc1.y += a.y * w.y; acc1.z += a.y * w.z; acc1.w += a.y * w.w;
            acc2.x += a.z * w.x; acc2.y += a.z * w.y; acc2.z += a.z * w.z; acc2.w += a.z * w.w;
            acc3.x += a.w * w.x; acc3.y += a.w * w.y; acc3.z += a.w * w.z; acc3.w += a.w * w.w;
        }
        __syncthreads();
    }
    int r0 = rbase + rg * 4;
    if (r0 + 0 < N_) {
        uint2 o = {bfpack(acc0.x, acc0.y), bfpack(acc0.z, acc0.w)};
        *(uint2*)(PQt + (size_t)(r0 + 0) * 64 + cg * 2) = o;
    }
    if (r0 + 1 < N_) {
        uint2 o = {bfpack(acc1.x, acc1.y), bfpack(acc1.z, acc1.w)};
        *(uint2*)(PQt + (size_t)(r0 + 1) * 64 + cg * 2) = o;
    }
    if (r0 + 2 < N_) {
        uint2 o = {bfpack(acc2.x, acc2.y), bfpack(acc2.z, acc2.w)};
        *(uint2*)(PQt + (size_t)(r0 + 2) * 64 + cg * 2) = o;
    }
    if (r0 + 3 < N_) {
        uint2 o = {bfpack(acc3.x, acc3.y), bfpack(acc3.z, acc3.w)};
        *(uint2*)(PQt + (size_t)(r0 + 3) * 64 + cg * 2) = o;
    }
}

// fp32 in-place fallback
__global__ __launch_bounds__(256) void k_pq_f32(float* __restrict__ AH,
                                                const float* __restrict__ WU) {
    __shared__ float AT[32][36];
    __shared__ float WUc[32][128];
    int t = blockIdx.y;
    int rbase = blockIdx.x * 32;
    int tid = threadIdx.x;
    const float* wu = WU + (size_t)t * 16384;
    float* AHt = AH + (size_t)t * N_ * F0_;
    int cg = tid & 31;
    int rg = tid >> 5;
    float4 acc0 = {0.f, 0.f, 0.f, 0.f};
    float4 acc1 = {0.f, 0.f, 0.f, 0.f};
    float4 acc2 = {0.f, 0.f, 0.f, 0.f};
    float4 acc3 = {0.f, 0.f, 0.f, 0.f};
    int srow = tid >> 3;
    int sk4 = (tid & 7) * 4;
    for (int kc = 0; kc < 128; kc += 32) {
        {
            float4 v = {0.f, 0.f, 0.f, 0.f};
            int r = rbase + srow;
            if (r < N_) v = *(const float4*)(AHt + (size_t)r * F0_ + kc + sk4);
            AT[sk4 + 0][srow] = v.x;
            AT[sk4 + 1][srow] = v.y;
            AT[sk4 + 2][srow] = v.z;
            AT[sk4 + 3][srow] = v.w;
        }
        {
            const float4* src = (const float4*)(wu + (size_t)kc * 128);
            float4* dst = (float4*)&WUc[0][0];
            dst[tid] = src[tid];
            dst[tid + 256] = src[tid + 256];
            dst[tid + 512] = src[tid + 512];
            dst[tid + 768] = src[tid + 768];
        }
        __syncthreads();
#pragma unroll 4
        for (int kk = 0; kk < 32; kk++) {
            float4 a = *(const float4*)&AT[kk][rg * 4];
            float4 w = *(const float4*)&WUc[kk][cg * 4];
            acc0.x += a.x * w.x; acc0.y += a.x * w.y; acc0.z += a.x * w.z; acc0.w += a.x * w.w;
            acc1.x += a.y * w.x; acc1.y += a.y * w.y; acc1.z += a.y * w.z; acc1.w += a.y * w.w;
            acc2.x += a.z * w.x; acc2.y += a.z * w.y; acc2.z += a.z * w.z; acc2.w += a.z * w.w;
            acc3.x += a.w * w.x; acc3.y += a.w * w.y; acc3.z += a.w * w.z; acc3.w += a.w * w.w;
        }
        __syncthreads();
    }
    int r0 = rbase + rg * 4;
    if (r0 + 0 < N_) *(float4*)(AHt + (size_t)(r0 + 0) * F0_ + cg * 4) = acc0;
    if (r0 + 1 < N_) *(float4*)(AHt + (size_t)(r0 + 1) * F0_ + cg * 4) = acc1;
    if (r0 + 2 < N_) *(float4*)(AHt + (size_t)(r0 + 2) * F0_ + cg * 4) = acc2;
    if (r0 + 3 < N_) *(float4*)(AHt + (size_t)(r0 + 3) * F0_ + cg * 4) = acc3;
}

// ---------- out[e] = P[flat_src] + Q[flat_trg]  (bf16 PQh) ----------
__global__ void k_final(const unsigned* __restrict__ PQh, const int* __restrict__ et,
                        const int* __restrict__ es, const int* __restrict__ eg,
                        float* __restrict__ out) {
    int gid = blockIdx.x * 256 + threadIdx.x;  // e*16 + q
    if (gid >= E_ * 16) return;
    int e = gid >> 4, q = gid & 15;
    int t = et[e];
    const uint2 a = *(const uint2*)(PQh + ((size_t)(t * N_ + es[e])) * 64 + q * 2);
    const uint2 b = *(const uint2*)(PQh + ((size_t)(t * N_ + eg[e])) * 64 + 32 + q * 2);
    float4 o;
    o.x = bflo(a.x) + bflo(b.x);
    o.y = bfhi(a.x) + bfhi(b.x);
    o.z = bflo(a.y) + bflo(b.y);
    o.w = bfhi(a.y) + bfhi(b.y);
    *(float4*)(out + (size_t)e * 64 + q * 4) = o;
}

__global__ void k_final_f32(const float* __restrict__ PQ, const int* __restrict__ et,
                            const int* __restrict__ es, const int* __restrict__ eg,
                            float* __restrict__ out) {
    int gid = blockIdx.x * 256 + threadIdx.x;  // e*16 + q
    if (gid >= E_ * 16) return;
    int e = gid >> 4, q = gid & 15;
    int t = et[e];
    const float4 a = *(const float4*)(PQ + ((size_t)(t * N_ + es[e])) * 128 + q * 4);
    const float4 b = *(const float4*)(PQ + ((size_t)(t * N_ + eg[e])) * 128 + 64 + q * 4);
    float4 o = {a.x + b.x, a.y + b.y, a.z + b.z, a.w + b.w};
    *(float4*)(out + (size_t)e * 64 + q * 4) = o;
}

__global__ void k_wfin(const float* __restrict__ W_seq, float* __restrict__ out) {
    int gid = blockIdx.x * 256 + threadIdx.x;
    out[(size_t)E_ * 64 + gid] = W_seq[(size_t)7 * 16384 + gid];
}

// ---------- launch ----------
extern "C" void kernel_launch(void* const* d_in, const int* in_sizes, int n_in,
                              void* d_out, int out_size, void* d_ws, size_t ws_size,
                              hipStream_t stream) {
    const float* X = (const float*)d_in[0];
    const int* A_rows = (const int*)d_in[1];
    const int* A_cols = (const int*)d_in[2];
    const float* A_val = (const float*)d_in[3];
    const int* edge_time = (const int*)d_in[4];
    const int* edge_src = (const int*)d_in[5];
    const int* edge_trg = (const int*)d_in[6];
    const float* p = (const float*)d_in[7];
    const float* W_Z = (const float*)d_in[8];
    const float* U_Z = (const float*)d_in[9];
    const float* B_Z = (const float*)d_in[10];
    const float* W_R = (const float*)d_in[11];
    const float* U_R = (const float*)d_in[12];
    const float* B_R = (const float*)d_in[13];
    const float* W_H = (const float*)d_in[14];
    const float* U_H = (const float*)d_in[15];
    const float* B_H = (const float*)d_in[16];
    const float* W_init = (const float*)d_in[17];
    const float* U = (const float*)d_in[18];
    float* out = (float*)d_out;

    char* ws = (char*)d_ws;
    size_t off = 0;
    auto take = [&](size_t bytes) {
        char* ptr = ws + off;
        off = (off + bytes + 255) & ~(size_t)255;
        return (void*)ptr;
    };
    float* AH = (float*)take((size_t)T_ * N_ * F0_ * 4);   // 204.8 MB
    int2* ecv = (int2*)take((size_t)T_ * NNZ_ * 8);        // 51.2 MB
    float* yv = (float*)take((size_t)T_ * N_ * 4);
    int* row_ptr = (int*)take((size_t)T_ * (N_ + 1) * 4);
    int* cnt = (int*)take((size_t)T_ * N_ * 4);
    int* fill = (int*)take((size_t)T_ * N_ * 4);
    int* bsum = (int*)take((size_t)T_ * SCB * 4);
    float* p_hat = (float*)take(512);
    float* topv = (float*)take((size_t)T_ * K_ * 4);
    int* topidx = (int*)take((size_t)T_ * K_ * 4);
    float* Z = (float*)take((size_t)T_ * F0_ * K_ * 4);
    float* AZb = (float*)take((size_t)T_ * 16384 * 4);
    float* ARb = (float*)take((size_t)T_ * 16384 * 4);
    float* AHb = (float*)take((size_t)T_ * 16384 * 4);
    float* W_seq = (float*)take((size_t)T_ * 16384 * 4);
    float* WU = (float*)take((size_t)T_ * 16384 * 4);
    unsigned* Xh = (unsigned*)take((size_t)T_ * N_ * 64 * 4);  // 102.4 MB; reused as PQh
    bool use_bf16 = (off <= ws_size);
    unsigned* PQh = Xh;  // Xh retired after k_spmm; reuse as bf16 PQ

    hipMemsetAsync(cnt, 0, (size_t)T_ * N_ * 4, stream);
    hipMemsetAsync(fill, 0, (size_t)T_ * N_ * 4, stream);

    k_phat<<<1, 128, 0, stream>>>(p, p_hat);
    k_y<<<(T_ * N_ * 64) / 256, 256, 0, stream>>>(X, p_hat, yv, use_bf16 ? Xh : nullptr);
    k_topk<<<T_, 1024, 0, stream>>>(yv, topv, topidx);
    k_z<<<(T_ * F0_ * K_) / 256, 256, 0, stream>>>(X, topv, topidx, Z);
    k_az<<<(3 * T_ * 16384) / 256, 256, 0, stream>>>(W_Z, W_R, W_H, B_Z, B_R, B_H, Z,
                                                     AZb, ARb, AHb);
    k_hist<<<(T_ * NNZ_ + 255) / 256, 256, 0, stream>>>(A_rows, cnt);
    {
        dim3 g(SCB, T_);
        k_s1<<<g, 1024, 0, stream>>>(cnt, row_ptr, bsum);
        k_s2<<<1, 512, 0, stream>>>(bsum, row_ptr);
        k_s3<<<g, 1024, 0, stream>>>(row_ptr, bsum);
    }
    k_scatter<<<(T_ * NNZ_ + 255) / 256, 256, 0, stream>>>(A_rows, A_cols, A_val, row_ptr,
                                                           fill, ecv);
    if (use_bf16)
        k_spmm<<<(T_ * N_ * 64) / 256, 256, 0, stream>>>(Xh, row_ptr, ecv, AH);
    else
        k_spmm_f32<<<(T_ * N_ * 64) / 256, 256, 0, stream>>>(X, row_ptr, ecv, AH);
    for (int t = 0; t < T_; t++) {
        const float* Wprev = (t == 0) ? W_init : (W_seq + (size_t)(t - 1) * 16384);
        k_gru<<<64, 256, 0, stream>>>(AZb + (size_t)t * 16384, ARb + (size_t)t * 16384,
                                      AHb + (size_t)t * 16384, U_Z, U_R, U_H, Wprev,
                                      W_seq + (size_t)t * 16384);
    }
    k_wu<<<T_ * 128, 128, 0, stream>>>(W_seq, U, WU);
    {
        dim3 g((N_ + 31) / 32, T_);
        if (use_bf16) {
            k_pq<<<g, 256, 0, stream>>>(AH, WU, PQh);
            k_final<<<(E_ * 16) / 256, 256, 0, stream>>>(PQh, edge_time, edge_src,
                                                         edge_trg, out);
        } else {
            k_pq_f32<<<g, 256, 0, stream>>>(AH, WU);
            k_final_f32<<<(E_ * 16) / 256, 256, 0, stream>>>(AH, edge_time, edge_src,
                                                             edge_trg, out);
        }
    }
    k_wfin<<<(F0_ * H0_) / 256, 256, 0, stream>>>(W_seq, out);
}

// Round 6
// 1204.461 us; speedup vs baseline: 8.8366x; 1.1383x over previous
//
#include <hip/hip_runtime.h>
#include <math.h>

#define T_ 8
#define N_ 50000
#define F0_ 128
#define H0_ 128
#define H1_ 64
#define NNZ_ 800000
#define E_ 1000000
#define K_ 128
#define CAP_ 3072
#define SCB 49   // ceil(N_/1024)
#define NB 391   // ceil(N_/128) buckets of 128 rows
#define BCH 8192 // edges per k_binA block

// ---------- helpers ----------
__device__ inline unsigned ford(float f) {
    unsigned b = __float_as_uint(f);
    return (b & 0x80000000u) ? ~b : (b | 0x80000000u);
}
__device__ inline float funord(unsigned u) {
    unsigned b = (u & 0x80000000u) ? (u & 0x7fffffffu) : ~u;
    return __uint_as_float(b);
}
__device__ inline unsigned bfr(float f) {  // fp32 -> bf16 bits (RNE)
    unsigned u = __float_as_uint(f);
    return (u + 0x7fffu + ((u >> 16) & 1u)) >> 16;
}
__device__ inline unsigned bfpack(float lo, float hi) { return bfr(lo) | (bfr(hi) << 16); }
__device__ inline float bflo(unsigned u) { return __uint_as_float(u << 16); }
__device__ inline float bfhi(unsigned u) { return __uint_as_float(u & 0xffff0000u); }

// ---------- p_hat = p / ||p|| ----------
__global__ void k_phat(const float* p, float* p_hat) {
    __shared__ float s[128];
    int i = threadIdx.x;
    float v = p[i];
    s[i] = v * v;
    __syncthreads();
    for (int off = 64; off > 0; off >>= 1) {
        if (i < off) s[i] += s[i + off];
        __syncthreads();
    }
    p_hat[i] = v / sqrtf(s[0]);
}

// ---------- y = X @ p_hat (wave/row) + bf16 copy of X ----------
__global__ void k_y(const float* __restrict__ X, const float* __restrict__ p_hat,
                    float* __restrict__ y, unsigned* __restrict__ Xh) {
    int gid = blockIdx.x * 256 + threadIdx.x;
    int wave = gid >> 6, lane = gid & 63;
    if (wave >= T_ * N_) return;
    const float2* xr = (const float2*)(X + (size_t)wave * F0_);
    float2 a = xr[lane];
    if (Xh) Xh[(size_t)wave * 64 + lane] = bfpack(a.x, a.y);
    float2 ph = ((const float2*)p_hat)[lane];
    float acc = a.x * ph.x + a.y * ph.y;
#pragma unroll
    for (int off = 32; off > 0; off >>= 1) acc += __shfl_down(acc, off);
    if (lane == 0) y[wave] = acc;
}

// ---------- exact top-128 per t: 2-level radix select + exact rank ----------
__global__ __launch_bounds__(1024) void k_topk(const float* __restrict__ y,
                                               float* __restrict__ topv,
                                               int* __restrict__ topidx) {
    int t = blockIdx.x;
    const float* yt = y + (size_t)t * N_;
    __shared__ int hist[256];
    __shared__ int sb1, sAbove, sP, scand;
    __shared__ unsigned cu[CAP_];
    __shared__ int cidx[CAP_];
    int tid = threadIdx.x;

    if (tid < 256) hist[tid] = 0;
    __syncthreads();
    for (int i = tid; i < N_; i += 1024) {
        unsigned u = ford(yt[i]);
        atomicAdd(&hist[u >> 24], 1);
    }
    __syncthreads();
    if (tid == 0) {
        int acc = 0, b = 255;
        for (; b >= 0; b--) { acc += hist[b]; if (acc >= K_) break; }
        sb1 = b;
        sAbove = acc - hist[b];
    }
    __syncthreads();
    int b1 = sb1;
    if (tid < 256) hist[tid] = 0;
    __syncthreads();
    for (int i = tid; i < N_; i += 1024) {
        unsigned u = ford(yt[i]);
        if ((int)(u >> 24) == b1) atomicAdd(&hist[(u >> 16) & 255], 1);
    }
    __syncthreads();
    if (tid == 0) {
        int acc = sAbove, b = 255;
        for (; b >= 0; b--) { acc += hist[b]; if (acc >= K_) break; }
        sP = (b1 << 8) | b;
        scand = 0;
    }
    __syncthreads();
    unsigned P = (unsigned)sP;
    for (int i = tid; i < N_; i += 1024) {
        unsigned u = ford(yt[i]);
        if ((u >> 16) >= P) {
            int pos = atomicAdd(&scand, 1);
            if (pos < CAP_) { cu[pos] = u; cidx[pos] = i; }
        }
    }
    __syncthreads();
    int C = min(scand, CAP_);
    for (int c = tid; c < C; c += 1024) {
        unsigned uc = cu[c];
        int ic = cidx[c];
        int rank = 0;
        for (int o = 0; o < C; o++) {
            unsigned uo = cu[o];
            rank += (uo > uc) || (uo == uc && cidx[o] < ic);
        }
        if (rank < K_) {
            topv[t * K_ + rank] = funord(uc);
            topidx[t * K_ + rank] = ic;
        }
    }
}

// ---------- Z[t][f][j] = X[t][idx[j]][f] * topv[j] ----------
__global__ void k_z(const float* __restrict__ X, const float* __restrict__ topv,
                    const int* __restrict__ topidx, float* __restrict__ Z) {
    int gid = blockIdx.x * 256 + threadIdx.x;  // t*16384 + f*128 + j
    if (gid >= T_ * F0_ * K_) return;
    int j = gid & 127;
    int f = (gid >> 7) & 127;
    int t = gid >> 14;
    int idx = topidx[t * K_ + j];
    float v = topv[t * K_ + j];
    Z[gid] = X[((size_t)(t * N_ + idx)) * F0_ + f] * v;
}

// ---------- A_g[t] = W_g @ Z_t + B_g  (g in {Z,R,H}, all t parallel) ----------
__global__ void k_az(const float* __restrict__ WZ, const float* __restrict__ WR,
                     const float* __restrict__ WH, const float* __restrict__ BZ,
                     const float* __restrict__ BR, const float* __restrict__ BH,
                     const float* __restrict__ Z, float* __restrict__ AZ,
                     float* __restrict__ AR, float* __restrict__ AHo) {
    int gid = blockIdx.x * 256 + threadIdx.x;  // g*131072 + t*16384 + i*128 + j
    int j = gid & 127;
    int i = (gid >> 7) & 127;
    int t = (gid >> 14) & 7;
    int g = gid >> 17;
    const float* W = (g == 0) ? WZ : (g == 1) ? WR : WH;
    const float* B = (g == 0) ? BZ : (g == 1) ? BR : BH;
    float* Ao = (g == 0) ? AZ : (g == 1) ? AR : AHo;
    const float* Zt = Z + (size_t)t * 16384;
    float acc = B[i * 128 + j];
    for (int k = 0; k < 128; k++) acc += W[i * 128 + k] * Zt[k * 128 + j];
    Ao[(size_t)(t * 128 + i) * 128 + j] = acc;
}

// ---------- CSR build: row histogram ----------
__global__ void k_hist(const int* __restrict__ A_rows, int* __restrict__ cnt) {
    int gid = blockIdx.x * 256 + threadIdx.x;
    if (gid >= T_ * NNZ_) return;
    int t = gid / NNZ_;
    atomicAdd(&cnt[t * N_ + A_rows[gid]], 1);
}

// 3-phase scan: per-block scan -> block-sum scan -> add offsets
__global__ __launch_bounds__(1024) void k_s1(const int* __restrict__ cnt,
                                             int* __restrict__ row_ptr,
                                             int* __restrict__ bsum) {
    int t = blockIdx.y, b = blockIdx.x;
    int tid = threadIdx.x;
    int i = b * 1024 + tid;
    __shared__ int buf[1024];
    int v = (i < N_) ? cnt[(size_t)t * N_ + i] : 0;
    buf[tid] = v;
    __syncthreads();
    for (int off = 1; off < 1024; off <<= 1) {
        int x = (tid >= off) ? buf[tid - off] : 0;
        __syncthreads();
        buf[tid] += x;
        __syncthreads();
    }
    if (i < N_) row_ptr[(size_t)t * (N_ + 1) + i] = buf[tid] - v;  // block-local exclusive
    if (tid == 1023) bsum[t * SCB + b] = buf[1023];
}

__global__ void k_s2(int* __restrict__ bsum, int* __restrict__ row_ptr) {
    int w = threadIdx.x >> 6, lane = threadIdx.x & 63;  // 8 waves, one per t
    int orig = (lane < SCB) ? bsum[w * SCB + lane] : 0;
    int v = orig;
#pragma unroll
    for (int off = 1; off < 64; off <<= 1) {
        int x = __shfl_up(v, off);
        if (lane >= off) v += x;
    }
    if (lane < SCB) bsum[w * SCB + lane] = v - orig;  // exclusive block offset
    if (lane == 63) row_ptr[(size_t)w * (N_ + 1) + N_] = v;  // total
}

__global__ __launch_bounds__(1024) void k_s3(int* __restrict__ row_ptr,
                                             const int* __restrict__ bsum) {
    int t = blockIdx.y, b = blockIdx.x;
    int i = b * 1024 + threadIdx.x;
    if (i < N_) row_ptr[(size_t)t * (N_ + 1) + i] += bsum[t * SCB + b];
}

// ---------- Pass A: bin edges into 128-row buckets, group-contiguous writes ----------
// meta = col(16b) | rlo(7b)<<16 | b(9b)<<23 ; sentinel 0xFFFFFFFF (b=511 impossible)
__global__ __launch_bounds__(512) void k_binA(const int* __restrict__ A_rows,
                                              const int* __restrict__ A_cols,
                                              const float* __restrict__ A_val,
                                              const int* __restrict__ row_ptr,
                                              int* __restrict__ bfill,
                                              int2* __restrict__ ebuck) {
    __shared__ int cnt[NB];
    __shared__ int gbase[NB];
    __shared__ int rbase[NB];
    int t = blockIdx.y, ci = blockIdx.x;
    int tid = threadIdx.x;
    for (int i = tid; i < NB; i += 512) cnt[i] = 0;
    __syncthreads();
    unsigned meta[16];
    float val[16];
    int lrank[16];
    int e0 = ci * BCH;
#pragma unroll
    for (int k = 0; k < 16; k++) {
        int idx = e0 + tid + k * 512;
        meta[k] = 0xFFFFFFFFu;
        val[k] = 0.f;
        lrank[k] = 0;
        if (idx < NNZ_) {
            int r = A_rows[(size_t)t * NNZ_ + idx];
            int c = A_cols[(size_t)t * NNZ_ + idx];
            val[k] = A_val[(size_t)t * NNZ_ + idx];
            int b = r >> 7, rlo = r & 127;
            meta[k] = (unsigned)c | ((unsigned)rlo << 16) | ((unsigned)b << 23);
            lrank[k] = atomicAdd(&cnt[b], 1);
        }
    }
    __syncthreads();
    for (int b = tid; b < NB; b += 512) {
        int n = cnt[b];
        gbase[b] = n ? atomicAdd(&bfill[t * NB + b], n) : 0;
        rbase[b] = row_ptr[(size_t)t * (N_ + 1) + (b << 7)];
    }
    __syncthreads();
#pragma unroll
    for (int k = 0; k < 16; k++) {
        if (meta[k] != 0xFFFFFFFFu) {
            int b = meta[k] >> 23;
            ebuck[(size_t)t * NNZ_ + rbase[b] + gbase[b] + lrank[k]] =
                make_int2((int)meta[k], __float_as_int(val[k]));
        }
    }
}

// ---------- Pass B: sort each bucket into final CSR order (exact row_ptr offsets) ----------
__global__ __launch_bounds__(256) void k_bsort(const int* __restrict__ row_ptr,
                                               const int2* __restrict__ ebuck,
                                               int2* __restrict__ ecv) {
    __shared__ int lbase[128];
    __shared__ int lfill[128];
    int t = blockIdx.y, b = blockIdx.x;
    int tid = threadIdx.x;
    int r0 = b << 7;
    int nrows = min(128, N_ - r0);
    const int* rp = row_ptr + (size_t)t * (N_ + 1);
    int base = rp[r0];
    if (tid < nrows) {
        lbase[tid] = rp[r0 + tid] - base;
        lfill[tid] = 0;
    }
    __syncthreads();
    int n = rp[r0 + nrows] - base;
    const int2* src = ebuck + (size_t)t * NNZ_ + base;
    int2* dst = ecv + (size_t)t * NNZ_ + base;
    for (int i = tid; i < n; i += 256) {
        int2 e = src[i];
        int rlo = (e.x >> 16) & 127;
        int col = e.x & 0xFFFF;
        int pos = lbase[rlo] + atomicAdd(&lfill[rlo], 1);
        dst[pos] = make_int2(col, e.y);
    }
}

// ---------- SpMM (bf16 gather, 8 loads in flight): AH[t][r] = sum val*Xh[t][col] ----------
__global__ void k_spmm(const unsigned* __restrict__ Xh, const int* __restrict__ row_ptr,
                       const int2* __restrict__ ecv, float* __restrict__ AH) {
    int gid = blockIdx.x * 256 + threadIdx.x;
    int wave = gid >> 6, lane = gid & 63;
    if (wave >= T_ * N_) return;
    int t = wave / N_;
    int r = wave - t * N_;
    int s = row_ptr[(size_t)t * (N_ + 1) + r];
    int len = row_ptr[(size_t)t * (N_ + 1) + r + 1] - s;
    const unsigned* Xt = Xh + (size_t)t * N_ * 64 + lane;
    const int2* ev = ecv + (size_t)t * NNZ_;
    float2 acc = {0.f, 0.f};
    for (int base = 0; base < len; base += 64) {
        int nn = min(64, len - base);
        int2 my = {0, 0};
        if (base + lane < len) my = ev[s + base + lane];
        int q = 0;
        for (; q + 8 <= nn; q += 8) {
            int c0 = __shfl(my.x, q + 0); float v0 = __int_as_float(__shfl(my.y, q + 0));
            int c1 = __shfl(my.x, q + 1); float v1 = __int_as_float(__shfl(my.y, q + 1));
            int c2 = __shfl(my.x, q + 2); float v2 = __int_as_float(__shfl(my.y, q + 2));
            int c3 = __shfl(my.x, q + 3); float v3 = __int_as_float(__shfl(my.y, q + 3));
            int c4 = __shfl(my.x, q + 4); float v4 = __int_as_float(__shfl(my.y, q + 4));
            int c5 = __shfl(my.x, q + 5); float v5 = __int_as_float(__shfl(my.y, q + 5));
            int c6 = __shfl(my.x, q + 6); float v6 = __int_as_float(__shfl(my.y, q + 6));
            int c7 = __shfl(my.x, q + 7); float v7 = __int_as_float(__shfl(my.y, q + 7));
            unsigned x0 = Xt[(size_t)c0 * 64];
            unsigned x1 = Xt[(size_t)c1 * 64];
            unsigned x2 = Xt[(size_t)c2 * 64];
            unsigned x3 = Xt[(size_t)c3 * 64];
            unsigned x4 = Xt[(size_t)c4 * 64];
            unsigned x5 = Xt[(size_t)c5 * 64];
            unsigned x6 = Xt[(size_t)c6 * 64];
            unsigned x7 = Xt[(size_t)c7 * 64];
            acc.x += v0 * bflo(x0); acc.y += v0 * bfhi(x0);
            acc.x += v1 * bflo(x1); acc.y += v1 * bfhi(x1);
            acc.x += v2 * bflo(x2); acc.y += v2 * bfhi(x2);
            acc.x += v3 * bflo(x3); acc.y += v3 * bfhi(x3);
            acc.x += v4 * bflo(x4); acc.y += v4 * bfhi(x4);
            acc.x += v5 * bflo(x5); acc.y += v5 * bfhi(x5);
            acc.x += v6 * bflo(x6); acc.y += v6 * bfhi(x6);
            acc.x += v7 * bflo(x7); acc.y += v7 * bfhi(x7);
        }
        for (; q < nn; q++) {
            int c = __shfl(my.x, q);
            float v = __int_as_float(__shfl(my.y, q));
            unsigned xp = Xt[(size_t)c * 64];
            acc.x += v * bflo(xp);
            acc.y += v * bfhi(xp);
        }
    }
    ((float2*)AH)[(size_t)wave * 64 + lane] = acc;
}

// fallback (fp32 gather) if workspace can't hold Xh
__global__ void k_spmm_f32(const float* __restrict__ X, const int* __restrict__ row_ptr,
                           const int2* __restrict__ ecv, float* __restrict__ AH) {
    int gid = blockIdx.x * 256 + threadIdx.x;
    int wave = gid >> 6, lane = gid & 63;
    if (wave >= T_ * N_) return;
    int t = wave / N_;
    int r = wave - t * N_;
    int s = row_ptr[(size_t)t * (N_ + 1) + r];
    int len = row_ptr[(size_t)t * (N_ + 1) + r + 1] - s;
    const float2* Xt = (const float2*)(X + (size_t)t * N_ * F0_);
    const int2* ev = ecv + (size_t)t * NNZ_;
    float2 acc = {0.f, 0.f};
    for (int base = 0; base < len; base += 64) {
        int nn = min(64, len - base);
        int2 my = {0, 0};
        if (base + lane < len) my = ev[s + base + lane];
        for (int q = 0; q < nn; q++) {
            int c = __shfl(my.x, q);
            float v = __int_as_float(__shfl(my.y, q));
            float2 x = Xt[(size_t)c * 64 + lane];
            acc.x += v * x.x;
            acc.y += v * x.y;
        }
    }
    ((float2*)AH)[(size_t)wave * 64 + lane] = acc;
}

// ---------- fused GRU step (column-separable): one launch per t ----------
__global__ __launch_bounds__(256) void k_gru(const float* __restrict__ AZt,
                                             const float* __restrict__ ARt,
                                             const float* __restrict__ AHt,
                                             const float* __restrict__ UZ,
                                             const float* __restrict__ UR,
                                             const float* __restrict__ UH,
                                             const float* __restrict__ Wprev,
                                             float* __restrict__ Wnew) {
    __shared__ float RWs[128][2];
    int jl = threadIdx.x >> 7;  // 0..1
    int i = threadIdx.x & 127;
    int j = blockIdx.x * 2 + jl;
    int gid = i * 128 + j;
    float az = AZt[gid], ar = ARt[gid];
    for (int k = 0; k < 128; k++) {
        float w = Wprev[k * 128 + j];  // wave-uniform broadcast
        az += UZ[i * 128 + k] * w;
        ar += UR[i * 128 + k] * w;
    }
    float zg = 1.f / (1.f + expf(-az));
    float rg = 1.f / (1.f + expf(-ar));
    RWs[i][jl] = rg * Wprev[gid];
    __syncthreads();
    float acc = AHt[gid];
    for (int k = 0; k < 128; k++) acc += UH[i * 128 + k] * RWs[k][jl];
    float ht = tanhf(acc);
    float w0 = Wprev[gid];
    Wnew[gid] = (1.f - zg) * w0 + zg * ht;
}

// ---------- WU[t][k][h2] = sum_m W_t[k][m] * U[(h2<64? m : 128+m)][h2&63] ----------
__global__ void k_wu(const float* __restrict__ W_seq, const float* __restrict__ U,
                     float* __restrict__ WU) {
    int blk = blockIdx.x;  // t*128 + k
    int t = blk >> 7, k = blk & 127;
    int h2 = threadIdx.x;
    const float* Wt = W_seq + (size_t)t * 16384;
    int h = h2 & 63;
    const float* Ub = U + (h2 < 64 ? 0 : 128 * 64);
    float acc = 0.f;
    for (int m = 0; m < 128; m++) acc += Wt[k * 128 + m] * Ub[m * 64 + h];
    WU[((size_t)t * 128 + k) * 128 + h2] = acc;
}

// ---------- PQ = AH @ WU[t], bf16-packed into PQh (reuses Xh buffer) ----------
__global__ __launch_bounds__(256) void k_pq(const float* __restrict__ AH,
                                            const float* __restrict__ WU,
                                            unsigned* __restrict__ PQh) {
    __shared__ float AT[32][36];
    __shared__ float WUc[32][128];
    int t = blockIdx.y;
    int rbase = blockIdx.x * 32;
    int tid = threadIdx.x;
    const float* wu = WU + (size_t)t * 16384;
    const float* AHt = AH + (size_t)t * N_ * F0_;
    unsigned* PQt = PQh + (size_t)t * N_ * 64;
    int cg = tid & 31;
    int rg = tid >> 5;
    float4 acc0 = {0.f, 0.f, 0.f, 0.f};
    float4 acc1 = {0.f, 0.f, 0.f, 0.f};
    float4 acc2 = {0.f, 0.f, 0.f, 0.f};
    float4 acc3 = {0.f, 0.f, 0.f, 0.f};
    int srow = tid >> 3;
    int sk4 = (tid & 7) * 4;
    for (int kc = 0; kc < 128; kc += 32) {
        {
            float4 v = {0.f, 0.f, 0.f, 0.f};
            int r = rbase + srow;
            if (r < N_) v = *(const float4*)(AHt + (size_t)r * F0_ + kc + sk4);
            AT[sk4 + 0][srow] = v.x;
            AT[sk4 + 1][srow] = v.y;
            AT[sk4 + 2][srow] = v.z;
            AT[sk4 + 3][srow] = v.w;
        }
        {
            const float4* src = (const float4*)(wu + (size_t)kc * 128);
            float4* dst = (float4*)&WUc[0][0];
            dst[tid] = src[tid];
            dst[tid + 256] = src[tid + 256];
            dst[tid + 512] = src[tid + 512];
            dst[tid + 768] = src[tid + 768];
        }
        __syncthreads();
#pragma unroll 4
        for (int kk = 0; kk < 32; kk++) {
            float4 a = *(const float4*)&AT[kk][rg * 4];
            float4 w = *(const float4*)&WUc[kk][cg * 4];
            acc0.x += a.x * w.x; acc0.y += a.x * w.y; acc0.z += a.x * w.z; acc0.w += a.x * w.w;
            acc1.x += a.y * w.x; acc1.y += a.y * w.y; acc1.z += a.y * w.z; acc1.w += a.y * w.w;
            acc2.x += a.z * w.x; acc2.y += a.z * w.y; acc2.z += a.z * w.z; acc2.w += a.z * w.w;
            acc3.x += a.w * w.x; acc3.y += a.w * w.y; acc3.z += a.w * w.z; acc3.w += a.w * w.w;
        }
        __syncthreads();
    }
    int r0 = rbase + rg * 4;
    if (r0 + 0 < N_) {
        uint2 o = {bfpack(acc0.x, acc0.y), bfpack(acc0.z, acc0.w)};
        *(uint2*)(PQt + (size_t)(r0 + 0) * 64 + cg * 2) = o;
    }
    if (r0 + 1 < N_) {
        uint2 o = {bfpack(acc1.x, acc1.y), bfpack(acc1.z, acc1.w)};
        *(uint2*)(PQt + (size_t)(r0 + 1) * 64 + cg * 2) = o;
    }
    if (r0 + 2 < N_) {
        uint2 o = {bfpack(acc2.x, acc2.y), bfpack(acc2.z, acc2.w)};
        *(uint2*)(PQt + (size_t)(r0 + 2) * 64 + cg * 2) = o;
    }
    if (r0 + 3 < N_) {
        uint2 o = {bfpack(acc3.x, acc3.y), bfpack(acc3.z, acc3.w)};
        *(uint2*)(PQt + (size_t)(r0 + 3) * 64 + cg * 2) = o;
    }
}

// fp32 in-place fallback
__global__ __launch_bounds__(256) void k_pq_f32(float* __restrict__ AH,
                                                const float* __restrict__ WU) {
    __shared__ float AT[32][36];
    __shared__ float WUc[32][128];
    int t = blockIdx.y;
    int rbase = blockIdx.x * 32;
    int tid = threadIdx.x;
    const float* wu = WU + (size_t)t * 16384;
    float* AHt = AH + (size_t)t * N_ * F0_;
    int cg = tid & 31;
    int rg = tid >> 5;
    float4 acc0 = {0.f, 0.f, 0.f, 0.f};
    float4 acc1 = {0.f, 0.f, 0.f, 0.f};
    float4 acc2 = {0.f, 0.f, 0.f, 0.f};
    float4 acc3 = {0.f, 0.f, 0.f, 0.f};
    int srow = tid >> 3;
    int sk4 = (tid & 7) * 4;
    for (int kc = 0; kc < 128; kc += 32) {
        {
            float4 v = {0.f, 0.f, 0.f, 0.f};
            int r = rbase + srow;
            if (r < N_) v = *(const float4*)(AHt + (size_t)r * F0_ + kc + sk4);
            AT[sk4 + 0][srow] = v.x;
            AT[sk4 + 1][srow] = v.y;
            AT[sk4 + 2][srow] = v.z;
            AT[sk4 + 3][srow] = v.w;
        }
        {
            const float4* src = (const float4*)(wu + (size_t)kc * 128);
            float4* dst = (float4*)&WUc[0][0];
            dst[tid] = src[tid];
            dst[tid + 256] = src[tid + 256];
            dst[tid + 512] = src[tid + 512];
            dst[tid + 768] = src[tid + 768];
        }
        __syncthreads();
#pragma unroll 4
        for (int kk = 0; kk < 32; kk++) {
            float4 a = *(const float4*)&AT[kk][rg * 4];
            float4 w = *(const float4*)&WUc[kk][cg * 4];
            acc0.x += a.x * w.x; acc0.y += a.x * w.y; acc0.z += a.x * w.z; acc0.w += a.x * w.w;
            acc1.x += a.y * w.x; acc1.y += a.y * w.y; acc1.z += a.y * w.z; acc1.w += a.y * w.w;
            acc2.x += a.z * w.x; acc2.y += a.z * w.y; acc2.z += a.z * w.z; acc2.w += a.z * w.w;
            acc3.x += a.w * w.x; acc3.y += a.w * w.y; acc3.z += a.w * w.z; acc3.w += a.w * w.w;
        }
        __syncthreads();
    }
    int r0 = rbase + rg * 4;
    if (r0 + 0 < N_) *(float4*)(AHt + (size_t)(r0 + 0) * F0_ + cg * 4) = acc0;
    if (r0 + 1 < N_) *(float4*)(AHt + (size_t)(r0 + 1) * F0_ + cg * 4) = acc1;
    if (r0 + 2 < N_) *(float4*)(AHt + (size_t)(r0 + 2) * F0_ + cg * 4) = acc2;
    if (r0 + 3 < N_) *(float4*)(AHt + (size_t)(r0 + 3) * F0_ + cg * 4) = acc3;
}

// ---------- out[e] = P[flat_src] + Q[flat_trg]  (bf16 PQh) ----------
__global__ void k_final(const unsigned* __restrict__ PQh, const int* __restrict__ et,
                        const int* __restrict__ es, const int* __restrict__ eg,
                        float* __restrict__ out) {
    int gid = blockIdx.x * 256 + threadIdx.x;  // e*16 + q
    if (gid >= E_ * 16) return;
    int e = gid >> 4, q = gid & 15;
    int t = et[e];
    const uint2 a = *(const uint2*)(PQh + ((size_t)(t * N_ + es[e])) * 64 + q * 2);
    const uint2 b = *(const uint2*)(PQh + ((size_t)(t * N_ + eg[e])) * 64 + 32 + q * 2);
    float4 o;
    o.x = bflo(a.x) + bflo(b.x);
    o.y = bfhi(a.x) + bfhi(b.x);
    o.z = bflo(a.y) + bflo(b.y);
    o.w = bfhi(a.y) + bfhi(b.y);
    *(float4*)(out + (size_t)e * 64 + q * 4) = o;
}

__global__ void k_final_f32(const float* __restrict__ PQ, const int* __restrict__ et,
                            const int* __restrict__ es, const int* __restrict__ eg,
                            float* __restrict__ out) {
    int gid = blockIdx.x * 256 + threadIdx.x;  // e*16 + q
    if (gid >= E_ * 16) return;
    int e = gid >> 4, q = gid & 15;
    int t = et[e];
    const float4 a = *(const float4*)(PQ + ((size_t)(t * N_ + es[e])) * 128 + q * 4);
    const float4 b = *(const float4*)(PQ + ((size_t)(t * N_ + eg[e])) * 128 + 64 + q * 4);
    float4 o = {a.x + b.x, a.y + b.y, a.z + b.z, a.w + b.w};
    *(float4*)(out + (size_t)e * 64 + q * 4) = o;
}

__global__ void k_wfin(const float* __restrict__ W_seq, float* __restrict__ out) {
    int gid = blockIdx.x * 256 + threadIdx.x;
    out[(size_t)E_ * 64 + gid] = W_seq[(size_t)7 * 16384 + gid];
}

// ---------- launch ----------
extern "C" void kernel_launch(void* const* d_in, const int* in_sizes, int n_in,
                              void* d_out, int out_size, void* d_ws, size_t ws_size,
                              hipStream_t stream) {
    const float* X = (const float*)d_in[0];
    const int* A_rows = (const int*)d_in[1];
    const int* A_cols = (const int*)d_in[2];
    const float* A_val = (const float*)d_in[3];
    const int* edge_time = (const int*)d_in[4];
    const int* edge_src = (const int*)d_in[5];
    const int* edge_trg = (const int*)d_in[6];
    const float* p = (const float*)d_in[7];
    const float* W_Z = (const float*)d_in[8];
    const float* U_Z = (const float*)d_in[9];
    const float* B_Z = (const float*)d_in[10];
    const float* W_R = (const float*)d_in[11];
    const float* U_R = (const float*)d_in[12];
    const float* B_R = (const float*)d_in[13];
    const float* W_H = (const float*)d_in[14];
    const float* U_H = (const float*)d_in[15];
    const float* B_H = (const float*)d_in[16];
    const float* W_init = (const float*)d_in[17];
    const float* U = (const float*)d_in[18];
    float* out = (float*)d_out;

    char* ws = (char*)d_ws;
    size_t off = 0;
    auto take = [&](size_t bytes) {
        char* ptr = ws + off;
        off = (off + bytes + 255) & ~(size_t)255;
        return (void*)ptr;
    };
    float* AH = (float*)take((size_t)T_ * N_ * F0_ * 4);   // 204.8 MB (ebuck overlays)
    int2* ecv = (int2*)take((size_t)T_ * NNZ_ * 8);        // 51.2 MB final CSR
    float* yv = (float*)take((size_t)T_ * N_ * 4);
    int* row_ptr = (int*)take((size_t)T_ * (N_ + 1) * 4);
    int* cnt = (int*)take((size_t)T_ * N_ * 4);
    int* bfill = (int*)take((size_t)T_ * NB * 4);
    int* bsum = (int*)take((size_t)T_ * SCB * 4);
    float* p_hat = (float*)take(512);
    float* topv = (float*)take((size_t)T_ * K_ * 4);
    int* topidx = (int*)take((size_t)T_ * K_ * 4);
    float* Z = (float*)take((size_t)T_ * F0_ * K_ * 4);
    float* AZb = (float*)take((size_t)T_ * 16384 * 4);
    float* ARb = (float*)take((size_t)T_ * 16384 * 4);
    float* AHb = (float*)take((size_t)T_ * 16384 * 4);
    float* W_seq = (float*)take((size_t)T_ * 16384 * 4);
    float* WU = (float*)take((size_t)T_ * 16384 * 4);
    unsigned* Xh = (unsigned*)take((size_t)T_ * N_ * 64 * 4);  // 102.4 MB; reused as PQh
    bool use_bf16 = (off <= ws_size);
    unsigned* PQh = Xh;        // Xh retired after k_spmm; reuse as bf16 PQ
    int2* ebuck = (int2*)AH;   // AH live range starts at k_spmm; ebuck dead by then

    hipMemsetAsync(cnt, 0, (size_t)T_ * N_ * 4, stream);
    hipMemsetAsync(bfill, 0, (size_t)T_ * NB * 4, stream);

    k_phat<<<1, 128, 0, stream>>>(p, p_hat);
    k_y<<<(T_ * N_ * 64) / 256, 256, 0, stream>>>(X, p_hat, yv, use_bf16 ? Xh : nullptr);
    k_topk<<<T_, 1024, 0, stream>>>(yv, topv, topidx);
    k_z<<<(T_ * F0_ * K_) / 256, 256, 0, stream>>>(X, topv, topidx, Z);
    k_az<<<(3 * T_ * 16384) / 256, 256, 0, stream>>>(W_Z, W_R, W_H, B_Z, B_R, B_H, Z,
                                                     AZb, ARb, AHb);
    k_hist<<<(T_ * NNZ_ + 255) / 256, 256, 0, stream>>>(A_rows, cnt);
    {
        dim3 g(SCB, T_);
        k_s1<<<g, 1024, 0, stream>>>(cnt, row_ptr, bsum);
        k_s2<<<1, 512, 0, stream>>>(bsum, row_ptr);
        k_s3<<<g, 1024, 0, stream>>>(row_ptr, bsum);
    }
    {
        dim3 gA((NNZ_ + BCH - 1) / BCH, T_);  // 98 x 8
        k_binA<<<gA, 512, 0, stream>>>(A_rows, A_cols, A_val, row_ptr, bfill, ebuck);
        dim3 gB(NB, T_);                      // 391 x 8
        k_bsort<<<gB, 256, 0, stream>>>(row_ptr, ebuck, ecv);
    }
    if (use_bf16)
        k_spmm<<<(T_ * N_ * 64) / 256, 256, 0, stream>>>(Xh, row_ptr, ecv, AH);
    else
        k_spmm_f32<<<(T_ * N_ * 64) / 256, 256, 0, stream>>>(X, row_ptr, ecv, AH);
    for (int t = 0; t < T_; t++) {
        const float* Wprev = (t == 0) ? W_init : (W_seq + (size_t)(t - 1) * 16384);
        k_gru<<<64, 256, 0, stream>>>(AZb + (size_t)t * 16384, ARb + (size_t)t * 16384,
                                      AHb + (size_t)t * 16384, U_Z, U_R, U_H, Wprev,
                                      W_seq + (size_t)t * 16384);
    }
    k_wu<<<T_ * 128, 128, 0, stream>>>(W_seq, U, WU);
    {
        dim3 g((N_ + 31) / 32, T_);
        if (use_bf16) {
            k_pq<<<g, 256, 0, stream>>>(AH, WU, PQh);
            k_final<<<(E_ * 16) / 256, 256, 0, stream>>>(PQh, edge_time, edge_src,
                                                         edge_trg, out);
        } else {
            k_pq_f32<<<g, 256, 0, stream>>>(AH, WU);
            k_final_f32<<<(E_ * 16) / 256, 256, 0, stream>>>(AH, edge_time, edge_src,
                                                             edge_trg, out);
        }
    }
    k_wfin<<<(F0_ * H0_) / 256, 256, 0, stream>>>(W_seq, out);
}

// Round 7
// 966.526 us; speedup vs baseline: 11.0119x; 1.2462x over previous
//
#include <hip/hip_runtime.h>
#include <math.h>

#define T_ 8
#define N_ 50000
#define F0_ 128
#define H0_ 128
#define H1_ 64
#define NNZ_ 800000
#define E_ 1000000
#define K_ 128
#define CAP_ 3072
#define NB 391   // ceil(N_/128) buckets of 128 rows
#define BCH 8192 // edges per chunk block

// ---------- helpers ----------
__device__ inline unsigned ford(float f) {
    unsigned b = __float_as_uint(f);
    return (b & 0x80000000u) ? ~b : (b | 0x80000000u);
}
__device__ inline float funord(unsigned u) {
    unsigned b = (u & 0x80000000u) ? (u & 0x7fffffffu) : ~u;
    return __uint_as_float(b);
}
__device__ inline unsigned bfr(float f) {  // fp32 -> bf16 bits (RNE)
    unsigned u = __float_as_uint(f);
    return (u + 0x7fffu + ((u >> 16) & 1u)) >> 16;
}
__device__ inline unsigned bfpack(float lo, float hi) { return bfr(lo) | (bfr(hi) << 16); }
__device__ inline float bflo(unsigned u) { return __uint_as_float(u << 16); }
__device__ inline float bfhi(unsigned u) { return __uint_as_float(u & 0xffff0000u); }

// ---------- p_hat = p / ||p|| ----------
__global__ void k_phat(const float* p, float* p_hat) {
    __shared__ float s[128];
    int i = threadIdx.x;
    float v = p[i];
    s[i] = v * v;
    __syncthreads();
    for (int off = 64; off > 0; off >>= 1) {
        if (i < off) s[i] += s[i + off];
        __syncthreads();
    }
    p_hat[i] = v / sqrtf(s[0]);
}

// ---------- y = X @ p_hat (wave/row) + bf16 copy of X ----------
__global__ void k_y(const float* __restrict__ X, const float* __restrict__ p_hat,
                    float* __restrict__ y, unsigned* __restrict__ Xh) {
    int gid = blockIdx.x * 256 + threadIdx.x;
    int wave = gid >> 6, lane = gid & 63;
    if (wave >= T_ * N_) return;
    const float2* xr = (const float2*)(X + (size_t)wave * F0_);
    float2 a = xr[lane];
    if (Xh) Xh[(size_t)wave * 64 + lane] = bfpack(a.x, a.y);
    float2 ph = ((const float2*)p_hat)[lane];
    float acc = a.x * ph.x + a.y * ph.y;
#pragma unroll
    for (int off = 32; off > 0; off >>= 1) acc += __shfl_down(acc, off);
    if (lane == 0) y[wave] = acc;
}

// ---------- exact top-128 per t: 2-level radix select + exact rank ----------
__global__ __launch_bounds__(1024) void k_topk(const float* __restrict__ y,
                                               float* __restrict__ topv,
                                               int* __restrict__ topidx) {
    int t = blockIdx.x;
    const float* yt = y + (size_t)t * N_;
    __shared__ int hist[256];
    __shared__ int sb1, sAbove, sP, scand;
    __shared__ unsigned cu[CAP_];
    __shared__ int cidx[CAP_];
    int tid = threadIdx.x;

    if (tid < 256) hist[tid] = 0;
    __syncthreads();
    for (int i = tid; i < N_; i += 1024) {
        unsigned u = ford(yt[i]);
        atomicAdd(&hist[u >> 24], 1);
    }
    __syncthreads();
    if (tid == 0) {
        int acc = 0, b = 255;
        for (; b >= 0; b--) { acc += hist[b]; if (acc >= K_) break; }
        sb1 = b;
        sAbove = acc - hist[b];
    }
    __syncthreads();
    int b1 = sb1;
    if (tid < 256) hist[tid] = 0;
    __syncthreads();
    for (int i = tid; i < N_; i += 1024) {
        unsigned u = ford(yt[i]);
        if ((int)(u >> 24) == b1) atomicAdd(&hist[(u >> 16) & 255], 1);
    }
    __syncthreads();
    if (tid == 0) {
        int acc = sAbove, b = 255;
        for (; b >= 0; b--) { acc += hist[b]; if (acc >= K_) break; }
        sP = (b1 << 8) | b;
        scand = 0;
    }
    __syncthreads();
    unsigned P = (unsigned)sP;
    for (int i = tid; i < N_; i += 1024) {
        unsigned u = ford(yt[i]);
        if ((u >> 16) >= P) {
            int pos = atomicAdd(&scand, 1);
            if (pos < CAP_) { cu[pos] = u; cidx[pos] = i; }
        }
    }
    __syncthreads();
    int C = min(scand, CAP_);
    for (int c = tid; c < C; c += 1024) {
        unsigned uc = cu[c];
        int ic = cidx[c];
        int rank = 0;
        for (int o = 0; o < C; o++) {
            unsigned uo = cu[o];
            rank += (uo > uc) || (uo == uc && cidx[o] < ic);
        }
        if (rank < K_) {
            topv[t * K_ + rank] = funord(uc);
            topidx[t * K_ + rank] = ic;
        }
    }
}

// ---------- Z[t][f][j] = X[t][idx[j]][f] * topv[j] ----------
__global__ void k_z(const float* __restrict__ X, const float* __restrict__ topv,
                    const int* __restrict__ topidx, float* __restrict__ Z) {
    int gid = blockIdx.x * 256 + threadIdx.x;  // t*16384 + f*128 + j
    if (gid >= T_ * F0_ * K_) return;
    int j = gid & 127;
    int f = (gid >> 7) & 127;
    int t = gid >> 14;
    int idx = topidx[t * K_ + j];
    float v = topv[t * K_ + j];
    Z[gid] = X[((size_t)(t * N_ + idx)) * F0_ + f] * v;
}

// ---------- A_g[t] = W_g @ Z_t + B_g  (g in {Z,R,H}, all t parallel) ----------
__global__ void k_az(const float* __restrict__ WZ, const float* __restrict__ WR,
                     const float* __restrict__ WH, const float* __restrict__ BZ,
                     const float* __restrict__ BR, const float* __restrict__ BH,
                     const float* __restrict__ Z, float* __restrict__ AZ,
                     float* __restrict__ AR, float* __restrict__ AHo) {
    int gid = blockIdx.x * 256 + threadIdx.x;  // g*131072 + t*16384 + i*128 + j
    int j = gid & 127;
    int i = (gid >> 7) & 127;
    int t = (gid >> 14) & 7;
    int g = gid >> 17;
    const float* W = (g == 0) ? WZ : (g == 1) ? WR : WH;
    const float* B = (g == 0) ? BZ : (g == 1) ? BR : BH;
    float* Ao = (g == 0) ? AZ : (g == 1) ? AR : AHo;
    const float* Zt = Z + (size_t)t * 16384;
    float acc = B[i * 128 + j];
    for (int k = 0; k < 128; k++) acc += W[i * 128 + k] * Zt[k * 128 + j];
    Ao[(size_t)(t * 128 + i) * 128 + j] = acc;
}

// ---------- CSR build pass 0: bucket counts via LDS histogram ----------
__global__ __launch_bounds__(512) void k_cnt(const int* __restrict__ A_rows,
                                             int* __restrict__ bcnt) {
    __shared__ int cnt[NB];
    int t = blockIdx.y, ci = blockIdx.x;
    int tid = threadIdx.x;
    for (int i = tid; i < NB; i += 512) cnt[i] = 0;
    __syncthreads();
    int e0 = ci * BCH;
#pragma unroll
    for (int k = 0; k < 16; k++) {
        int idx = e0 + tid + k * 512;
        if (idx < NNZ_) atomicAdd(&cnt[A_rows[(size_t)t * NNZ_ + idx] >> 7], 1);
    }
    __syncthreads();
    for (int b = tid; b < NB; b += 512)
        if (cnt[b]) atomicAdd(&bcnt[t * NB + b], cnt[b]);
}

// ---------- bucket scan: bbase[t][b] = excl prefix of bcnt[t][*] ----------
__global__ __launch_bounds__(512) void k_bscan(const int* __restrict__ bcnt,
                                               int* __restrict__ bbase) {
    int t = blockIdx.x;
    int tid = threadIdx.x;
    __shared__ int buf[512];
    int v = (tid < NB) ? bcnt[t * NB + tid] : 0;
    buf[tid] = v;
    __syncthreads();
    for (int off = 1; off < 512; off <<= 1) {
        int x = (tid >= off) ? buf[tid - off] : 0;
        __syncthreads();
        buf[tid] += x;
        __syncthreads();
    }
    if (tid < NB) bbase[t * NB + tid] = buf[tid] - v;
}

// ---------- Pass A: bin edges into 128-row buckets, group-contiguous writes ----------
// meta = col(16b) | rlo(7b)<<16 | b(9b)<<23 ; sentinel 0xFFFFFFFF (b=511 impossible)
__global__ __launch_bounds__(512) void k_binA(const int* __restrict__ A_rows,
                                              const int* __restrict__ A_cols,
                                              const float* __restrict__ A_val,
                                              const int* __restrict__ bbase,
                                              int* __restrict__ bfill,
                                              int2* __restrict__ ebuck) {
    __shared__ int cnt[NB];
    __shared__ int gbase[NB];
    __shared__ int rbase[NB];
    int t = blockIdx.y, ci = blockIdx.x;
    int tid = threadIdx.x;
    for (int i = tid; i < NB; i += 512) cnt[i] = 0;
    __syncthreads();
    unsigned meta[16];
    float val[16];
    int lrank[16];
    int e0 = ci * BCH;
#pragma unroll
    for (int k = 0; k < 16; k++) {
        int idx = e0 + tid + k * 512;
        meta[k] = 0xFFFFFFFFu;
        val[k] = 0.f;
        lrank[k] = 0;
        if (idx < NNZ_) {
            int r = A_rows[(size_t)t * NNZ_ + idx];
            int c = A_cols[(size_t)t * NNZ_ + idx];
            val[k] = A_val[(size_t)t * NNZ_ + idx];
            int b = r >> 7, rlo = r & 127;
            meta[k] = (unsigned)c | ((unsigned)rlo << 16) | ((unsigned)b << 23);
            lrank[k] = atomicAdd(&cnt[b], 1);
        }
    }
    __syncthreads();
    for (int b = tid; b < NB; b += 512) {
        int n = cnt[b];
        gbase[b] = n ? atomicAdd(&bfill[t * NB + b], n) : 0;
        rbase[b] = bbase[t * NB + b];
    }
    __syncthreads();
#pragma unroll
    for (int k = 0; k < 16; k++) {
        if (meta[k] != 0xFFFFFFFFu) {
            int b = meta[k] >> 23;
            ebuck[(size_t)t * NNZ_ + rbase[b] + gbase[b] + lrank[k]] =
                make_int2((int)meta[k], __float_as_int(val[k]));
        }
    }
}

// ---------- Pass B: per-bucket row count + scan -> row_ptr; sort edges into CSR ----------
__global__ __launch_bounds__(256) void k_bsort(const int* __restrict__ bbase,
                                               const int* __restrict__ bcnt,
                                               const int2* __restrict__ ebuck,
                                               int2* __restrict__ ecv,
                                               int* __restrict__ row_ptr) {
    __shared__ int rcnt[128];
    __shared__ int rex[128];
    __shared__ int rfill[128];
    __shared__ int sbuf[128];
    int t = blockIdx.y, b = blockIdx.x;
    int tid = threadIdx.x;
    int r0 = b << 7;
    int nrows = min(128, N_ - r0);
    int base = bbase[t * NB + b];
    int n = bcnt[t * NB + b];
    if (tid < 128) {
        rcnt[tid] = 0;
        rfill[tid] = 0;
    }
    __syncthreads();
    const int2* src = ebuck + (size_t)t * NNZ_ + base;
    int2* dst = ecv + (size_t)t * NNZ_ + base;
    for (int i = tid; i < n; i += 256) atomicAdd(&rcnt[(src[i].x >> 16) & 127], 1);
    __syncthreads();
    // exclusive scan of rcnt (128 wide)
    if (tid < 128) sbuf[tid] = rcnt[tid];
    __syncthreads();
    for (int off = 1; off < 128; off <<= 1) {
        int x = (tid >= off && tid < 128) ? sbuf[tid - off] : 0;
        __syncthreads();
        if (tid < 128) sbuf[tid] += x;
        __syncthreads();
    }
    if (tid < 128) rex[tid] = sbuf[tid] - rcnt[tid];
    if (tid < nrows) row_ptr[(size_t)t * (N_ + 1) + r0 + tid] = base + sbuf[tid] - rcnt[tid];
    if (b == 0 && tid == 0) row_ptr[(size_t)t * (N_ + 1) + N_] = NNZ_;
    __syncthreads();
    for (int i = tid; i < n; i += 256) {
        int2 e = src[i];
        int rlo = (e.x >> 16) & 127;
        int col = e.x & 0xFFFF;
        int pos = rex[rlo] + atomicAdd(&rfill[rlo], 1);
        dst[pos] = make_int2(col, e.y);
    }
}

// ---------- SpMM (bf16 gather, 8 loads in flight): AH[t][r] = sum val*Xh[t][col] ----------
__global__ void k_spmm(const unsigned* __restrict__ Xh, const int* __restrict__ row_ptr,
                       const int2* __restrict__ ecv, float* __restrict__ AH) {
    int gid = blockIdx.x * 256 + threadIdx.x;
    int wave = gid >> 6, lane = gid & 63;
    if (wave >= T_ * N_) return;
    int t = wave / N_;
    int r = wave - t * N_;
    int s = row_ptr[(size_t)t * (N_ + 1) + r];
    int len = row_ptr[(size_t)t * (N_ + 1) + r + 1] - s;
    const unsigned* Xt = Xh + (size_t)t * N_ * 64 + lane;
    const int2* ev = ecv + (size_t)t * NNZ_;
    float2 acc = {0.f, 0.f};
    for (int base = 0; base < len; base += 64) {
        int nn = min(64, len - base);
        int2 my = {0, 0};
        if (base + lane < len) my = ev[s + base + lane];
        int q = 0;
        for (; q + 8 <= nn; q += 8) {
            int c0 = __shfl(my.x, q + 0); float v0 = __int_as_float(__shfl(my.y, q + 0));
            int c1 = __shfl(my.x, q + 1); float v1 = __int_as_float(__shfl(my.y, q + 1));
            int c2 = __shfl(my.x, q + 2); float v2 = __int_as_float(__shfl(my.y, q + 2));
            int c3 = __shfl(my.x, q + 3); float v3 = __int_as_float(__shfl(my.y, q + 3));
            int c4 = __shfl(my.x, q + 4); float v4 = __int_as_float(__shfl(my.y, q + 4));
            int c5 = __shfl(my.x, q + 5); float v5 = __int_as_float(__shfl(my.y, q + 5));
            int c6 = __shfl(my.x, q + 6); float v6 = __int_as_float(__shfl(my.y, q + 6));
            int c7 = __shfl(my.x, q + 7); float v7 = __int_as_float(__shfl(my.y, q + 7));
            unsigned x0 = Xt[(size_t)c0 * 64];
            unsigned x1 = Xt[(size_t)c1 * 64];
            unsigned x2 = Xt[(size_t)c2 * 64];
            unsigned x3 = Xt[(size_t)c3 * 64];
            unsigned x4 = Xt[(size_t)c4 * 64];
            unsigned x5 = Xt[(size_t)c5 * 64];
            unsigned x6 = Xt[(size_t)c6 * 64];
            unsigned x7 = Xt[(size_t)c7 * 64];
            acc.x += v0 * bflo(x0); acc.y += v0 * bfhi(x0);
            acc.x += v1 * bflo(x1); acc.y += v1 * bfhi(x1);
            acc.x += v2 * bflo(x2); acc.y += v2 * bfhi(x2);
            acc.x += v3 * bflo(x3); acc.y += v3 * bfhi(x3);
            acc.x += v4 * bflo(x4); acc.y += v4 * bfhi(x4);
            acc.x += v5 * bflo(x5); acc.y += v5 * bfhi(x5);
            acc.x += v6 * bflo(x6); acc.y += v6 * bfhi(x6);
            acc.x += v7 * bflo(x7); acc.y += v7 * bfhi(x7);
        }
        for (; q < nn; q++) {
            int c = __shfl(my.x, q);
            float v = __int_as_float(__shfl(my.y, q));
            unsigned xp = Xt[(size_t)c * 64];
            acc.x += v * bflo(xp);
            acc.y += v * bfhi(xp);
        }
    }
    ((float2*)AH)[(size_t)wave * 64 + lane] = acc;
}

// fallback (fp32 gather) if workspace can't hold Xh
__global__ void k_spmm_f32(const float* __restrict__ X, const int* __restrict__ row_ptr,
                           const int2* __restrict__ ecv, float* __restrict__ AH) {
    int gid = blockIdx.x * 256 + threadIdx.x;
    int wave = gid >> 6, lane = gid & 63;
    if (wave >= T_ * N_) return;
    int t = wave / N_;
    int r = wave - t * N_;
    int s = row_ptr[(size_t)t * (N_ + 1) + r];
    int len = row_ptr[(size_t)t * (N_ + 1) + r + 1] - s;
    const float2* Xt = (const float2*)(X + (size_t)t * N_ * F0_);
    const int2* ev = ecv + (size_t)t * NNZ_;
    float2 acc = {0.f, 0.f};
    for (int base = 0; base < len; base += 64) {
        int nn = min(64, len - base);
        int2 my = {0, 0};
        if (base + lane < len) my = ev[s + base + lane];
        for (int q = 0; q < nn; q++) {
            int c = __shfl(my.x, q);
            float v = __int_as_float(__shfl(my.y, q));
            float2 x = Xt[(size_t)c * 64 + lane];
            acc.x += v * x.x;
            acc.y += v * x.y;
        }
    }
    ((float2*)AH)[(size_t)wave * 64 + lane] = acc;
}

// ---------- fused GRU step (column-separable): one launch per t ----------
__global__ __launch_bounds__(256) void k_gru(const float* __restrict__ AZt,
                                             const float* __restrict__ ARt,
                                             const float* __restrict__ AHt,
                                             const float* __restrict__ UZ,
                                             const float* __restrict__ UR,
                                             const float* __restrict__ UH,
                                             const float* __restrict__ Wprev,
                                             float* __restrict__ Wnew) {
    __shared__ float RWs[128][2];
    int jl = threadIdx.x >> 7;  // 0..1
    int i = threadIdx.x & 127;
    int j = blockIdx.x * 2 + jl;
    int gid = i * 128 + j;
    float az = AZt[gid], ar = ARt[gid];
    for (int k = 0; k < 128; k++) {
        float w = Wprev[k * 128 + j];  // wave-uniform broadcast
        az += UZ[i * 128 + k] * w;
        ar += UR[i * 128 + k] * w;
    }
    float zg = 1.f / (1.f + expf(-az));
    float rg = 1.f / (1.f + expf(-ar));
    RWs[i][jl] = rg * Wprev[gid];
    __syncthreads();
    float acc = AHt[gid];
    for (int k = 0; k < 128; k++) acc += UH[i * 128 + k] * RWs[k][jl];
    float ht = tanhf(acc);
    float w0 = Wprev[gid];
    Wnew[gid] = (1.f - zg) * w0 + zg * ht;
}

// ---------- WU[t][k][h2] = sum_m W_t[k][m] * U[(h2<64? m : 128+m)][h2&63] ----------
__global__ void k_wu(const float* __restrict__ W_seq, const float* __restrict__ U,
                     float* __restrict__ WU) {
    int blk = blockIdx.x;  // t*128 + k
    int t = blk >> 7, k = blk & 127;
    int h2 = threadIdx.x;
    const float* Wt = W_seq + (size_t)t * 16384;
    int h = h2 & 63;
    const float* Ub = U + (h2 < 64 ? 0 : 128 * 64);
    float acc = 0.f;
    for (int m = 0; m < 128; m++) acc += Wt[k * 128 + m] * Ub[m * 64 + h];
    WU[((size_t)t * 128 + k) * 128 + h2] = acc;
}

// ---------- PQ = AH @ WU[t], bf16-packed into PQh (reuses Xh buffer) ----------
__global__ __launch_bounds__(256) void k_pq(const float* __restrict__ AH,
                                            const float* __restrict__ WU,
                                            unsigned* __restrict__ PQh) {
    __shared__ float AT[32][36];
    __shared__ float WUc[32][128];
    int t = blockIdx.y;
    int rbase = blockIdx.x * 32;
    int tid = threadIdx.x;
    const float* wu = WU + (size_t)t * 16384;
    const float* AHt = AH + (size_t)t * N_ * F0_;
    unsigned* PQt = PQh + (size_t)t * N_ * 64;
    int cg = tid & 31;
    int rg = tid >> 5;
    float4 acc0 = {0.f, 0.f, 0.f, 0.f};
    float4 acc1 = {0.f, 0.f, 0.f, 0.f};
    float4 acc2 = {0.f, 0.f, 0.f, 0.f};
    float4 acc3 = {0.f, 0.f, 0.f, 0.f};
    int srow = tid >> 3;
    int sk4 = (tid & 7) * 4;
    for (int kc = 0; kc < 128; kc += 32) {
        {
            float4 v = {0.f, 0.f, 0.f, 0.f};
            int r = rbase + srow;
            if (r < N_) v = *(const float4*)(AHt + (size_t)r * F0_ + kc + sk4);
            AT[sk4 + 0][srow] = v.x;
            AT[sk4 + 1][srow] = v.y;
            AT[sk4 + 2][srow] = v.z;
            AT[sk4 + 3][srow] = v.w;
        }
        {
            const float4* src = (const float4*)(wu + (size_t)kc * 128);
            float4* dst = (float4*)&WUc[0][0];
            dst[tid] = src[tid];
            dst[tid + 256] = src[tid + 256];
            dst[tid + 512] = src[tid + 512];
            dst[tid + 768] = src[tid + 768];
        }
        __syncthreads();
#pragma unroll 4
        for (int kk = 0; kk < 32; kk++) {
            float4 a = *(const float4*)&AT[kk][rg * 4];
            float4 w = *(const float4*)&WUc[kk][cg * 4];
            acc0.x += a.x * w.x; acc0.y += a.x * w.y; acc0.z += a.x * w.z; acc0.w += a.x * w.w;
            acc1.x += a.y * w.x; acc1.y += a.y * w.y; acc1.z += a.y * w.z; acc1.w += a.y * w.w;
            acc2.x += a.z * w.x; acc2.y += a.z * w.y; acc2.z += a.z * w.z; acc2.w += a.z * w.w;
            acc3.x += a.w * w.x; acc3.y += a.w * w.y; acc3.z += a.w * w.z; acc3.w += a.w * w.w;
        }
        __syncthreads();
    }
    int r0 = rbase + rg * 4;
    if (r0 + 0 < N_) {
        uint2 o = {bfpack(acc0.x, acc0.y), bfpack(acc0.z, acc0.w)};
        *(uint2*)(PQt + (size_t)(r0 + 0) * 64 + cg * 2) = o;
    }
    if (r0 + 1 < N_) {
        uint2 o = {bfpack(acc1.x, acc1.y), bfpack(acc1.z, acc1.w)};
        *(uint2*)(PQt + (size_t)(r0 + 1) * 64 + cg * 2) = o;
    }
    if (r0 + 2 < N_) {
        uint2 o = {bfpack(acc2.x, acc2.y), bfpack(acc2.z, acc2.w)};
        *(uint2*)(PQt + (size_t)(r0 + 2) * 64 + cg * 2) = o;
    }
    if (r0 + 3 < N_) {
        uint2 o = {bfpack(acc3.x, acc3.y), bfpack(acc3.z, acc3.w)};
        *(uint2*)(PQt + (size_t)(r0 + 3) * 64 + cg * 2) = o;
    }
}

// fp32 in-place fallback
__global__ __launch_bounds__(256) void k_pq_f32(float* __restrict__ AH,
                                                const float* __restrict__ WU) {
    __shared__ float AT[32][36];
    __shared__ float WUc[32][128];
    int t = blockIdx.y;
    int rbase = blockIdx.x * 32;
    int tid = threadIdx.x;
    const float* wu = WU + (size_t)t * 16384;
    float* AHt = AH + (size_t)t * N_ * F0_;
    int cg = tid & 31;
    int rg = tid >> 5;
    float4 acc0 = {0.f, 0.f, 0.f, 0.f};
    float4 acc1 = {0.f, 0.f, 0.f, 0.f};
    float4 acc2 = {0.f, 0.f, 0.f, 0.f};
    float4 acc3 = {0.f, 0.f, 0.f, 0.f};
    int srow = tid >> 3;
    int sk4 = (tid & 7) * 4;
    for (int kc = 0; kc < 128; kc += 32) {
        {
            float4 v = {0.f, 0.f, 0.f, 0.f};
            int r = rbase + srow;
            if (r < N_) v = *(const float4*)(AHt + (size_t)r * F0_ + kc + sk4);
            AT[sk4 + 0][srow] = v.x;
            AT[sk4 + 1][srow] = v.y;
            AT[sk4 + 2][srow] = v.z;
            AT[sk4 + 3][srow] = v.w;
        }
        {
            const float4* src = (const float4*)(wu + (size_t)kc * 128);
            float4* dst = (float4*)&WUc[0][0];
            dst[tid] = src[tid];
            dst[tid + 256] = src[tid + 256];
            dst[tid + 512] = src[tid + 512];
            dst[tid + 768] = src[tid + 768];
        }
        __syncthreads();
#pragma unroll 4
        for (int kk = 0; kk < 32; kk++) {
            float4 a = *(const float4*)&AT[kk][rg * 4];
            float4 w = *(const float4*)&WUc[kk][cg * 4];
            acc0.x += a.x * w.x; acc0.y += a.x * w.y; acc0.z += a.x * w.z; acc0.w += a.x * w.w;
            acc1.x += a.y * w.x; acc1.y += a.y * w.y; acc1.z += a.y * w.z; acc1.w += a.y * w.w;
            acc2.x += a.z * w.x; acc2.y += a.z * w.y; acc2.z += a.z * w.z; acc2.w += a.z * w.w;
            acc3.x += a.w * w.x; acc3.y += a.w * w.y; acc3.z += a.w * w.z; acc3.w += a.w * w.w;
        }
        __syncthreads();
    }
    int r0 = rbase + rg * 4;
    if (r0 + 0 < N_) *(float4*)(AHt + (size_t)(r0 + 0) * F0_ + cg * 4) = acc0;
    if (r0 + 1 < N_) *(float4*)(AHt + (size_t)(r0 + 1) * F0_ + cg * 4) = acc1;
    if (r0 + 2 < N_) *(float4*)(AHt + (size_t)(r0 + 2) * F0_ + cg * 4) = acc2;
    if (r0 + 3 < N_) *(float4*)(AHt + (size_t)(r0 + 3) * F0_ + cg * 4) = acc3;
}

// ---------- out[e] = P[flat_src] + Q[flat_trg]  (bf16 PQh) ----------
__global__ void k_final(const unsigned* __restrict__ PQh, const int* __restrict__ et,
                        const int* __restrict__ es, const int* __restrict__ eg,
                        float* __restrict__ out) {
    int gid = blockIdx.x * 256 + threadIdx.x;  // e*16 + q
    if (gid >= E_ * 16) return;
    int e = gid >> 4, q = gid & 15;
    int t = et[e];
    const uint2 a = *(const uint2*)(PQh + ((size_t)(t * N_ + es[e])) * 64 + q * 2);
    const uint2 b = *(const uint2*)(PQh + ((size_t)(t * N_ + eg[e])) * 64 + 32 + q * 2);
    float4 o;
    o.x = bflo(a.x) + bflo(b.x);
    o.y = bfhi(a.x) + bfhi(b.x);
    o.z = bflo(a.y) + bflo(b.y);
    o.w = bfhi(a.y) + bfhi(b.y);
    *(float4*)(out + (size_t)e * 64 + q * 4) = o;
}

__global__ void k_final_f32(const float* __restrict__ PQ, const int* __restrict__ et,
                            const int* __restrict__ es, const int* __restrict__ eg,
                            float* __restrict__ out) {
    int gid = blockIdx.x * 256 + threadIdx.x;  // e*16 + q
    if (gid >= E_ * 16) return;
    int e = gid >> 4, q = gid & 15;
    int t = et[e];
    const float4 a = *(const float4*)(PQ + ((size_t)(t * N_ + es[e])) * 128 + q * 4);
    const float4 b = *(const float4*)(PQ + ((size_t)(t * N_ + eg[e])) * 128 + 64 + q * 4);
    float4 o = {a.x + b.x, a.y + b.y, a.z + b.z, a.w + b.w};
    *(float4*)(out + (size_t)e * 64 + q * 4) = o;
}

__global__ void k_wfin(const float* __restrict__ W_seq, float* __restrict__ out) {
    int gid = blockIdx.x * 256 + threadIdx.x;
    out[(size_t)E_ * 64 + gid] = W_seq[(size_t)7 * 16384 + gid];
}

// ---------- launch ----------
extern "C" void kernel_launch(void* const* d_in, const int* in_sizes, int n_in,
                              void* d_out, int out_size, void* d_ws, size_t ws_size,
                              hipStream_t stream) {
    const float* X = (const float*)d_in[0];
    const int* A_rows = (const int*)d_in[1];
    const int* A_cols = (const int*)d_in[2];
    const float* A_val = (const float*)d_in[3];
    const int* edge_time = (const int*)d_in[4];
    const int* edge_src = (const int*)d_in[5];
    const int* edge_trg = (const int*)d_in[6];
    const float* p = (const float*)d_in[7];
    const float* W_Z = (const float*)d_in[8];
    const float* U_Z = (const float*)d_in[9];
    const float* B_Z = (const float*)d_in[10];
    const float* W_R = (const float*)d_in[11];
    const float* U_R = (const float*)d_in[12];
    const float* B_R = (const float*)d_in[13];
    const float* W_H = (const float*)d_in[14];
    const float* U_H = (const float*)d_in[15];
    const float* B_H = (const float*)d_in[16];
    const float* W_init = (const float*)d_in[17];
    const float* U = (const float*)d_in[18];
    float* out = (float*)d_out;

    char* ws = (char*)d_ws;
    size_t off = 0;
    auto take = [&](size_t bytes) {
        char* ptr = ws + off;
        off = (off + bytes + 255) & ~(size_t)255;
        return (void*)ptr;
    };
    float* AH = (float*)take((size_t)T_ * N_ * F0_ * 4);   // 204.8 MB (ebuck overlays)
    int2* ecv = (int2*)take((size_t)T_ * NNZ_ * 8);        // 51.2 MB final CSR
    float* yv = (float*)take((size_t)T_ * N_ * 4);
    int* row_ptr = (int*)take((size_t)T_ * (N_ + 1) * 4);
    int* bcnt = (int*)take((size_t)T_ * NB * 4);
    int* bbase = (int*)take((size_t)T_ * NB * 4);
    int* bfill = (int*)take((size_t)T_ * NB * 4);
    float* p_hat = (float*)take(512);
    float* topv = (float*)take((size_t)T_ * K_ * 4);
    int* topidx = (int*)take((size_t)T_ * K_ * 4);
    float* Z = (float*)take((size_t)T_ * F0_ * K_ * 4);
    float* AZb = (float*)take((size_t)T_ * 16384 * 4);
    float* ARb = (float*)take((size_t)T_ * 16384 * 4);
    float* AHb = (float*)take((size_t)T_ * 16384 * 4);
    float* W_seq = (float*)take((size_t)T_ * 16384 * 4);
    float* WU = (float*)take((size_t)T_ * 16384 * 4);
    unsigned* Xh = (unsigned*)take((size_t)T_ * N_ * 64 * 4);  // 102.4 MB; reused as PQh
    bool use_bf16 = (off <= ws_size);
    unsigned* PQh = Xh;        // Xh retired after k_spmm; reuse as bf16 PQ
    int2* ebuck = (int2*)AH;   // AH live range starts at k_spmm; ebuck dead by then

    hipMemsetAsync(bcnt, 0, (size_t)T_ * NB * 4, stream);
    hipMemsetAsync(bfill, 0, (size_t)T_ * NB * 4, stream);

    k_phat<<<1, 128, 0, stream>>>(p, p_hat);
    k_y<<<(T_ * N_ * 64) / 256, 256, 0, stream>>>(X, p_hat, yv, use_bf16 ? Xh : nullptr);
    k_topk<<<T_, 1024, 0, stream>>>(yv, topv, topidx);
    k_z<<<(T_ * F0_ * K_) / 256, 256, 0, stream>>>(X, topv, topidx, Z);
    k_az<<<(3 * T_ * 16384) / 256, 256, 0, stream>>>(W_Z, W_R, W_H, B_Z, B_R, B_H, Z,
                                                     AZb, ARb, AHb);
    {
        dim3 gA((NNZ_ + BCH - 1) / BCH, T_);  // 98 x 8
        k_cnt<<<gA, 512, 0, stream>>>(A_rows, bcnt);
        k_bscan<<<T_, 512, 0, stream>>>(bcnt, bbase);
        k_binA<<<gA, 512, 0, stream>>>(A_rows, A_cols, A_val, bbase, bfill, ebuck);
        dim3 gB(NB, T_);                      // 391 x 8
        k_bsort<<<gB, 256, 0, stream>>>(bbase, bcnt, ebuck, ecv, row_ptr);
    }
    if (use_bf16)
        k_spmm<<<(T_ * N_ * 64) / 256, 256, 0, stream>>>(Xh, row_ptr, ecv, AH);
    else
        k_spmm_f32<<<(T_ * N_ * 64) / 256, 256, 0, stream>>>(X, row_ptr, ecv, AH);
    for (int t = 0; t < T_; t++) {
        const float* Wprev = (t == 0) ? W_init : (W_seq + (size_t)(t - 1) * 16384);
        k_gru<<<64, 256, 0, stream>>>(AZb + (size_t)t * 16384, ARb + (size_t)t * 16384,
                                      AHb + (size_t)t * 16384, U_Z, U_R, U_H, Wprev,
                                      W_seq + (size_t)t * 16384);
    }
    k_wu<<<T_ * 128, 128, 0, stream>>>(W_seq, U, WU);
    {
        dim3 g((N_ + 31) / 32, T_);
        if (use_bf16) {
            k_pq<<<g, 256, 0, stream>>>(AH, WU, PQh);
            k_final<<<(E_ * 16) / 256, 256, 0, stream>>>(PQh, edge_time, edge_src,
                                                         edge_trg, out);
        } else {
            k_pq_f32<<<g, 256, 0, stream>>>(AH, WU);
            k_final_f32<<<(E_ * 16) / 256, 256, 0, stream>>>(AH, edge_time, edge_src,
                                                             edge_trg, out);
        }
    }
    k_wfin<<<(F0_ * H0_) / 256, 256, 0, stream>>>(W_seq, out);
}

// Round 8
// 954.354 us; speedup vs baseline: 11.1524x; 1.0128x over previous
//
#include <hip/hip_runtime.h>
#include <math.h>

#define T_ 8
#define N_ 50000
#define F0_ 128
#define H0_ 128
#define H1_ 64
#define NNZ_ 800000
#define E_ 1000000
#define K_ 128
#define CAP_ 3072
#define NB 391   // ceil(N_/128) buckets of 128 rows
#define BCH 8192 // edges per chunk block

// ---------- helpers ----------
__device__ inline unsigned ford(float f) {
    unsigned b = __float_as_uint(f);
    return (b & 0x80000000u) ? ~b : (b | 0x80000000u);
}
__device__ inline float funord(unsigned u) {
    unsigned b = (u & 0x80000000u) ? (u & 0x7fffffffu) : ~u;
    return __uint_as_float(b);
}
__device__ inline unsigned bfr(float f) {  // fp32 -> bf16 bits (RNE)
    unsigned u = __float_as_uint(f);
    return (u + 0x7fffu + ((u >> 16) & 1u)) >> 16;
}
__device__ inline unsigned bfpack(float lo, float hi) { return bfr(lo) | (bfr(hi) << 16); }
__device__ inline float bflo(unsigned u) { return __uint_as_float(u << 16); }
__device__ inline float bfhi(unsigned u) { return __uint_as_float(u & 0xffff0000u); }

// ---------- p_hat = p / ||p|| ----------
__global__ void k_phat(const float* p, float* p_hat) {
    __shared__ float s[128];
    int i = threadIdx.x;
    float v = p[i];
    s[i] = v * v;
    __syncthreads();
    for (int off = 64; off > 0; off >>= 1) {
        if (i < off) s[i] += s[i + off];
        __syncthreads();
    }
    p_hat[i] = v / sqrtf(s[0]);
}

// ---------- y = X @ p_hat (wave/row) + bf16 copy of X ----------
__global__ void k_y(const float* __restrict__ X, const float* __restrict__ p_hat,
                    float* __restrict__ y, unsigned* __restrict__ Xh) {
    int gid = blockIdx.x * 256 + threadIdx.x;
    int wave = gid >> 6, lane = gid & 63;
    if (wave >= T_ * N_) return;
    const float2* xr = (const float2*)(X + (size_t)wave * F0_);
    float2 a = xr[lane];
    if (Xh) Xh[(size_t)wave * 64 + lane] = bfpack(a.x, a.y);
    float2 ph = ((const float2*)p_hat)[lane];
    float acc = a.x * ph.x + a.y * ph.y;
#pragma unroll
    for (int off = 32; off > 0; off >>= 1) acc += __shfl_down(acc, off);
    if (lane == 0) y[wave] = acc;
}

// ---------- exact top-128 per t: 2-level radix select + exact rank ----------
__global__ __launch_bounds__(1024) void k_topk(const float* __restrict__ y,
                                               float* __restrict__ topv,
                                               int* __restrict__ topidx) {
    int t = blockIdx.x;
    const float* yt = y + (size_t)t * N_;
    __shared__ int hist[256];
    __shared__ int sb1, sAbove, sP, scand;
    __shared__ unsigned cu[CAP_];
    __shared__ int cidx[CAP_];
    int tid = threadIdx.x;

    if (tid < 256) hist[tid] = 0;
    __syncthreads();
    for (int i = tid; i < N_; i += 1024) {
        unsigned u = ford(yt[i]);
        atomicAdd(&hist[u >> 24], 1);
    }
    __syncthreads();
    if (tid == 0) {
        int acc = 0, b = 255;
        for (; b >= 0; b--) { acc += hist[b]; if (acc >= K_) break; }
        sb1 = b;
        sAbove = acc - hist[b];
    }
    __syncthreads();
    int b1 = sb1;
    if (tid < 256) hist[tid] = 0;
    __syncthreads();
    for (int i = tid; i < N_; i += 1024) {
        unsigned u = ford(yt[i]);
        if ((int)(u >> 24) == b1) atomicAdd(&hist[(u >> 16) & 255], 1);
    }
    __syncthreads();
    if (tid == 0) {
        int acc = sAbove, b = 255;
        for (; b >= 0; b--) { acc += hist[b]; if (acc >= K_) break; }
        sP = (b1 << 8) | b;
        scand = 0;
    }
    __syncthreads();
    unsigned P = (unsigned)sP;
    for (int i = tid; i < N_; i += 1024) {
        unsigned u = ford(yt[i]);
        if ((u >> 16) >= P) {
            int pos = atomicAdd(&scand, 1);
            if (pos < CAP_) { cu[pos] = u; cidx[pos] = i; }
        }
    }
    __syncthreads();
    int C = min(scand, CAP_);
    for (int c = tid; c < C; c += 1024) {
        unsigned uc = cu[c];
        int ic = cidx[c];
        int rank = 0;
        for (int o = 0; o < C; o++) {
            unsigned uo = cu[o];
            rank += (uo > uc) || (uo == uc && cidx[o] < ic);
        }
        if (rank < K_) {
            topv[t * K_ + rank] = funord(uc);
            topidx[t * K_ + rank] = ic;
        }
    }
}

// ---------- Z[t][f][j] = X[t][idx[j]][f] * topv[j] ----------
__global__ void k_z(const float* __restrict__ X, const float* __restrict__ topv,
                    const int* __restrict__ topidx, float* __restrict__ Z) {
    int gid = blockIdx.x * 256 + threadIdx.x;  // t*16384 + f*128 + j
    if (gid >= T_ * F0_ * K_) return;
    int j = gid & 127;
    int f = (gid >> 7) & 127;
    int t = gid >> 14;
    int idx = topidx[t * K_ + j];
    float v = topv[t * K_ + j];
    Z[gid] = X[((size_t)(t * N_ + idx)) * F0_ + f] * v;
}

// ---------- A_g[t] = W_g @ Z_t + B_g  (g in {Z,R,H}, all t parallel) ----------
__global__ void k_az(const float* __restrict__ WZ, const float* __restrict__ WR,
                     const float* __restrict__ WH, const float* __restrict__ BZ,
                     const float* __restrict__ BR, const float* __restrict__ BH,
                     const float* __restrict__ Z, float* __restrict__ AZ,
                     float* __restrict__ AR, float* __restrict__ AHo) {
    int gid = blockIdx.x * 256 + threadIdx.x;  // g*131072 + t*16384 + i*128 + j
    int j = gid & 127;
    int i = (gid >> 7) & 127;
    int t = (gid >> 14) & 7;
    int g = gid >> 17;
    const float* W = (g == 0) ? WZ : (g == 1) ? WR : WH;
    const float* B = (g == 0) ? BZ : (g == 1) ? BR : BH;
    float* Ao = (g == 0) ? AZ : (g == 1) ? AR : AHo;
    const float* Zt = Z + (size_t)t * 16384;
    float acc = B[i * 128 + j];
    for (int k = 0; k < 128; k++) acc += W[i * 128 + k] * Zt[k * 128 + j];
    Ao[(size_t)(t * 128 + i) * 128 + j] = acc;
}

// ---------- CSR build pass 0: bucket counts via LDS histogram ----------
__global__ __launch_bounds__(512) void k_cnt(const int* __restrict__ A_rows,
                                             int* __restrict__ bcnt) {
    __shared__ int cnt[NB];
    int t = blockIdx.y, ci = blockIdx.x;
    int tid = threadIdx.x;
    for (int i = tid; i < NB; i += 512) cnt[i] = 0;
    __syncthreads();
    int e0 = ci * BCH;
#pragma unroll
    for (int k = 0; k < 16; k++) {
        int idx = e0 + tid + k * 512;
        if (idx < NNZ_) atomicAdd(&cnt[A_rows[(size_t)t * NNZ_ + idx] >> 7], 1);
    }
    __syncthreads();
    for (int b = tid; b < NB; b += 512)
        if (cnt[b]) atomicAdd(&bcnt[t * NB + b], cnt[b]);
}

// ---------- bucket scan: bbase[t][b] = excl prefix of bcnt[t][*] ----------
__global__ __launch_bounds__(512) void k_bscan(const int* __restrict__ bcnt,
                                               int* __restrict__ bbase) {
    int t = blockIdx.x;
    int tid = threadIdx.x;
    __shared__ int buf[512];
    int v = (tid < NB) ? bcnt[t * NB + tid] : 0;
    buf[tid] = v;
    __syncthreads();
    for (int off = 1; off < 512; off <<= 1) {
        int x = (tid >= off) ? buf[tid - off] : 0;
        __syncthreads();
        buf[tid] += x;
        __syncthreads();
    }
    if (tid < NB) bbase[t * NB + tid] = buf[tid] - v;
}

// ---------- Pass A: bin edges into 128-row buckets, group-contiguous writes ----------
// meta = col(16b) | rlo(7b)<<16 | b(9b)<<23 ; sentinel 0xFFFFFFFF (b=511 impossible)
__global__ __launch_bounds__(512) void k_binA(const int* __restrict__ A_rows,
                                              const int* __restrict__ A_cols,
                                              const float* __restrict__ A_val,
                                              const int* __restrict__ bbase,
                                              int* __restrict__ bfill,
                                              int2* __restrict__ ebuck) {
    __shared__ int cnt[NB];
    __shared__ int gbase[NB];
    __shared__ int rbase[NB];
    int t = blockIdx.y, ci = blockIdx.x;
    int tid = threadIdx.x;
    for (int i = tid; i < NB; i += 512) cnt[i] = 0;
    __syncthreads();
    unsigned meta[16];
    float val[16];
    int lrank[16];
    int e0 = ci * BCH;
#pragma unroll
    for (int k = 0; k < 16; k++) {
        int idx = e0 + tid + k * 512;
        meta[k] = 0xFFFFFFFFu;
        val[k] = 0.f;
        lrank[k] = 0;
        if (idx < NNZ_) {
            int r = A_rows[(size_t)t * NNZ_ + idx];
            int c = A_cols[(size_t)t * NNZ_ + idx];
            val[k] = A_val[(size_t)t * NNZ_ + idx];
            int b = r >> 7, rlo = r & 127;
            meta[k] = (unsigned)c | ((unsigned)rlo << 16) | ((unsigned)b << 23);
            lrank[k] = atomicAdd(&cnt[b], 1);
        }
    }
    __syncthreads();
    for (int b = tid; b < NB; b += 512) {
        int n = cnt[b];
        gbase[b] = n ? atomicAdd(&bfill[t * NB + b], n) : 0;
        rbase[b] = bbase[t * NB + b];
    }
    __syncthreads();
#pragma unroll
    for (int k = 0; k < 16; k++) {
        if (meta[k] != 0xFFFFFFFFu) {
            int b = meta[k] >> 23;
            ebuck[(size_t)t * NNZ_ + rbase[b] + gbase[b] + lrank[k]] =
                make_int2((int)meta[k], __float_as_int(val[k]));
        }
    }
}

// ---------- Pass B: per-bucket row count + scan -> row_ptr; sort edges into CSR ----------
__global__ __launch_bounds__(256) void k_bsort(const int* __restrict__ bbase,
                                               const int* __restrict__ bcnt,
                                               const int2* __restrict__ ebuck,
                                               int2* __restrict__ ecv,
                                               int* __restrict__ row_ptr) {
    __shared__ int rcnt[128];
    __shared__ int rex[128];
    __shared__ int rfill[128];
    __shared__ int sbuf[128];
    int t = blockIdx.y, b = blockIdx.x;
    int tid = threadIdx.x;
    int r0 = b << 7;
    int nrows = min(128, N_ - r0);
    int base = bbase[t * NB + b];
    int n = bcnt[t * NB + b];
    if (tid < 128) {
        rcnt[tid] = 0;
        rfill[tid] = 0;
    }
    __syncthreads();
    const int2* src = ebuck + (size_t)t * NNZ_ + base;
    int2* dst = ecv + (size_t)t * NNZ_ + base;
    for (int i = tid; i < n; i += 256) atomicAdd(&rcnt[(src[i].x >> 16) & 127], 1);
    __syncthreads();
    // exclusive scan of rcnt (128 wide)
    if (tid < 128) sbuf[tid] = rcnt[tid];
    __syncthreads();
    for (int off = 1; off < 128; off <<= 1) {
        int x = (tid >= off && tid < 128) ? sbuf[tid - off] : 0;
        __syncthreads();
        if (tid < 128) sbuf[tid] += x;
        __syncthreads();
    }
    if (tid < 128) rex[tid] = sbuf[tid] - rcnt[tid];
    if (tid < nrows) row_ptr[(size_t)t * (N_ + 1) + r0 + tid] = base + sbuf[tid] - rcnt[tid];
    if (b == 0 && tid == 0) row_ptr[(size_t)t * (N_ + 1) + N_] = NNZ_;
    __syncthreads();
    for (int i = tid; i < n; i += 256) {
        int2 e = src[i];
        int rlo = (e.x >> 16) & 127;
        int col = e.x & 0xFFFF;
        int pos = rex[rlo] + atomicAdd(&rfill[rlo], 1);
        dst[pos] = make_int2(col, e.y);
    }
}

// ---------- XWU[t] = Xh[t] @ WU[t]  (bf16 in, bf16 out; k_pq structure) ----------
__global__ __launch_bounds__(256) void k_xwu(const unsigned* __restrict__ Xh,
                                             const float* __restrict__ WU,
                                             unsigned* __restrict__ XWU) {
    __shared__ float AT[32][36];
    __shared__ float WUc[32][128];
    int t = blockIdx.y;
    int rbase = blockIdx.x * 32;
    int tid = threadIdx.x;
    const float* wu = WU + (size_t)t * 16384;
    const unsigned* Xt = Xh + (size_t)t * N_ * 64;
    unsigned* XWUt = XWU + (size_t)t * N_ * 64;
    int cg = tid & 31;
    int rg = tid >> 5;
    float4 acc0 = {0.f, 0.f, 0.f, 0.f};
    float4 acc1 = {0.f, 0.f, 0.f, 0.f};
    float4 acc2 = {0.f, 0.f, 0.f, 0.f};
    float4 acc3 = {0.f, 0.f, 0.f, 0.f};
    int srow = tid >> 3;
    int sk4 = (tid & 7) * 4;
    for (int kc = 0; kc < 128; kc += 32) {
        {
            uint2 u = {0u, 0u};
            int r = rbase + srow;
            if (r < N_) u = *(const uint2*)(Xt + (size_t)r * 64 + (kc >> 1) + (sk4 >> 1));
            AT[sk4 + 0][srow] = bflo(u.x);
            AT[sk4 + 1][srow] = bfhi(u.x);
            AT[sk4 + 2][srow] = bflo(u.y);
            AT[sk4 + 3][srow] = bfhi(u.y);
        }
        {
            const float4* src = (const float4*)(wu + (size_t)kc * 128);
            float4* dst = (float4*)&WUc[0][0];
            dst[tid] = src[tid];
            dst[tid + 256] = src[tid + 256];
            dst[tid + 512] = src[tid + 512];
            dst[tid + 768] = src[tid + 768];
        }
        __syncthreads();
#pragma unroll 4
        for (int kk = 0; kk < 32; kk++) {
            float4 a = *(const float4*)&AT[kk][rg * 4];
            float4 w = *(const float4*)&WUc[kk][cg * 4];
            acc0.x += a.x * w.x; acc0.y += a.x * w.y; acc0.z += a.x * w.z; acc0.w += a.x * w.w;
            acc1.x += a.y * w.x; acc1.y += a.y * w.y; acc1.z += a.y * w.z; acc1.w += a.y * w.w;
            acc2.x += a.z * w.x; acc2.y += a.z * w.y; acc2.z += a.z * w.z; acc2.w += a.z * w.w;
            acc3.x += a.w * w.x; acc3.y += a.w * w.y; acc3.z += a.w * w.z; acc3.w += a.w * w.w;
        }
        __syncthreads();
    }
    int r0 = rbase + rg * 4;
    if (r0 + 0 < N_) {
        uint2 o = {bfpack(acc0.x, acc0.y), bfpack(acc0.z, acc0.w)};
        *(uint2*)(XWUt + (size_t)(r0 + 0) * 64 + cg * 2) = o;
    }
    if (r0 + 1 < N_) {
        uint2 o = {bfpack(acc1.x, acc1.y), bfpack(acc1.z, acc1.w)};
        *(uint2*)(XWUt + (size_t)(r0 + 1) * 64 + cg * 2) = o;
    }
    if (r0 + 2 < N_) {
        uint2 o = {bfpack(acc2.x, acc2.y), bfpack(acc2.z, acc2.w)};
        *(uint2*)(XWUt + (size_t)(r0 + 2) * 64 + cg * 2) = o;
    }
    if (r0 + 3 < N_) {
        uint2 o = {bfpack(acc3.x, acc3.y), bfpack(acc3.z, acc3.w)};
        *(uint2*)(XWUt + (size_t)(r0 + 3) * 64 + cg * 2) = o;
    }
}

// ---------- SpMM2: PQh[t][r] = sum val*XWU[t][col]  (bf16 gather, bf16 out, 16 deep) ----------
__global__ void k_spmm2(const unsigned* __restrict__ XWU, const int* __restrict__ row_ptr,
                        const int2* __restrict__ ecv, unsigned* __restrict__ PQh) {
    int gid = blockIdx.x * 256 + threadIdx.x;
    int wave = gid >> 6, lane = gid & 63;
    if (wave >= T_ * N_) return;
    int t = wave / N_;
    int r = wave - t * N_;
    int s = row_ptr[(size_t)t * (N_ + 1) + r];
    int len = row_ptr[(size_t)t * (N_ + 1) + r + 1] - s;
    const unsigned* Xt = XWU + (size_t)t * N_ * 64 + lane;
    const int2* ev = ecv + (size_t)t * NNZ_;
    float2 acc = {0.f, 0.f};
    for (int base = 0; base < len; base += 64) {
        int nn = min(64, len - base);
        int2 my = {0, 0};
        if (base + lane < len) my = ev[s + base + lane];
        int q = 0;
        for (; q + 16 <= nn; q += 16) {
            int c0 = __shfl(my.x, q + 0);  float v0 = __int_as_float(__shfl(my.y, q + 0));
            int c1 = __shfl(my.x, q + 1);  float v1 = __int_as_float(__shfl(my.y, q + 1));
            int c2 = __shfl(my.x, q + 2);  float v2 = __int_as_float(__shfl(my.y, q + 2));
            int c3 = __shfl(my.x, q + 3);  float v3 = __int_as_float(__shfl(my.y, q + 3));
            int c4 = __shfl(my.x, q + 4);  float v4 = __int_as_float(__shfl(my.y, q + 4));
            int c5 = __shfl(my.x, q + 5);  float v5 = __int_as_float(__shfl(my.y, q + 5));
            int c6 = __shfl(my.x, q + 6);  float v6 = __int_as_float(__shfl(my.y, q + 6));
            int c7 = __shfl(my.x, q + 7);  float v7 = __int_as_float(__shfl(my.y, q + 7));
            int c8 = __shfl(my.x, q + 8);  float v8 = __int_as_float(__shfl(my.y, q + 8));
            int c9 = __shfl(my.x, q + 9);  float v9 = __int_as_float(__shfl(my.y, q + 9));
            int cA = __shfl(my.x, q + 10); float vA = __int_as_float(__shfl(my.y, q + 10));
            int cB = __shfl(my.x, q + 11); float vB = __int_as_float(__shfl(my.y, q + 11));
            int cC = __shfl(my.x, q + 12); float vC = __int_as_float(__shfl(my.y, q + 12));
            int cD = __shfl(my.x, q + 13); float vD = __int_as_float(__shfl(my.y, q + 13));
            int cE = __shfl(my.x, q + 14); float vE = __int_as_float(__shfl(my.y, q + 14));
            int cF = __shfl(my.x, q + 15); float vF = __int_as_float(__shfl(my.y, q + 15));
            unsigned x0 = Xt[(size_t)c0 * 64];
            unsigned x1 = Xt[(size_t)c1 * 64];
            unsigned x2 = Xt[(size_t)c2 * 64];
            unsigned x3 = Xt[(size_t)c3 * 64];
            unsigned x4 = Xt[(size_t)c4 * 64];
            unsigned x5 = Xt[(size_t)c5 * 64];
            unsigned x6 = Xt[(size_t)c6 * 64];
            unsigned x7 = Xt[(size_t)c7 * 64];
            unsigned x8 = Xt[(size_t)c8 * 64];
            unsigned x9 = Xt[(size_t)c9 * 64];
            unsigned xA = Xt[(size_t)cA * 64];
            unsigned xB = Xt[(size_t)cB * 64];
            unsigned xC = Xt[(size_t)cC * 64];
            unsigned xD = Xt[(size_t)cD * 64];
            unsigned xE = Xt[(size_t)cE * 64];
            unsigned xF = Xt[(size_t)cF * 64];
            acc.x += v0 * bflo(x0); acc.y += v0 * bfhi(x0);
            acc.x += v1 * bflo(x1); acc.y += v1 * bfhi(x1);
            acc.x += v2 * bflo(x2); acc.y += v2 * bfhi(x2);
            acc.x += v3 * bflo(x3); acc.y += v3 * bfhi(x3);
            acc.x += v4 * bflo(x4); acc.y += v4 * bfhi(x4);
            acc.x += v5 * bflo(x5); acc.y += v5 * bfhi(x5);
            acc.x += v6 * bflo(x6); acc.y += v6 * bfhi(x6);
            acc.x += v7 * bflo(x7); acc.y += v7 * bfhi(x7);
            acc.x += v8 * bflo(x8); acc.y += v8 * bfhi(x8);
            acc.x += v9 * bflo(x9); acc.y += v9 * bfhi(x9);
            acc.x += vA * bflo(xA); acc.y += vA * bfhi(xA);
            acc.x += vB * bflo(xB); acc.y += vB * bfhi(xB);
            acc.x += vC * bflo(xC); acc.y += vC * bfhi(xC);
            acc.x += vD * bflo(xD); acc.y += vD * bfhi(xD);
            acc.x += vE * bflo(xE); acc.y += vE * bfhi(xE);
            acc.x += vF * bflo(xF); acc.y += vF * bfhi(xF);
        }
        for (; q + 8 <= nn; q += 8) {
            int c0 = __shfl(my.x, q + 0); float v0 = __int_as_float(__shfl(my.y, q + 0));
            int c1 = __shfl(my.x, q + 1); float v1 = __int_as_float(__shfl(my.y, q + 1));
            int c2 = __shfl(my.x, q + 2); float v2 = __int_as_float(__shfl(my.y, q + 2));
            int c3 = __shfl(my.x, q + 3); float v3 = __int_as_float(__shfl(my.y, q + 3));
            int c4 = __shfl(my.x, q + 4); float v4 = __int_as_float(__shfl(my.y, q + 4));
            int c5 = __shfl(my.x, q + 5); float v5 = __int_as_float(__shfl(my.y, q + 5));
            int c6 = __shfl(my.x, q + 6); float v6 = __int_as_float(__shfl(my.y, q + 6));
            int c7 = __shfl(my.x, q + 7); float v7 = __int_as_float(__shfl(my.y, q + 7));
            unsigned x0 = Xt[(size_t)c0 * 64];
            unsigned x1 = Xt[(size_t)c1 * 64];
            unsigned x2 = Xt[(size_t)c2 * 64];
            unsigned x3 = Xt[(size_t)c3 * 64];
            unsigned x4 = Xt[(size_t)c4 * 64];
            unsigned x5 = Xt[(size_t)c5 * 64];
            unsigned x6 = Xt[(size_t)c6 * 64];
            unsigned x7 = Xt[(size_t)c7 * 64];
            acc.x += v0 * bflo(x0); acc.y += v0 * bfhi(x0);
            acc.x += v1 * bflo(x1); acc.y += v1 * bfhi(x1);
            acc.x += v2 * bflo(x2); acc.y += v2 * bfhi(x2);
            acc.x += v3 * bflo(x3); acc.y += v3 * bfhi(x3);
            acc.x += v4 * bflo(x4); acc.y += v4 * bfhi(x4);
            acc.x += v5 * bflo(x5); acc.y += v5 * bfhi(x5);
            acc.x += v6 * bflo(x6); acc.y += v6 * bfhi(x6);
            acc.x += v7 * bflo(x7); acc.y += v7 * bfhi(x7);
        }
        for (; q < nn; q++) {
            int c = __shfl(my.x, q);
            float v = __int_as_float(__shfl(my.y, q));
            unsigned xp = Xt[(size_t)c * 64];
            acc.x += v * bflo(xp);
            acc.y += v * bfhi(xp);
        }
    }
    PQh[(size_t)wave * 64 + lane] = bfpack(acc.x, acc.y);
}

// fallback (fp32 gather) if workspace can't hold Xh
__global__ void k_spmm_f32(const float* __restrict__ X, const int* __restrict__ row_ptr,
                           const int2* __restrict__ ecv, float* __restrict__ AH) {
    int gid = blockIdx.x * 256 + threadIdx.x;
    int wave = gid >> 6, lane = gid & 63;
    if (wave >= T_ * N_) return;
    int t = wave / N_;
    int r = wave - t * N_;
    int s = row_ptr[(size_t)t * (N_ + 1) + r];
    int len = row_ptr[(size_t)t * (N_ + 1) + r + 1] - s;
    const float2* Xt = (const float2*)(X + (size_t)t * N_ * F0_);
    const int2* ev = ecv + (size_t)t * NNZ_;
    float2 acc = {0.f, 0.f};
    for (int base = 0; base < len; base += 64) {
        int nn = min(64, len - base);
        int2 my = {0, 0};
        if (base + lane < len) my = ev[s + base + lane];
        for (int q = 0; q < nn; q++) {
            int c = __shfl(my.x, q);
            float v = __int_as_float(__shfl(my.y, q));
            float2 x = Xt[(size_t)c * 64 + lane];
            acc.x += v * x.x;
            acc.y += v * x.y;
        }
    }
    ((float2*)AH)[(size_t)wave * 64 + lane] = acc;
}

// ---------- fused GRU step (column-separable): one launch per t ----------
__global__ __launch_bounds__(256) void k_gru(const float* __restrict__ AZt,
                                             const float* __restrict__ ARt,
                                             const float* __restrict__ AHt,
                                             const float* __restrict__ UZ,
                                             const float* __restrict__ UR,
                                             const float* __restrict__ UH,
                                             const float* __restrict__ Wprev,
                                             float* __restrict__ Wnew) {
    __shared__ float RWs[128][2];
    int jl = threadIdx.x >> 7;  // 0..1
    int i = threadIdx.x & 127;
    int j = blockIdx.x * 2 + jl;
    int gid = i * 128 + j;
    float az = AZt[gid], ar = ARt[gid];
    for (int k = 0; k < 128; k++) {
        float w = Wprev[k * 128 + j];  // wave-uniform broadcast
        az += UZ[i * 128 + k] * w;
        ar += UR[i * 128 + k] * w;
    }
    float zg = 1.f / (1.f + expf(-az));
    float rg = 1.f / (1.f + expf(-ar));
    RWs[i][jl] = rg * Wprev[gid];
    __syncthreads();
    float acc = AHt[gid];
    for (int k = 0; k < 128; k++) acc += UH[i * 128 + k] * RWs[k][jl];
    float ht = tanhf(acc);
    float w0 = Wprev[gid];
    Wnew[gid] = (1.f - zg) * w0 + zg * ht;
}

// ---------- WU[t][k][h2] = sum_m W_t[k][m] * U[(h2<64? m : 128+m)][h2&63] ----------
__global__ void k_wu(const float* __restrict__ W_seq, const float* __restrict__ U,
                     float* __restrict__ WU) {
    int blk = blockIdx.x;  // t*128 + k
    int t = blk >> 7, k = blk & 127;
    int h2 = threadIdx.x;
    const float* Wt = W_seq + (size_t)t * 16384;
    int h = h2 & 63;
    const float* Ub = U + (h2 < 64 ? 0 : 128 * 64);
    float acc = 0.f;
    for (int m = 0; m < 128; m++) acc += Wt[k * 128 + m] * Ub[m * 64 + h];
    WU[((size_t)t * 128 + k) * 128 + h2] = acc;
}

// fp32 in-place fallback GEMM (AH -> PQ in place)
__global__ __launch_bounds__(256) void k_pq_f32(float* __restrict__ AH,
                                                const float* __restrict__ WU) {
    __shared__ float AT[32][36];
    __shared__ float WUc[32][128];
    int t = blockIdx.y;
    int rbase = blockIdx.x * 32;
    int tid = threadIdx.x;
    const float* wu = WU + (size_t)t * 16384;
    float* AHt = AH + (size_t)t * N_ * F0_;
    int cg = tid & 31;
    int rg = tid >> 5;
    float4 acc0 = {0.f, 0.f, 0.f, 0.f};
    float4 acc1 = {0.f, 0.f, 0.f, 0.f};
    float4 acc2 = {0.f, 0.f, 0.f, 0.f};
    float4 acc3 = {0.f, 0.f, 0.f, 0.f};
    int srow = tid >> 3;
    int sk4 = (tid & 7) * 4;
    for (int kc = 0; kc < 128; kc += 32) {
        {
            float4 v = {0.f, 0.f, 0.f, 0.f};
            int r = rbase + srow;
            if (r < N_) v = *(const float4*)(AHt + (size_t)r * F0_ + kc + sk4);
            AT[sk4 + 0][srow] = v.x;
            AT[sk4 + 1][srow] = v.y;
            AT[sk4 + 2][srow] = v.z;
            AT[sk4 + 3][srow] = v.w;
        }
        {
            const float4* src = (const float4*)(wu + (size_t)kc * 128);
            float4* dst = (float4*)&WUc[0][0];
            dst[tid] = src[tid];
            dst[tid + 256] = src[tid + 256];
            dst[tid + 512] = src[tid + 512];
            dst[tid + 768] = src[tid + 768];
        }
        __syncthreads();
#pragma unroll 4
        for (int kk = 0; kk < 32; kk++) {
            float4 a = *(const float4*)&AT[kk][rg * 4];
            float4 w = *(const float4*)&WUc[kk][cg * 4];
            acc0.x += a.x * w.x; acc0.y += a.x * w.y; acc0.z += a.x * w.z; acc0.w += a.x * w.w;
            acc1.x += a.y * w.x; acc1.y += a.y * w.y; acc1.z += a.y * w.z; acc1.w += a.y * w.w;
            acc2.x += a.z * w.x; acc2.y += a.z * w.y; acc2.z += a.z * w.z; acc2.w += a.z * w.w;
            acc3.x += a.w * w.x; acc3.y += a.w * w.y; acc3.z += a.w * w.z; acc3.w += a.w * w.w;
        }
        __syncthreads();
    }
    int r0 = rbase + rg * 4;
    if (r0 + 0 < N_) *(float4*)(AHt + (size_t)(r0 + 0) * F0_ + cg * 4) = acc0;
    if (r0 + 1 < N_) *(float4*)(AHt + (size_t)(r0 + 1) * F0_ + cg * 4) = acc1;
    if (r0 + 2 < N_) *(float4*)(AHt + (size_t)(r0 + 2) * F0_ + cg * 4) = acc2;
    if (r0 + 3 < N_) *(float4*)(AHt + (size_t)(r0 + 3) * F0_ + cg * 4) = acc3;
}

// ---------- out[e] = P[flat_src] + Q[flat_trg]  (bf16 PQh) ----------
__global__ void k_final(const unsigned* __restrict__ PQh, const int* __restrict__ et,
                        const int* __restrict__ es, const int* __restrict__ eg,
                        float* __restrict__ out) {
    int gid = blockIdx.x * 256 + threadIdx.x;  // e*16 + q
    if (gid >= E_ * 16) return;
    int e = gid >> 4, q = gid & 15;
    int t = et[e];
    const uint2 a = *(const uint2*)(PQh + ((size_t)(t * N_ + es[e])) * 64 + q * 2);
    const uint2 b = *(const uint2*)(PQh + ((size_t)(t * N_ + eg[e])) * 64 + 32 + q * 2);
    float4 o;
    o.x = bflo(a.x) + bflo(b.x);
    o.y = bfhi(a.x) + bfhi(b.x);
    o.z = bflo(a.y) + bflo(b.y);
    o.w = bfhi(a.y) + bfhi(b.y);
    *(float4*)(out + (size_t)e * 64 + q * 4) = o;
}

__global__ void k_final_f32(const float* __restrict__ PQ, const int* __restrict__ et,
                            const int* __restrict__ es, const int* __restrict__ eg,
                            float* __restrict__ out) {
    int gid = blockIdx.x * 256 + threadIdx.x;  // e*16 + q
    if (gid >= E_ * 16) return;
    int e = gid >> 4, q = gid & 15;
    int t = et[e];
    const float4 a = *(const float4*)(PQ + ((size_t)(t * N_ + es[e])) * 128 + q * 4);
    const float4 b = *(const float4*)(PQ + ((size_t)(t * N_ + eg[e])) * 128 + 64 + q * 4);
    float4 o = {a.x + b.x, a.y + b.y, a.z + b.z, a.w + b.w};
    *(float4*)(out + (size_t)e * 64 + q * 4) = o;
}

__global__ void k_wfin(const float* __restrict__ W_seq, float* __restrict__ out) {
    int gid = blockIdx.x * 256 + threadIdx.x;
    out[(size_t)E_ * 64 + gid] = W_seq[(size_t)7 * 16384 + gid];
}

// ---------- launch ----------
extern "C" void kernel_launch(void* const* d_in, const int* in_sizes, int n_in,
                              void* d_out, int out_size, void* d_ws, size_t ws_size,
                              hipStream_t stream) {
    const float* X = (const float*)d_in[0];
    const int* A_rows = (const int*)d_in[1];
    const int* A_cols = (const int*)d_in[2];
    const float* A_val = (const float*)d_in[3];
    const int* edge_time = (const int*)d_in[4];
    const int* edge_src = (const int*)d_in[5];
    const int* edge_trg = (const int*)d_in[6];
    const float* p = (const float*)d_in[7];
    const float* W_Z = (const float*)d_in[8];
    const float* U_Z = (const float*)d_in[9];
    const float* B_Z = (const float*)d_in[10];
    const float* W_R = (const float*)d_in[11];
    const float* U_R = (const float*)d_in[12];
    const float* B_R = (const float*)d_in[13];
    const float* W_H = (const float*)d_in[14];
    const float* U_H = (const float*)d_in[15];
    const float* B_H = (const float*)d_in[16];
    const float* W_init = (const float*)d_in[17];
    const float* U = (const float*)d_in[18];
    float* out = (float*)d_out;

    char* ws = (char*)d_ws;
    size_t off = 0;
    auto take = [&](size_t bytes) {
        char* ptr = ws + off;
        off = (off + bytes + 255) & ~(size_t)255;
        return (void*)ptr;
    };
    float* AHreg = (float*)take((size_t)T_ * N_ * F0_ * 4);  // 204.8 MB: ebuck / XWU+PQh / AH(fallback)
    int2* ecv = (int2*)take((size_t)T_ * NNZ_ * 8);          // 51.2 MB final CSR
    float* yv = (float*)take((size_t)T_ * N_ * 4);
    int* row_ptr = (int*)take((size_t)T_ * (N_ + 1) * 4);
    int* bcnt = (int*)take((size_t)T_ * NB * 4);
    int* bbase = (int*)take((size_t)T_ * NB * 4);
    int* bfill = (int*)take((size_t)T_ * NB * 4);
    float* p_hat = (float*)take(512);
    float* topv = (float*)take((size_t)T_ * K_ * 4);
    int* topidx = (int*)take((size_t)T_ * K_ * 4);
    float* Z = (float*)take((size_t)T_ * F0_ * K_ * 4);
    float* AZb = (float*)take((size_t)T_ * 16384 * 4);
    float* ARb = (float*)take((size_t)T_ * 16384 * 4);
    float* AHb = (float*)take((size_t)T_ * 16384 * 4);
    float* W_seq = (float*)take((size_t)T_ * 16384 * 4);
    float* WU = (float*)take((size_t)T_ * 16384 * 4);
    unsigned* Xh = (unsigned*)take((size_t)T_ * N_ * 64 * 4);  // 102.4 MB bf16 X
    bool use_bf16 = (off <= ws_size);
    int2* ebuck = (int2*)AHreg;                 // dead after k_bsort
    unsigned* XWU = (unsigned*)AHreg;           // first 102.4 MB
    unsigned* PQh = XWU + (size_t)T_ * N_ * 64; // second 102.4 MB

    hipMemsetAsync(bcnt, 0, (size_t)T_ * NB * 4, stream);
    hipMemsetAsync(bfill, 0, (size_t)T_ * NB * 4, stream);

    k_phat<<<1, 128, 0, stream>>>(p, p_hat);
    k_y<<<(T_ * N_ * 64) / 256, 256, 0, stream>>>(X, p_hat, yv, use_bf16 ? Xh : nullptr);
    k_topk<<<T_, 1024, 0, stream>>>(yv, topv, topidx);
    k_z<<<(T_ * F0_ * K_) / 256, 256, 0, stream>>>(X, topv, topidx, Z);
    k_az<<<(3 * T_ * 16384) / 256, 256, 0, stream>>>(W_Z, W_R, W_H, B_Z, B_R, B_H, Z,
                                                     AZb, ARb, AHb);
    {
        dim3 gA((NNZ_ + BCH - 1) / BCH, T_);  // 98 x 8
        k_cnt<<<gA, 512, 0, stream>>>(A_rows, bcnt);
        k_bscan<<<T_, 512, 0, stream>>>(bcnt, bbase);
        k_binA<<<gA, 512, 0, stream>>>(A_rows, A_cols, A_val, bbase, bfill, ebuck);
        dim3 gB(NB, T_);                      // 391 x 8
        k_bsort<<<gB, 256, 0, stream>>>(bbase, bcnt, ebuck, ecv, row_ptr);
    }
    for (int t = 0; t < T_; t++) {
        const float* Wprev = (t == 0) ? W_init : (W_seq + (size_t)(t - 1) * 16384);
        k_gru<<<64, 256, 0, stream>>>(AZb + (size_t)t * 16384, ARb + (size_t)t * 16384,
                                      AHb + (size_t)t * 16384, U_Z, U_R, U_H, Wprev,
                                      W_seq + (size_t)t * 16384);
    }
    k_wu<<<T_ * 128, 128, 0, stream>>>(W_seq, U, WU);
    if (use_bf16) {
        dim3 g((N_ + 31) / 32, T_);
        k_xwu<<<g, 256, 0, stream>>>(Xh, WU, XWU);
        k_spmm2<<<(T_ * N_ * 64) / 256, 256, 0, stream>>>(XWU, row_ptr, ecv, PQh);
        k_final<<<(E_ * 16) / 256, 256, 0, stream>>>(PQh, edge_time, edge_src,
                                                     edge_trg, out);
    } else {
        float* AH = AHreg;
        k_spmm_f32<<<(T_ * N_ * 64) / 256, 256, 0, stream>>>(X, row_ptr, ecv, AH);
        dim3 g((N_ + 31) / 32, T_);
        k_pq_f32<<<g, 256, 0, stream>>>(AH, WU);
        k_final_f32<<<(E_ * 16) / 256, 256, 0, stream>>>(AH, edge_time, edge_src,
                                                         edge_trg, out);
    }
    k_wfin<<<(F0_ * H0_) / 256, 256, 0, stream>>>(W_seq, out);
}

// Round 9
// 937.228 us; speedup vs baseline: 11.3562x; 1.0183x over previous
//
#include <hip/hip_runtime.h>
#include <math.h>

#define T_ 8
#define N_ 50000
#define F0_ 128
#define H0_ 128
#define H1_ 64
#define NNZ_ 800000
#define E_ 1000000
#define K_ 128
#define CAP_ 3072
#define NB 391   // ceil(N_/128) buckets of 128 rows
#define BCH 8192 // edges per chunk block

// ---------- helpers ----------
__device__ inline unsigned ford(float f) {
    unsigned b = __float_as_uint(f);
    return (b & 0x80000000u) ? ~b : (b | 0x80000000u);
}
__device__ inline float funord(unsigned u) {
    unsigned b = (u & 0x80000000u) ? (u & 0x7fffffffu) : ~u;
    return __uint_as_float(b);
}
__device__ inline unsigned bfr(float f) {  // fp32 -> bf16 bits (RNE)
    unsigned u = __float_as_uint(f);
    return (u + 0x7fffu + ((u >> 16) & 1u)) >> 16;
}
__device__ inline unsigned bfpack(float lo, float hi) { return bfr(lo) | (bfr(hi) << 16); }
__device__ inline float bflo(unsigned u) { return __uint_as_float(u << 16); }
__device__ inline float bfhi(unsigned u) { return __uint_as_float(u & 0xffff0000u); }

// ---------- p_hat = p / ||p|| ----------
__global__ void k_phat(const float* p, float* p_hat) {
    __shared__ float s[128];
    int i = threadIdx.x;
    float v = p[i];
    s[i] = v * v;
    __syncthreads();
    for (int off = 64; off > 0; off >>= 1) {
        if (i < off) s[i] += s[i + off];
        __syncthreads();
    }
    p_hat[i] = v / sqrtf(s[0]);
}

// ---------- y = X @ p_hat (wave/row) + bf16 copy of X ----------
__global__ void k_y(const float* __restrict__ X, const float* __restrict__ p_hat,
                    float* __restrict__ y, unsigned* __restrict__ Xh) {
    int gid = blockIdx.x * 256 + threadIdx.x;
    int wave = gid >> 6, lane = gid & 63;
    if (wave >= T_ * N_) return;
    const float2* xr = (const float2*)(X + (size_t)wave * F0_);
    float2 a = xr[lane];
    if (Xh) Xh[(size_t)wave * 64 + lane] = bfpack(a.x, a.y);
    float2 ph = ((const float2*)p_hat)[lane];
    float acc = a.x * ph.x + a.y * ph.y;
#pragma unroll
    for (int off = 32; off > 0; off >>= 1) acc += __shfl_down(acc, off);
    if (lane == 0) y[wave] = acc;
}

// ---------- exact top-128 per t: 2-level radix select + exact rank ----------
__global__ __launch_bounds__(1024) void k_topk(const float* __restrict__ y,
                                               float* __restrict__ topv,
                                               int* __restrict__ topidx) {
    int t = blockIdx.x;
    const float* yt = y + (size_t)t * N_;
    __shared__ int hist[256];
    __shared__ int sb1, sAbove, sP, scand;
    __shared__ unsigned cu[CAP_];
    __shared__ int cidx[CAP_];
    int tid = threadIdx.x;

    if (tid < 256) hist[tid] = 0;
    __syncthreads();
    for (int i = tid; i < N_; i += 1024) {
        unsigned u = ford(yt[i]);
        atomicAdd(&hist[u >> 24], 1);
    }
    __syncthreads();
    if (tid == 0) {
        int acc = 0, b = 255;
        for (; b >= 0; b--) { acc += hist[b]; if (acc >= K_) break; }
        sb1 = b;
        sAbove = acc - hist[b];
    }
    __syncthreads();
    int b1 = sb1;
    if (tid < 256) hist[tid] = 0;
    __syncthreads();
    for (int i = tid; i < N_; i += 1024) {
        unsigned u = ford(yt[i]);
        if ((int)(u >> 24) == b1) atomicAdd(&hist[(u >> 16) & 255], 1);
    }
    __syncthreads();
    if (tid == 0) {
        int acc = sAbove, b = 255;
        for (; b >= 0; b--) { acc += hist[b]; if (acc >= K_) break; }
        sP = (b1 << 8) | b;
        scand = 0;
    }
    __syncthreads();
    unsigned P = (unsigned)sP;
    for (int i = tid; i < N_; i += 1024) {
        unsigned u = ford(yt[i]);
        if ((u >> 16) >= P) {
            int pos = atomicAdd(&scand, 1);
            if (pos < CAP_) { cu[pos] = u; cidx[pos] = i; }
        }
    }
    __syncthreads();
    int C = min(scand, CAP_);
    for (int c = tid; c < C; c += 1024) {
        unsigned uc = cu[c];
        int ic = cidx[c];
        int rank = 0;
        for (int o = 0; o < C; o++) {
            unsigned uo = cu[o];
            rank += (uo > uc) || (uo == uc && cidx[o] < ic);
        }
        if (rank < K_) {
            topv[t * K_ + rank] = funord(uc);
            topidx[t * K_ + rank] = ic;
        }
    }
}

// ---------- Z[t][f][j] = X[t][idx[j]][f] * topv[j] ----------
__global__ void k_z(const float* __restrict__ X, const float* __restrict__ topv,
                    const int* __restrict__ topidx, float* __restrict__ Z) {
    int gid = blockIdx.x * 256 + threadIdx.x;  // t*16384 + f*128 + j
    if (gid >= T_ * F0_ * K_) return;
    int j = gid & 127;
    int f = (gid >> 7) & 127;
    int t = gid >> 14;
    int idx = topidx[t * K_ + j];
    float v = topv[t * K_ + j];
    Z[gid] = X[((size_t)(t * N_ + idx)) * F0_ + f] * v;
}

// ---------- A_g[t] = W_g @ Z_t + B_g  (g in {Z,R,H}, all t parallel) ----------
__global__ void k_az(const float* __restrict__ WZ, const float* __restrict__ WR,
                     const float* __restrict__ WH, const float* __restrict__ BZ,
                     const float* __restrict__ BR, const float* __restrict__ BH,
                     const float* __restrict__ Z, float* __restrict__ AZ,
                     float* __restrict__ AR, float* __restrict__ AHo) {
    int gid = blockIdx.x * 256 + threadIdx.x;  // g*131072 + t*16384 + i*128 + j
    int j = gid & 127;
    int i = (gid >> 7) & 127;
    int t = (gid >> 14) & 7;
    int g = gid >> 17;
    const float* W = (g == 0) ? WZ : (g == 1) ? WR : WH;
    const float* B = (g == 0) ? BZ : (g == 1) ? BR : BH;
    float* Ao = (g == 0) ? AZ : (g == 1) ? AR : AHo;
    const float* Zt = Z + (size_t)t * 16384;
    float acc = B[i * 128 + j];
    for (int k = 0; k < 128; k++) acc += W[i * 128 + k] * Zt[k * 128 + j];
    Ao[(size_t)(t * 128 + i) * 128 + j] = acc;
}

// ---------- CSR build pass 0: bucket counts via LDS histogram ----------
__global__ __launch_bounds__(512) void k_cnt(const int* __restrict__ A_rows,
                                             int* __restrict__ bcnt) {
    __shared__ int cnt[NB];
    int t = blockIdx.y, ci = blockIdx.x;
    int tid = threadIdx.x;
    for (int i = tid; i < NB; i += 512) cnt[i] = 0;
    __syncthreads();
    int e0 = ci * BCH;
#pragma unroll
    for (int k = 0; k < 16; k++) {
        int idx = e0 + tid + k * 512;
        if (idx < NNZ_) atomicAdd(&cnt[A_rows[(size_t)t * NNZ_ + idx] >> 7], 1);
    }
    __syncthreads();
    for (int b = tid; b < NB; b += 512)
        if (cnt[b]) atomicAdd(&bcnt[t * NB + b], cnt[b]);
}

// ---------- bucket scan: bbase[t][b] = excl prefix of bcnt[t][*] ----------
__global__ __launch_bounds__(512) void k_bscan(const int* __restrict__ bcnt,
                                               int* __restrict__ bbase) {
    int t = blockIdx.x;
    int tid = threadIdx.x;
    __shared__ int buf[512];
    int v = (tid < NB) ? bcnt[t * NB + tid] : 0;
    buf[tid] = v;
    __syncthreads();
    for (int off = 1; off < 512; off <<= 1) {
        int x = (tid >= off) ? buf[tid - off] : 0;
        __syncthreads();
        buf[tid] += x;
        __syncthreads();
    }
    if (tid < NB) bbase[t * NB + tid] = buf[tid] - v;
}

// ---------- Pass A: bin edges into 128-row buckets, group-contiguous writes ----------
// meta = col(16b) | rlo(7b)<<16 | b(9b)<<23 ; sentinel 0xFFFFFFFF (b=511 impossible)
__global__ __launch_bounds__(512) void k_binA(const int* __restrict__ A_rows,
                                              const int* __restrict__ A_cols,
                                              const float* __restrict__ A_val,
                                              const int* __restrict__ bbase,
                                              int* __restrict__ bfill,
                                              int2* __restrict__ ebuck) {
    __shared__ int cnt[NB];
    __shared__ int gbase[NB];
    __shared__ int rbase[NB];
    int t = blockIdx.y, ci = blockIdx.x;
    int tid = threadIdx.x;
    for (int i = tid; i < NB; i += 512) cnt[i] = 0;
    __syncthreads();
    unsigned meta[16];
    float val[16];
    int lrank[16];
    int e0 = ci * BCH;
#pragma unroll
    for (int k = 0; k < 16; k++) {
        int idx = e0 + tid + k * 512;
        meta[k] = 0xFFFFFFFFu;
        val[k] = 0.f;
        lrank[k] = 0;
        if (idx < NNZ_) {
            int r = A_rows[(size_t)t * NNZ_ + idx];
            int c = A_cols[(size_t)t * NNZ_ + idx];
            val[k] = A_val[(size_t)t * NNZ_ + idx];
            int b = r >> 7, rlo = r & 127;
            meta[k] = (unsigned)c | ((unsigned)rlo << 16) | ((unsigned)b << 23);
            lrank[k] = atomicAdd(&cnt[b], 1);
        }
    }
    __syncthreads();
    for (int b = tid; b < NB; b += 512) {
        int n = cnt[b];
        gbase[b] = n ? atomicAdd(&bfill[t * NB + b], n) : 0;
        rbase[b] = bbase[t * NB + b];
    }
    __syncthreads();
#pragma unroll
    for (int k = 0; k < 16; k++) {
        if (meta[k] != 0xFFFFFFFFu) {
            int b = meta[k] >> 23;
            ebuck[(size_t)t * NNZ_ + rbase[b] + gbase[b] + lrank[k]] =
                make_int2((int)meta[k], __float_as_int(val[k]));
        }
    }
}

// ---------- Pass B: per-bucket row count + scan -> row_ptr; sort edges into CSR ----------
__global__ __launch_bounds__(256) void k_bsort(const int* __restrict__ bbase,
                                               const int* __restrict__ bcnt,
                                               const int2* __restrict__ ebuck,
                                               int2* __restrict__ ecv,
                                               int* __restrict__ row_ptr) {
    __shared__ int rcnt[128];
    __shared__ int rex[128];
    __shared__ int rfill[128];
    __shared__ int sbuf[128];
    int t = blockIdx.y, b = blockIdx.x;
    int tid = threadIdx.x;
    int r0 = b << 7;
    int nrows = min(128, N_ - r0);
    int base = bbase[t * NB + b];
    int n = bcnt[t * NB + b];
    if (tid < 128) {
        rcnt[tid] = 0;
        rfill[tid] = 0;
    }
    __syncthreads();
    const int2* src = ebuck + (size_t)t * NNZ_ + base;
    int2* dst = ecv + (size_t)t * NNZ_ + base;
    for (int i = tid; i < n; i += 256) atomicAdd(&rcnt[(src[i].x >> 16) & 127], 1);
    __syncthreads();
    // exclusive scan of rcnt (128 wide)
    if (tid < 128) sbuf[tid] = rcnt[tid];
    __syncthreads();
    for (int off = 1; off < 128; off <<= 1) {
        int x = (tid >= off && tid < 128) ? sbuf[tid - off] : 0;
        __syncthreads();
        if (tid < 128) sbuf[tid] += x;
        __syncthreads();
    }
    if (tid < 128) rex[tid] = sbuf[tid] - rcnt[tid];
    if (tid < nrows) row_ptr[(size_t)t * (N_ + 1) + r0 + tid] = base + sbuf[tid] - rcnt[tid];
    if (b == 0 && tid == 0) row_ptr[(size_t)t * (N_ + 1) + N_] = NNZ_;
    __syncthreads();
    for (int i = tid; i < n; i += 256) {
        int2 e = src[i];
        int rlo = (e.x >> 16) & 127;
        int col = e.x & 0xFFFF;
        int pos = rex[rlo] + atomicAdd(&rfill[rlo], 1);
        dst[pos] = make_int2(col, e.y);
    }
}

// ---------- fused 8-step GRU, column-separable: block owns 2 columns across all t ----------
// W_seqT layout: [t][col j][row k]  (transposed vs reference W[k][j])
__global__ __launch_bounds__(256) void k_gru8(const float* __restrict__ AZb,
                                              const float* __restrict__ ARb,
                                              const float* __restrict__ AHb,
                                              const float* __restrict__ UZ,
                                              const float* __restrict__ UR,
                                              const float* __restrict__ UH,
                                              const float* __restrict__ W_init,
                                              float* __restrict__ WT) {
    __shared__ float Wc[128][2];
    __shared__ float RWs[128][2];
    int jl = threadIdx.x >> 7;  // 0..1
    int i = threadIdx.x & 127;
    int j = blockIdx.x * 2 + jl;
    Wc[i][jl] = W_init[i * 128 + j];
    __syncthreads();
    for (int t = 0; t < T_; t++) {
        const float* AZt = AZb + (size_t)t * 16384;
        const float* ARt = ARb + (size_t)t * 16384;
        const float* AHt = AHb + (size_t)t * 16384;
        float az = AZt[i * 128 + j], ar = ARt[i * 128 + j];
        for (int k = 0; k < 128; k++) {
            float w = Wc[k][jl];  // LDS broadcast
            az += UZ[i * 128 + k] * w;
            ar += UR[i * 128 + k] * w;
        }
        float zg = 1.f / (1.f + expf(-az));
        float rg = 1.f / (1.f + expf(-ar));
        float wself = Wc[i][jl];
        RWs[i][jl] = rg * wself;
        __syncthreads();
        float acc = AHt[i * 128 + j];
        for (int k = 0; k < 128; k++) acc += UH[i * 128 + k] * RWs[k][jl];
        float ht = tanhf(acc);
        float nw = (1.f - zg) * wself + zg * ht;
        __syncthreads();
        Wc[i][jl] = nw;
        WT[((size_t)t * 128 + j) * 128 + i] = nw;  // coalesced in i
        __syncthreads();
    }
}

// ---------- WU[t][k][h2] = sum_m W_t[k][m] * U[(h2<64? m : 128+m)][h2&63] ----------
// W_t[k][m] = WT[t][m][k]
__global__ void k_wu(const float* __restrict__ WT, const float* __restrict__ U,
                     float* __restrict__ WU) {
    int blk = blockIdx.x;  // t*128 + k
    int t = blk >> 7, k = blk & 127;
    int h2 = threadIdx.x;
    int h = h2 & 63;
    const float* Ub = U + (h2 < 64 ? 0 : 128 * 64);
    float acc = 0.f;
    for (int m = 0; m < 128; m++)
        acc += WT[((size_t)t * 128 + m) * 128 + k] * Ub[m * 64 + h];
    WU[((size_t)t * 128 + k) * 128 + h2] = acc;
}

// ---------- XWU[t] = Xh[t] @ WU[t]  (bf16 in, bf16 out) ----------
__global__ __launch_bounds__(256) void k_xwu(const unsigned* __restrict__ Xh,
                                             const float* __restrict__ WU,
                                             unsigned* __restrict__ XWU) {
    __shared__ float AT[32][36];
    __shared__ float WUc[32][128];
    int t = blockIdx.y;
    int rbase = blockIdx.x * 32;
    int tid = threadIdx.x;
    const float* wu = WU + (size_t)t * 16384;
    const unsigned* Xt = Xh + (size_t)t * N_ * 64;
    unsigned* XWUt = XWU + (size_t)t * N_ * 64;
    int cg = tid & 31;
    int rg = tid >> 5;
    float4 acc0 = {0.f, 0.f, 0.f, 0.f};
    float4 acc1 = {0.f, 0.f, 0.f, 0.f};
    float4 acc2 = {0.f, 0.f, 0.f, 0.f};
    float4 acc3 = {0.f, 0.f, 0.f, 0.f};
    int srow = tid >> 3;
    int sk4 = (tid & 7) * 4;
    for (int kc = 0; kc < 128; kc += 32) {
        {
            uint2 u = {0u, 0u};
            int r = rbase + srow;
            if (r < N_) u = *(const uint2*)(Xt + (size_t)r * 64 + (kc >> 1) + (sk4 >> 1));
            AT[sk4 + 0][srow] = bflo(u.x);
            AT[sk4 + 1][srow] = bfhi(u.x);
            AT[sk4 + 2][srow] = bflo(u.y);
            AT[sk4 + 3][srow] = bfhi(u.y);
        }
        {
            const float4* src = (const float4*)(wu + (size_t)kc * 128);
            float4* dst = (float4*)&WUc[0][0];
            dst[tid] = src[tid];
            dst[tid + 256] = src[tid + 256];
            dst[tid + 512] = src[tid + 512];
            dst[tid + 768] = src[tid + 768];
        }
        __syncthreads();
#pragma unroll 4
        for (int kk = 0; kk < 32; kk++) {
            float4 a = *(const float4*)&AT[kk][rg * 4];
            float4 w = *(const float4*)&WUc[kk][cg * 4];
            acc0.x += a.x * w.x; acc0.y += a.x * w.y; acc0.z += a.x * w.z; acc0.w += a.x * w.w;
            acc1.x += a.y * w.x; acc1.y += a.y * w.y; acc1.z += a.y * w.z; acc1.w += a.y * w.w;
            acc2.x += a.z * w.x; acc2.y += a.z * w.y; acc2.z += a.z * w.z; acc2.w += a.z * w.w;
            acc3.x += a.w * w.x; acc3.y += a.w * w.y; acc3.z += a.w * w.z; acc3.w += a.w * w.w;
        }
        __syncthreads();
    }
    int r0 = rbase + rg * 4;
    if (r0 + 0 < N_) {
        uint2 o = {bfpack(acc0.x, acc0.y), bfpack(acc0.z, acc0.w)};
        *(uint2*)(XWUt + (size_t)(r0 + 0) * 64 + cg * 2) = o;
    }
    if (r0 + 1 < N_) {
        uint2 o = {bfpack(acc1.x, acc1.y), bfpack(acc1.z, acc1.w)};
        *(uint2*)(XWUt + (size_t)(r0 + 1) * 64 + cg * 2) = o;
    }
    if (r0 + 2 < N_) {
        uint2 o = {bfpack(acc2.x, acc2.y), bfpack(acc2.z, acc2.w)};
        *(uint2*)(XWUt + (size_t)(r0 + 2) * 64 + cg * 2) = o;
    }
    if (r0 + 3 < N_) {
        uint2 o = {bfpack(acc3.x, acc3.y), bfpack(acc3.z, acc3.w)};
        *(uint2*)(XWUt + (size_t)(r0 + 3) * 64 + cg * 2) = o;
    }
}

// ---------- SpMM2 half-wave: 2 edges per VMEM instr; lanes 0-31 edge q, 32-63 edge q+1 ----------
#define PAIRSEL(J, QOFF)                                                        \
    {                                                                           \
        int cl = __shfl(my.x, (QOFF) + 2 * J), ch = __shfl(my.x, (QOFF) + 2 * J + 1); \
        int vl = __shfl(my.y, (QOFF) + 2 * J), vh = __shfl(my.y, (QOFF) + 2 * J + 1); \
        c##J = hl ? ch : cl;                                                    \
        v##J = __int_as_float(hl ? vh : vl);                                    \
    }

__global__ void k_spmm2(const unsigned* __restrict__ XWU, const int* __restrict__ row_ptr,
                        const int2* __restrict__ ecv, unsigned* __restrict__ PQh) {
    int gid = blockIdx.x * 256 + threadIdx.x;
    int wave = gid >> 6, lane = gid & 63;
    if (wave >= T_ * N_) return;
    int t = wave / N_;
    int r = wave - t * N_;
    int s = row_ptr[(size_t)t * (N_ + 1) + r];
    int len = row_ptr[(size_t)t * (N_ + 1) + r + 1] - s;
    int hl = lane >> 5;
    const uint2* Xt2 = (const uint2*)(XWU + (size_t)t * N_ * 64) + (lane & 31);
    const int2* ev = ecv + (size_t)t * NNZ_;
    float4 acc = {0.f, 0.f, 0.f, 0.f};
    for (int base = 0; base < len; base += 64) {
        int nn = min(64, len - base);
        int2 my = {0, 0};
        if (base + lane < len) my = ev[s + base + lane];
        int q = 0;
        for (; q + 16 <= nn; q += 16) {  // 8 pairs, 8 loads in flight
            int c0, c1, c2, c3, c4, c5, c6, c7;
            float v0, v1, v2, v3, v4, v5, v6, v7;
            PAIRSEL(0, q) PAIRSEL(1, q) PAIRSEL(2, q) PAIRSEL(3, q)
            PAIRSEL(4, q) PAIRSEL(5, q) PAIRSEL(6, q) PAIRSEL(7, q)
            uint2 x0 = Xt2[(size_t)c0 * 32];
            uint2 x1 = Xt2[(size_t)c1 * 32];
            uint2 x2 = Xt2[(size_t)c2 * 32];
            uint2 x3 = Xt2[(size_t)c3 * 32];
            uint2 x4 = Xt2[(size_t)c4 * 32];
            uint2 x5 = Xt2[(size_t)c5 * 32];
            uint2 x6 = Xt2[(size_t)c6 * 32];
            uint2 x7 = Xt2[(size_t)c7 * 32];
            acc.x += v0 * bflo(x0.x); acc.y += v0 * bfhi(x0.x); acc.z += v0 * bflo(x0.y); acc.w += v0 * bfhi(x0.y);
            acc.x += v1 * bflo(x1.x); acc.y += v1 * bfhi(x1.x); acc.z += v1 * bflo(x1.y); acc.w += v1 * bfhi(x1.y);
            acc.x += v2 * bflo(x2.x); acc.y += v2 * bfhi(x2.x); acc.z += v2 * bflo(x2.y); acc.w += v2 * bfhi(x2.y);
            acc.x += v3 * bflo(x3.x); acc.y += v3 * bfhi(x3.x); acc.z += v3 * bflo(x3.y); acc.w += v3 * bfhi(x3.y);
            acc.x += v4 * bflo(x4.x); acc.y += v4 * bfhi(x4.x); acc.z += v4 * bflo(x4.y); acc.w += v4 * bfhi(x4.y);
            acc.x += v5 * bflo(x5.x); acc.y += v5 * bfhi(x5.x); acc.z += v5 * bflo(x5.y); acc.w += v5 * bfhi(x5.y);
            acc.x += v6 * bflo(x6.x); acc.y += v6 * bfhi(x6.x); acc.z += v6 * bflo(x6.y); acc.w += v6 * bfhi(x6.y);
            acc.x += v7 * bflo(x7.x); acc.y += v7 * bfhi(x7.x); acc.z += v7 * bflo(x7.y); acc.w += v7 * bfhi(x7.y);
        }
        for (; q + 2 <= nn; q += 2) {
            int c0;
            float v0;
            PAIRSEL(0, q)
            uint2 x0 = Xt2[(size_t)c0 * 32];
            acc.x += v0 * bflo(x0.x); acc.y += v0 * bfhi(x0.x); acc.z += v0 * bflo(x0.y); acc.w += v0 * bfhi(x0.y);
        }
        if (q < nn) {  // odd trailing edge: high half contributes zero
            int c = __shfl(my.x, q);
            float v = __int_as_float(__shfl(my.y, q));
            if (hl) v = 0.f;
            uint2 x = Xt2[(size_t)c * 32];
            acc.x += v * bflo(x.x); acc.y += v * bfhi(x.x); acc.z += v * bflo(x.y); acc.w += v * bfhi(x.y);
        }
    }
    acc.x += __shfl_down(acc.x, 32);
    acc.y += __shfl_down(acc.y, 32);
    acc.z += __shfl_down(acc.z, 32);
    acc.w += __shfl_down(acc.w, 32);
    if (lane < 32) {
        uint2 o = {bfpack(acc.x, acc.y), bfpack(acc.z, acc.w)};
        *((uint2*)(PQh + (size_t)wave * 64) + lane) = o;
    }
}

// fallback (fp32 gather) if workspace can't hold Xh
__global__ void k_spmm_f32(const float* __restrict__ X, const int* __restrict__ row_ptr,
                           const int2* __restrict__ ecv, float* __restrict__ AH) {
    int gid = blockIdx.x * 256 + threadIdx.x;
    int wave = gid >> 6, lane = gid & 63;
    if (wave >= T_ * N_) return;
    int t = wave / N_;
    int r = wave - t * N_;
    int s = row_ptr[(size_t)t * (N_ + 1) + r];
    int len = row_ptr[(size_t)t * (N_ + 1) + r + 1] - s;
    const float2* Xt = (const float2*)(X + (size_t)t * N_ * F0_);
    const int2* ev = ecv + (size_t)t * NNZ_;
    float2 acc = {0.f, 0.f};
    for (int base = 0; base < len; base += 64) {
        int nn = min(64, len - base);
        int2 my = {0, 0};
        if (base + lane < len) my = ev[s + base + lane];
        for (int q = 0; q < nn; q++) {
            int c = __shfl(my.x, q);
            float v = __int_as_float(__shfl(my.y, q));
            float2 x = Xt[(size_t)c * 64 + lane];
            acc.x += v * x.x;
            acc.y += v * x.y;
        }
    }
    ((float2*)AH)[(size_t)wave * 64 + lane] = acc;
}

// fp32 in-place fallback GEMM (AH -> PQ in place)
__global__ __launch_bounds__(256) void k_pq_f32(float* __restrict__ AH,
                                                const float* __restrict__ WU) {
    __shared__ float AT[32][36];
    __shared__ float WUc[32][128];
    int t = blockIdx.y;
    int rbase = blockIdx.x * 32;
    int tid = threadIdx.x;
    const float* wu = WU + (size_t)t * 16384;
    float* AHt = AH + (size_t)t * N_ * F0_;
    int cg = tid & 31;
    int rg = tid >> 5;
    float4 acc0 = {0.f, 0.f, 0.f, 0.f};
    float4 acc1 = {0.f, 0.f, 0.f, 0.f};
    float4 acc2 = {0.f, 0.f, 0.f, 0.f};
    float4 acc3 = {0.f, 0.f, 0.f, 0.f};
    int srow = tid >> 3;
    int sk4 = (tid & 7) * 4;
    for (int kc = 0; kc < 128; kc += 32) {
        {
            float4 v = {0.f, 0.f, 0.f, 0.f};
            int r = rbase + srow;
            if (r < N_) v = *(const float4*)(AHt + (size_t)r * F0_ + kc + sk4);
            AT[sk4 + 0][srow] = v.x;
            AT[sk4 + 1][srow] = v.y;
            AT[sk4 + 2][srow] = v.z;
            AT[sk4 + 3][srow] = v.w;
        }
        {
            const float4* src = (const float4*)(wu + (size_t)kc * 128);
            float4* dst = (float4*)&WUc[0][0];
            dst[tid] = src[tid];
            dst[tid + 256] = src[tid + 256];
            dst[tid + 512] = src[tid + 512];
            dst[tid + 768] = src[tid + 768];
        }
        __syncthreads();
#pragma unroll 4
        for (int kk = 0; kk < 32; kk++) {
            float4 a = *(const float4*)&AT[kk][rg * 4];
            float4 w = *(const float4*)&WUc[kk][cg * 4];
            acc0.x += a.x * w.x; acc0.y += a.x * w.y; acc0.z += a.x * w.z; acc0.w += a.x * w.w;
            acc1.x += a.y * w.x; acc1.y += a.y * w.y; acc1.z += a.y * w.z; acc1.w += a.y * w.w;
            acc2.x += a.z * w.x; acc2.y += a.z * w.y; acc2.z += a.z * w.z; acc2.w += a.z * w.w;
            acc3.x += a.w * w.x; acc3.y += a.w * w.y; acc3.z += a.w * w.z; acc3.w += a.w * w.w;
        }
        __syncthreads();
    }
    int r0 = rbase + rg * 4;
    if (r0 + 0 < N_) *(float4*)(AHt + (size_t)(r0 + 0) * F0_ + cg * 4) = acc0;
    if (r0 + 1 < N_) *(float4*)(AHt + (size_t)(r0 + 1) * F0_ + cg * 4) = acc1;
    if (r0 + 2 < N_) *(float4*)(AHt + (size_t)(r0 + 2) * F0_ + cg * 4) = acc2;
    if (r0 + 3 < N_) *(float4*)(AHt + (size_t)(r0 + 3) * F0_ + cg * 4) = acc3;
}

// ---------- out[e] = P[flat_src] + Q[flat_trg]  (bf16 PQh) ----------
__global__ void k_final(const unsigned* __restrict__ PQh, const int* __restrict__ et,
                        const int* __restrict__ es, const int* __restrict__ eg,
                        float* __restrict__ out) {
    int gid = blockIdx.x * 256 + threadIdx.x;  // e*16 + q
    if (gid >= E_ * 16) return;
    int e = gid >> 4, q = gid & 15;
    int t = et[e];
    const uint2 a = *(const uint2*)(PQh + ((size_t)(t * N_ + es[e])) * 64 + q * 2);
    const uint2 b = *(const uint2*)(PQh + ((size_t)(t * N_ + eg[e])) * 64 + 32 + q * 2);
    float4 o;
    o.x = bflo(a.x) + bflo(b.x);
    o.y = bfhi(a.x) + bfhi(b.x);
    o.z = bflo(a.y) + bflo(b.y);
    o.w = bfhi(a.y) + bfhi(b.y);
    *(float4*)(out + (size_t)e * 64 + q * 4) = o;
}

__global__ void k_final_f32(const float* __restrict__ PQ, const int* __restrict__ et,
                            const int* __restrict__ es, const int* __restrict__ eg,
                            float* __restrict__ out) {
    int gid = blockIdx.x * 256 + threadIdx.x;  // e*16 + q
    if (gid >= E_ * 16) return;
    int e = gid >> 4, q = gid & 15;
    int t = et[e];
    const float4 a = *(const float4*)(PQ + ((size_t)(t * N_ + es[e])) * 128 + q * 4);
    const float4 b = *(const float4*)(PQ + ((size_t)(t * N_ + eg[e])) * 128 + 64 + q * 4);
    float4 o = {a.x + b.x, a.y + b.y, a.z + b.z, a.w + b.w};
    *(float4*)(out + (size_t)e * 64 + q * 4) = o;
}

// W_fin[k][m] = WT[7][m][k]
__global__ void k_wfin(const float* __restrict__ WT, float* __restrict__ out) {
    int gid = blockIdx.x * 256 + threadIdx.x;  // k*128 + m
    int k = gid >> 7, m = gid & 127;
    out[(size_t)E_ * 64 + gid] = WT[(size_t)7 * 16384 + m * 128 + k];
}

// ---------- launch ----------
extern "C" void kernel_launch(void* const* d_in, const int* in_sizes, int n_in,
                              void* d_out, int out_size, void* d_ws, size_t ws_size,
                              hipStream_t stream) {
    const float* X = (const float*)d_in[0];
    const int* A_rows = (const int*)d_in[1];
    const int* A_cols = (const int*)d_in[2];
    const float* A_val = (const float*)d_in[3];
    const int* edge_time = (const int*)d_in[4];
    const int* edge_src = (const int*)d_in[5];
    const int* edge_trg = (const int*)d_in[6];
    const float* p = (const float*)d_in[7];
    const float* W_Z = (const float*)d_in[8];
    const float* U_Z = (const float*)d_in[9];
    const float* B_Z = (const float*)d_in[10];
    const float* W_R = (const float*)d_in[11];
    const float* U_R = (const float*)d_in[12];
    const float* B_R = (const float*)d_in[13];
    const float* W_H = (const float*)d_in[14];
    const float* U_H = (const float*)d_in[15];
    const float* B_H = (const float*)d_in[16];
    const float* W_init = (const float*)d_in[17];
    const float* U = (const float*)d_in[18];
    float* out = (float*)d_out;

    char* ws = (char*)d_ws;
    size_t off = 0;
    auto take = [&](size_t bytes) {
        char* ptr = ws + off;
        off = (off + bytes + 255) & ~(size_t)255;
        return (void*)ptr;
    };
    float* AHreg = (float*)take((size_t)T_ * N_ * F0_ * 4);  // 204.8 MB: ebuck / XWU+PQh / AH(fallback)
    int2* ecv = (int2*)take((size_t)T_ * NNZ_ * 8);          // 51.2 MB final CSR
    float* yv = (float*)take((size_t)T_ * N_ * 4);
    int* row_ptr = (int*)take((size_t)T_ * (N_ + 1) * 4);
    int* bcnt = (int*)take((size_t)T_ * NB * 4);
    int* bbase = (int*)take((size_t)T_ * NB * 4);
    int* bfill = (int*)take((size_t)T_ * NB * 4);
    float* p_hat = (float*)take(512);
    float* topv = (float*)take((size_t)T_ * K_ * 4);
    int* topidx = (int*)take((size_t)T_ * K_ * 4);
    float* Z = (float*)take((size_t)T_ * F0_ * K_ * 4);
    float* AZb = (float*)take((size_t)T_ * 16384 * 4);
    float* ARb = (float*)take((size_t)T_ * 16384 * 4);
    float* AHb = (float*)take((size_t)T_ * 16384 * 4);
    float* WT = (float*)take((size_t)T_ * 16384 * 4);  // W_seq transposed [t][j][k]
    float* WU = (float*)take((size_t)T_ * 16384 * 4);
    unsigned* Xh = (unsigned*)take((size_t)T_ * N_ * 64 * 4);  // 102.4 MB bf16 X
    bool use_bf16 = (off <= ws_size);
    int2* ebuck = (int2*)AHreg;                 // dead after k_bsort
    unsigned* XWU = (unsigned*)AHreg;           // first 102.4 MB
    unsigned* PQh = XWU + (size_t)T_ * N_ * 64; // second 102.4 MB

    hipMemsetAsync(bcnt, 0, (size_t)T_ * NB * 4, stream);
    hipMemsetAsync(bfill, 0, (size_t)T_ * NB * 4, stream);

    k_phat<<<1, 128, 0, stream>>>(p, p_hat);
    k_y<<<(T_ * N_ * 64) / 256, 256, 0, stream>>>(X, p_hat, yv, use_bf16 ? Xh : nullptr);
    k_topk<<<T_, 1024, 0, stream>>>(yv, topv, topidx);
    k_z<<<(T_ * F0_ * K_) / 256, 256, 0, stream>>>(X, topv, topidx, Z);
    k_az<<<(3 * T_ * 16384) / 256, 256, 0, stream>>>(W_Z, W_R, W_H, B_Z, B_R, B_H, Z,
                                                     AZb, ARb, AHb);
    {
        dim3 gA((NNZ_ + BCH - 1) / BCH, T_);  // 98 x 8
        k_cnt<<<gA, 512, 0, stream>>>(A_rows, bcnt);
        k_bscan<<<T_, 512, 0, stream>>>(bcnt, bbase);
        k_binA<<<gA, 512, 0, stream>>>(A_rows, A_cols, A_val, bbase, bfill, ebuck);
        dim3 gB(NB, T_);                      // 391 x 8
        k_bsort<<<gB, 256, 0, stream>>>(bbase, bcnt, ebuck, ecv, row_ptr);
    }
    k_gru8<<<64, 256, 0, stream>>>(AZb, ARb, AHb, U_Z, U_R, U_H, W_init, WT);
    k_wu<<<T_ * 128, 128, 0, stream>>>(WT, U, WU);
    if (use_bf16) {
        dim3 g((N_ + 31) / 32, T_);
        k_xwu<<<g, 256, 0, stream>>>(Xh, WU, XWU);
        k_spmm2<<<(T_ * N_ * 64) / 256, 256, 0, stream>>>(XWU, row_ptr, ecv, PQh);
        k_final<<<(E_ * 16) / 256, 256, 0, stream>>>(PQh, edge_time, edge_src,
                                                     edge_trg, out);
    } else {
        float* AH = AHreg;
        k_spmm_f32<<<(T_ * N_ * 64) / 256, 256, 0, stream>>>(X, row_ptr, ecv, AH);
        dim3 g((N_ + 31) / 32, T_);
        k_pq_f32<<<g, 256, 0, stream>>>(AH, WU);
        k_final_f32<<<(E_ * 16) / 256, 256, 0, stream>>>(AH, edge_time, edge_src,
                                                         edge_trg, out);
    }
    k_wfin<<<(F0_ * H0_) / 256, 256, 0, stream>>>(WT, out);
}

// Round 11
// 910.761 us; speedup vs baseline: 11.6862x; 1.0291x over previous
//
#include <hip/hip_runtime.h>
#include <math.h>

#define T_ 8
#define N_ 50000
#define F0_ 128
#define H0_ 128
#define H1_ 64
#define NNZ_ 800000
#define E_ 1000000
#define K_ 128
#define CAP_ 3072
#define NB 391   // ceil(N_/128) buckets of 128 rows
#define BCH 8192 // edges per chunk block

typedef float nf4 __attribute__((ext_vector_type(4)));

// ---------- helpers ----------
__device__ inline unsigned ford(float f) {
    unsigned b = __float_as_uint(f);
    return (b & 0x80000000u) ? ~b : (b | 0x80000000u);
}
__device__ inline float funord(unsigned u) {
    unsigned b = (u & 0x80000000u) ? (u & 0x7fffffffu) : ~u;
    return __uint_as_float(b);
}
__device__ inline unsigned bfr(float f) {  // fp32 -> bf16 bits (RNE)
    unsigned u = __float_as_uint(f);
    return (u + 0x7fffu + ((u >> 16) & 1u)) >> 16;
}
__device__ inline unsigned bfpack(float lo, float hi) { return bfr(lo) | (bfr(hi) << 16); }
__device__ inline float bflo(unsigned u) { return __uint_as_float(u << 16); }
__device__ inline float bfhi(unsigned u) { return __uint_as_float(u & 0xffff0000u); }

// ---------- p_hat = p / ||p|| ----------
__global__ void k_phat(const float* p, float* p_hat) {
    __shared__ float s[128];
    int i = threadIdx.x;
    float v = p[i];
    s[i] = v * v;
    __syncthreads();
    for (int off = 64; off > 0; off >>= 1) {
        if (i < off) s[i] += s[i + off];
        __syncthreads();
    }
    p_hat[i] = v / sqrtf(s[0]);
}

// ---------- y = X @ p_hat (wave/row) + bf16 copy of X ----------
__global__ void k_y(const float* __restrict__ X, const float* __restrict__ p_hat,
                    float* __restrict__ y, unsigned* __restrict__ Xh) {
    int gid = blockIdx.x * 256 + threadIdx.x;
    int wave = gid >> 6, lane = gid & 63;
    if (wave >= T_ * N_) return;
    const float2* xr = (const float2*)(X + (size_t)wave * F0_);
    float2 a = xr[lane];
    if (Xh) Xh[(size_t)wave * 64 + lane] = bfpack(a.x, a.y);
    float2 ph = ((const float2*)p_hat)[lane];
    float acc = a.x * ph.x + a.y * ph.y;
#pragma unroll
    for (int off = 32; off > 0; off >>= 1) acc += __shfl_down(acc, off);
    if (lane == 0) y[wave] = acc;
}

// ---------- exact top-128 per t: 2-level radix select + exact rank ----------
__global__ __launch_bounds__(1024) void k_topk(const float* __restrict__ y,
                                               float* __restrict__ topv,
                                               int* __restrict__ topidx) {
    int t = blockIdx.x;
    const float* yt = y + (size_t)t * N_;
    __shared__ int hist[256];
    __shared__ int sb1, sAbove, sP, scand;
    __shared__ unsigned cu[CAP_];
    __shared__ int cidx[CAP_];
    int tid = threadIdx.x;

    if (tid < 256) hist[tid] = 0;
    __syncthreads();
    for (int i = tid; i < N_; i += 1024) {
        unsigned u = ford(yt[i]);
        atomicAdd(&hist[u >> 24], 1);
    }
    __syncthreads();
    if (tid == 0) {
        int acc = 0, b = 255;
        for (; b >= 0; b--) { acc += hist[b]; if (acc >= K_) break; }
        sb1 = b;
        sAbove = acc - hist[b];
    }
    __syncthreads();
    int b1 = sb1;
    if (tid < 256) hist[tid] = 0;
    __syncthreads();
    for (int i = tid; i < N_; i += 1024) {
        unsigned u = ford(yt[i]);
        if ((int)(u >> 24) == b1) atomicAdd(&hist[(u >> 16) & 255], 1);
    }
    __syncthreads();
    if (tid == 0) {
        int acc = sAbove, b = 255;
        for (; b >= 0; b--) { acc += hist[b]; if (acc >= K_) break; }
        sP = (b1 << 8) | b;
        scand = 0;
    }
    __syncthreads();
    unsigned P = (unsigned)sP;
    for (int i = tid; i < N_; i += 1024) {
        unsigned u = ford(yt[i]);
        if ((u >> 16) >= P) {
            int pos = atomicAdd(&scand, 1);
            if (pos < CAP_) { cu[pos] = u; cidx[pos] = i; }
        }
    }
    __syncthreads();
    int C = min(scand, CAP_);
    for (int c = tid; c < C; c += 1024) {
        unsigned uc = cu[c];
        int ic = cidx[c];
        int rank = 0;
        for (int o = 0; o < C; o++) {
            unsigned uo = cu[o];
            rank += (uo > uc) || (uo == uc && cidx[o] < ic);
        }
        if (rank < K_) {
            topv[t * K_ + rank] = funord(uc);
            topidx[t * K_ + rank] = ic;
        }
    }
}

// ---------- Z[t][f][j] = X[t][idx[j]][f] * topv[j] ----------
__global__ void k_z(const float* __restrict__ X, const float* __restrict__ topv,
                    const int* __restrict__ topidx, float* __restrict__ Z) {
    int gid = blockIdx.x * 256 + threadIdx.x;  // t*16384 + f*128 + j
    if (gid >= T_ * F0_ * K_) return;
    int j = gid & 127;
    int f = (gid >> 7) & 127;
    int t = gid >> 14;
    int idx = topidx[t * K_ + j];
    float v = topv[t * K_ + j];
    Z[gid] = X[((size_t)(t * N_ + idx)) * F0_ + f] * v;
}

// ---------- A_g[t] = W_g @ Z_t + B_g  (g in {Z,R,H}, all t parallel) ----------
__global__ void k_az(const float* __restrict__ WZ, const float* __restrict__ WR,
                     const float* __restrict__ WH, const float* __restrict__ BZ,
                     const float* __restrict__ BR, const float* __restrict__ BH,
                     const float* __restrict__ Z, float* __restrict__ AZ,
                     float* __restrict__ AR, float* __restrict__ AHo) {
    int gid = blockIdx.x * 256 + threadIdx.x;  // g*131072 + t*16384 + i*128 + j
    int j = gid & 127;
    int i = (gid >> 7) & 127;
    int t = (gid >> 14) & 7;
    int g = gid >> 17;
    const float* W = (g == 0) ? WZ : (g == 1) ? WR : WH;
    const float* B = (g == 0) ? BZ : (g == 1) ? BR : BH;
    float* Ao = (g == 0) ? AZ : (g == 1) ? AR : AHo;
    const float* Zt = Z + (size_t)t * 16384;
    float acc = B[i * 128 + j];
    for (int k = 0; k < 128; k++) acc += W[i * 128 + k] * Zt[k * 128 + j];
    Ao[(size_t)(t * 128 + i) * 128 + j] = acc;
}

// ---------- CSR build pass 0: bucket counts via LDS histogram ----------
__global__ __launch_bounds__(512) void k_cnt(const int* __restrict__ A_rows,
                                             int* __restrict__ bcnt) {
    __shared__ int cnt[NB];
    int t = blockIdx.y, ci = blockIdx.x;
    int tid = threadIdx.x;
    for (int i = tid; i < NB; i += 512) cnt[i] = 0;
    __syncthreads();
    int e0 = ci * BCH;
#pragma unroll
    for (int k = 0; k < 16; k++) {
        int idx = e0 + tid + k * 512;
        if (idx < NNZ_) atomicAdd(&cnt[A_rows[(size_t)t * NNZ_ + idx] >> 7], 1);
    }
    __syncthreads();
    for (int b = tid; b < NB; b += 512)
        if (cnt[b]) atomicAdd(&bcnt[t * NB + b], cnt[b]);
}

// ---------- bucket scan: bbase[t][b] = excl prefix of bcnt[t][*] ----------
__global__ __launch_bounds__(512) void k_bscan(const int* __restrict__ bcnt,
                                               int* __restrict__ bbase) {
    int t = blockIdx.x;
    int tid = threadIdx.x;
    __shared__ int buf[512];
    int v = (tid < NB) ? bcnt[t * NB + tid] : 0;
    buf[tid] = v;
    __syncthreads();
    for (int off = 1; off < 512; off <<= 1) {
        int x = (tid >= off) ? buf[tid - off] : 0;
        __syncthreads();
        buf[tid] += x;
        __syncthreads();
    }
    if (tid < NB) bbase[t * NB + tid] = buf[tid] - v;
}

// ---------- Pass A: bin edges into 128-row buckets, group-contiguous writes ----------
// meta = col(16b) | rlo(7b)<<16 | b(9b)<<23 ; sentinel 0xFFFFFFFF (b=511 impossible)
__global__ __launch_bounds__(512) void k_binA(const int* __restrict__ A_rows,
                                              const int* __restrict__ A_cols,
                                              const float* __restrict__ A_val,
                                              const int* __restrict__ bbase,
                                              int* __restrict__ bfill,
                                              int2* __restrict__ ebuck) {
    __shared__ int cnt[NB];
    __shared__ int gbase[NB];
    __shared__ int rbase[NB];
    int t = blockIdx.y, ci = blockIdx.x;
    int tid = threadIdx.x;
    for (int i = tid; i < NB; i += 512) cnt[i] = 0;
    __syncthreads();
    unsigned meta[16];
    float val[16];
    int lrank[16];
    int e0 = ci * BCH;
#pragma unroll
    for (int k = 0; k < 16; k++) {
        int idx = e0 + tid + k * 512;
        meta[k] = 0xFFFFFFFFu;
        val[k] = 0.f;
        lrank[k] = 0;
        if (idx < NNZ_) {
            int r = A_rows[(size_t)t * NNZ_ + idx];
            int c = A_cols[(size_t)t * NNZ_ + idx];
            val[k] = A_val[(size_t)t * NNZ_ + idx];
            int b = r >> 7, rlo = r & 127;
            meta[k] = (unsigned)c | ((unsigned)rlo << 16) | ((unsigned)b << 23);
            lrank[k] = atomicAdd(&cnt[b], 1);
        }
    }
    __syncthreads();
    for (int b = tid; b < NB; b += 512) {
        int n = cnt[b];
        gbase[b] = n ? atomicAdd(&bfill[t * NB + b], n) : 0;
        rbase[b] = bbase[t * NB + b];
    }
    __syncthreads();
#pragma unroll
    for (int k = 0; k < 16; k++) {
        if (meta[k] != 0xFFFFFFFFu) {
            int b = meta[k] >> 23;
            ebuck[(size_t)t * NNZ_ + rbase[b] + gbase[b] + lrank[k]] =
                make_int2((int)meta[k], __float_as_int(val[k]));
        }
    }
}

// ---------- Pass B: per-bucket row count + scan -> row_ptr; sort edges into CSR ----------
__global__ __launch_bounds__(256) void k_bsort(const int* __restrict__ bbase,
                                               const int* __restrict__ bcnt,
                                               const int2* __restrict__ ebuck,
                                               int2* __restrict__ ecv,
                                               int* __restrict__ row_ptr) {
    __shared__ int rcnt[128];
    __shared__ int rex[128];
    __shared__ int rfill[128];
    __shared__ int sbuf[128];
    int t = blockIdx.y, b = blockIdx.x;
    int tid = threadIdx.x;
    int r0 = b << 7;
    int nrows = min(128, N_ - r0);
    int base = bbase[t * NB + b];
    int n = bcnt[t * NB + b];
    if (tid < 128) {
        rcnt[tid] = 0;
        rfill[tid] = 0;
    }
    __syncthreads();
    const int2* src = ebuck + (size_t)t * NNZ_ + base;
    int2* dst = ecv + (size_t)t * NNZ_ + base;
    for (int i = tid; i < n; i += 256) atomicAdd(&rcnt[(src[i].x >> 16) & 127], 1);
    __syncthreads();
    // exclusive scan of rcnt (128 wide)
    if (tid < 128) sbuf[tid] = rcnt[tid];
    __syncthreads();
    for (int off = 1; off < 128; off <<= 1) {
        int x = (tid >= off && tid < 128) ? sbuf[tid - off] : 0;
        __syncthreads();
        if (tid < 128) sbuf[tid] += x;
        __syncthreads();
    }
    if (tid < 128) rex[tid] = sbuf[tid] - rcnt[tid];
    if (tid < nrows) row_ptr[(size_t)t * (N_ + 1) + r0 + tid] = base + sbuf[tid] - rcnt[tid];
    if (b == 0 && tid == 0) row_ptr[(size_t)t * (N_ + 1) + N_] = NNZ_;
    __syncthreads();
    for (int i = tid; i < n; i += 256) {
        int2 e = src[i];
        int rlo = (e.x >> 16) & 127;
        int col = e.x & 0xFFFF;
        int pos = rex[rlo] + atomicAdd(&rfill[rlo], 1);
        dst[pos] = make_int2(col, e.y);
    }
}

// ---------- fused 8-step GRU, column-separable: block owns 2 columns across all t ----------
// WT layout: [t][col j][row k]  (transposed vs reference W[k][j])
__global__ __launch_bounds__(256) void k_gru8(const float* __restrict__ AZb,
                                              const float* __restrict__ ARb,
                                              const float* __restrict__ AHb,
                                              const float* __restrict__ UZ,
                                              const float* __restrict__ UR,
                                              const float* __restrict__ UH,
                                              const float* __restrict__ W_init,
                                              float* __restrict__ WT) {
    __shared__ float Wc[128][2];
    __shared__ float RWs[128][2];
    int jl = threadIdx.x >> 7;  // 0..1
    int i = threadIdx.x & 127;
    int j = blockIdx.x * 2 + jl;
    Wc[i][jl] = W_init[i * 128 + j];
    __syncthreads();
    for (int t = 0; t < T_; t++) {
        const float* AZt = AZb + (size_t)t * 16384;
        const float* ARt = ARb + (size_t)t * 16384;
        const float* AHt = AHb + (size_t)t * 16384;
        float az = AZt[i * 128 + j], ar = ARt[i * 128 + j];
        for (int k = 0; k < 128; k++) {
            float w = Wc[k][jl];  // LDS broadcast
            az += UZ[i * 128 + k] * w;
            ar += UR[i * 128 + k] * w;
        }
        float zg = 1.f / (1.f + expf(-az));
        float rg = 1.f / (1.f + expf(-ar));
        float wself = Wc[i][jl];
        RWs[i][jl] = rg * wself;
        __syncthreads();
        float acc = AHt[i * 128 + j];
        for (int k = 0; k < 128; k++) acc += UH[i * 128 + k] * RWs[k][jl];
        float ht = tanhf(acc);
        float nw = (1.f - zg) * wself + zg * ht;
        __syncthreads();
        Wc[i][jl] = nw;
        WT[((size_t)t * 128 + j) * 128 + i] = nw;  // coalesced in i
        __syncthreads();
    }
}

// ---------- WU[t][k][h2] = sum_m W_t[k][m] * U[(h2<64? m : 128+m)][h2&63] ----------
// W_t[k][m] = WT[t][m][k]
__global__ void k_wu(const float* __restrict__ WT, const float* __restrict__ U,
                     float* __restrict__ WU) {
    int blk = blockIdx.x;  // t*128 + k
    int t = blk >> 7, k = blk & 127;
    int h2 = threadIdx.x;
    int h = h2 & 63;
    const float* Ub = U + (h2 < 64 ? 0 : 128 * 64);
    float acc = 0.f;
    for (int m = 0; m < 128; m++)
        acc += WT[((size_t)t * 128 + m) * 128 + k] * Ub[m * 64 + h];
    WU[((size_t)t * 128 + k) * 128 + h2] = acc;
}

// ---------- XWU[t] = Xh[t] @ WU[t]  (bf16 in, bf16 out) ----------
__global__ __launch_bounds__(256) void k_xwu(const unsigned* __restrict__ Xh,
                                             const float* __restrict__ WU,
                                             unsigned* __restrict__ XWU) {
    __shared__ float AT[32][36];
    __shared__ float WUc[32][128];
    int t = blockIdx.y;
    int rbase = blockIdx.x * 32;
    int tid = threadIdx.x;
    const float* wu = WU + (size_t)t * 16384;
    const unsigned* Xt = Xh + (size_t)t * N_ * 64;
    unsigned* XWUt = XWU + (size_t)t * N_ * 64;
    int cg = tid & 31;
    int rg = tid >> 5;
    float4 acc0 = {0.f, 0.f, 0.f, 0.f};
    float4 acc1 = {0.f, 0.f, 0.f, 0.f};
    float4 acc2 = {0.f, 0.f, 0.f, 0.f};
    float4 acc3 = {0.f, 0.f, 0.f, 0.f};
    int srow = tid >> 3;
    int sk4 = (tid & 7) * 4;
    for (int kc = 0; kc < 128; kc += 32) {
        {
            uint2 u = {0u, 0u};
            int r = rbase + srow;
            if (r < N_) u = *(const uint2*)(Xt + (size_t)r * 64 + (kc >> 1) + (sk4 >> 1));
            AT[sk4 + 0][srow] = bflo(u.x);
            AT[sk4 + 1][srow] = bfhi(u.x);
            AT[sk4 + 2][srow] = bflo(u.y);
            AT[sk4 + 3][srow] = bfhi(u.y);
        }
        {
            const float4* src = (const float4*)(wu + (size_t)kc * 128);
            float4* dst = (float4*)&WUc[0][0];
            dst[tid] = src[tid];
            dst[tid + 256] = src[tid + 256];
            dst[tid + 512] = src[tid + 512];
            dst[tid + 768] = src[tid + 768];
        }
        __syncthreads();
#pragma unroll 4
        for (int kk = 0; kk < 32; kk++) {
            float4 a = *(const float4*)&AT[kk][rg * 4];
            float4 w = *(const float4*)&WUc[kk][cg * 4];
            acc0.x += a.x * w.x; acc0.y += a.x * w.y; acc0.z += a.x * w.z; acc0.w += a.x * w.w;
            acc1.x += a.y * w.x; acc1.y += a.y * w.y; acc1.z += a.y * w.z; acc1.w += a.y * w.w;
            acc2.x += a.z * w.x; acc2.y += a.z * w.y; acc2.z += a.z * w.z; acc2.w += a.z * w.w;
            acc3.x += a.w * w.x; acc3.y += a.w * w.y; acc3.z += a.w * w.z; acc3.w += a.w * w.w;
        }
        __syncthreads();
    }
    int r0 = rbase + rg * 4;
    if (r0 + 0 < N_) {
        uint2 o = {bfpack(acc0.x, acc0.y), bfpack(acc0.z, acc0.w)};
        *(uint2*)(XWUt + (size_t)(r0 + 0) * 64 + cg * 2) = o;
    }
    if (r0 + 1 < N_) {
        uint2 o = {bfpack(acc1.x, acc1.y), bfpack(acc1.z, acc1.w)};
        *(uint2*)(XWUt + (size_t)(r0 + 1) * 64 + cg * 2) = o;
    }
    if (r0 + 2 < N_) {
        uint2 o = {bfpack(acc2.x, acc2.y), bfpack(acc2.z, acc2.w)};
        *(uint2*)(XWUt + (size_t)(r0 + 2) * 64 + cg * 2) = o;
    }
    if (r0 + 3 < N_) {
        uint2 o = {bfpack(acc3.x, acc3.y), bfpack(acc3.z, acc3.w)};
        *(uint2*)(XWUt + (size_t)(r0 + 3) * 64 + cg * 2) = o;
    }
}

// ---------- SpMM2 (R8 form): PQh[t][r] = sum val*XWU[t][col]; 16 loads in flight ----------
__global__ void k_spmm2(const unsigned* __restrict__ XWU, const int* __restrict__ row_ptr,
                        const int2* __restrict__ ecv, unsigned* __restrict__ PQh) {
    int gid = blockIdx.x * 256 + threadIdx.x;
    int wave = gid >> 6, lane = gid & 63;
    if (wave >= T_ * N_) return;
    int t = wave / N_;
    int r = wave - t * N_;
    int s = row_ptr[(size_t)t * (N_ + 1) + r];
    int len = row_ptr[(size_t)t * (N_ + 1) + r + 1] - s;
    const unsigned* Xt = XWU + (size_t)t * N_ * 64 + lane;
    const int2* ev = ecv + (size_t)t * NNZ_;
    float2 acc = {0.f, 0.f};
    for (int base = 0; base < len; base += 64) {
        int nn = min(64, len - base);
        int2 my = {0, 0};
        if (base + lane < len) my = ev[s + base + lane];
        int q = 0;
        for (; q + 16 <= nn; q += 16) {
            int c0 = __shfl(my.x, q + 0);  float v0 = __int_as_float(__shfl(my.y, q + 0));
            int c1 = __shfl(my.x, q + 1);  float v1 = __int_as_float(__shfl(my.y, q + 1));
            int c2 = __shfl(my.x, q + 2);  float v2 = __int_as_float(__shfl(my.y, q + 2));
            int c3 = __shfl(my.x, q + 3);  float v3 = __int_as_float(__shfl(my.y, q + 3));
            int c4 = __shfl(my.x, q + 4);  float v4 = __int_as_float(__shfl(my.y, q + 4));
            int c5 = __shfl(my.x, q + 5);  float v5 = __int_as_float(__shfl(my.y, q + 5));
            int c6 = __shfl(my.x, q + 6);  float v6 = __int_as_float(__shfl(my.y, q + 6));
            int c7 = __shfl(my.x, q + 7);  float v7 = __int_as_float(__shfl(my.y, q + 7));
            int c8 = __shfl(my.x, q + 8);  float v8 = __int_as_float(__shfl(my.y, q + 8));
            int c9 = __shfl(my.x, q + 9);  float v9 = __int_as_float(__shfl(my.y, q + 9));
            int cA = __shfl(my.x, q + 10); float vA = __int_as_float(__shfl(my.y, q + 10));
            int cB = __shfl(my.x, q + 11); float vB = __int_as_float(__shfl(my.y, q + 11));
            int cC = __shfl(my.x, q + 12); float vC = __int_as_float(__shfl(my.y, q + 12));
            int cD = __shfl(my.x, q + 13); float vD = __int_as_float(__shfl(my.y, q + 13));
            int cE = __shfl(my.x, q + 14); float vE = __int_as_float(__shfl(my.y, q + 14));
            int cF = __shfl(my.x, q + 15); float vF = __int_as_float(__shfl(my.y, q + 15));
            unsigned x0 = Xt[(size_t)c0 * 64];
            unsigned x1 = Xt[(size_t)c1 * 64];
            unsigned x2 = Xt[(size_t)c2 * 64];
            unsigned x3 = Xt[(size_t)c3 * 64];
            unsigned x4 = Xt[(size_t)c4 * 64];
            unsigned x5 = Xt[(size_t)c5 * 64];
            unsigned x6 = Xt[(size_t)c6 * 64];
            unsigned x7 = Xt[(size_t)c7 * 64];
            unsigned x8 = Xt[(size_t)c8 * 64];
            unsigned x9 = Xt[(size_t)c9 * 64];
            unsigned xA = Xt[(size_t)cA * 64];
            unsigned xB = Xt[(size_t)cB * 64];
            unsigned xC = Xt[(size_t)cC * 64];
            unsigned xD = Xt[(size_t)cD * 64];
            unsigned xE = Xt[(size_t)cE * 64];
            unsigned xF = Xt[(size_t)cF * 64];
            acc.x += v0 * bflo(x0); acc.y += v0 * bfhi(x0);
            acc.x += v1 * bflo(x1); acc.y += v1 * bfhi(x1);
            acc.x += v2 * bflo(x2); acc.y += v2 * bfhi(x2);
            acc.x += v3 * bflo(x3); acc.y += v3 * bfhi(x3);
            acc.x += v4 * bflo(x4); acc.y += v4 * bfhi(x4);
            acc.x += v5 * bflo(x5); acc.y += v5 * bfhi(x5);
            acc.x += v6 * bflo(x6); acc.y += v6 * bfhi(x6);
            acc.x += v7 * bflo(x7); acc.y += v7 * bfhi(x7);
            acc.x += v8 * bflo(x8); acc.y += v8 * bfhi(x8);
            acc.x += v9 * bflo(x9); acc.y += v9 * bfhi(x9);
            acc.x += vA * bflo(xA); acc.y += vA * bfhi(xA);
            acc.x += vB * bflo(xB); acc.y += vB * bfhi(xB);
            acc.x += vC * bflo(xC); acc.y += vC * bfhi(xC);
            acc.x += vD * bflo(xD); acc.y += vD * bfhi(xD);
            acc.x += vE * bflo(xE); acc.y += vE * bfhi(xE);
            acc.x += vF * bflo(xF); acc.y += vF * bfhi(xF);
        }
        for (; q + 8 <= nn; q += 8) {
            int c0 = __shfl(my.x, q + 0); float v0 = __int_as_float(__shfl(my.y, q + 0));
            int c1 = __shfl(my.x, q + 1); float v1 = __int_as_float(__shfl(my.y, q + 1));
            int c2 = __shfl(my.x, q + 2); float v2 = __int_as_float(__shfl(my.y, q + 2));
            int c3 = __shfl(my.x, q + 3); float v3 = __int_as_float(__shfl(my.y, q + 3));
            int c4 = __shfl(my.x, q + 4); float v4 = __int_as_float(__shfl(my.y, q + 4));
            int c5 = __shfl(my.x, q + 5); float v5 = __int_as_float(__shfl(my.y, q + 5));
            int c6 = __shfl(my.x, q + 6); float v6 = __int_as_float(__shfl(my.y, q + 6));
            int c7 = __shfl(my.x, q + 7); float v7 = __int_as_float(__shfl(my.y, q + 7));
            unsigned x0 = Xt[(size_t)c0 * 64];
            unsigned x1 = Xt[(size_t)c1 * 64];
            unsigned x2 = Xt[(size_t)c2 * 64];
            unsigned x3 = Xt[(size_t)c3 * 64];
            unsigned x4 = Xt[(size_t)c4 * 64];
            unsigned x5 = Xt[(size_t)c5 * 64];
            unsigned x6 = Xt[(size_t)c6 * 64];
            unsigned x7 = Xt[(size_t)c7 * 64];
            acc.x += v0 * bflo(x0); acc.y += v0 * bfhi(x0);
            acc.x += v1 * bflo(x1); acc.y += v1 * bfhi(x1);
            acc.x += v2 * bflo(x2); acc.y += v2 * bfhi(x2);
            acc.x += v3 * bflo(x3); acc.y += v3 * bfhi(x3);
            acc.x += v4 * bflo(x4); acc.y += v4 * bfhi(x4);
            acc.x += v5 * bflo(x5); acc.y += v5 * bfhi(x5);
            acc.x += v6 * bflo(x6); acc.y += v6 * bfhi(x6);
            acc.x += v7 * bflo(x7); acc.y += v7 * bfhi(x7);
        }
        for (; q < nn; q++) {
            int c = __shfl(my.x, q);
            float v = __int_as_float(__shfl(my.y, q));
            unsigned xp = Xt[(size_t)c * 64];
            acc.x += v * bflo(xp);
            acc.y += v * bfhi(xp);
        }
    }
    PQh[(size_t)wave * 64 + lane] = bfpack(acc.x, acc.y);
}

// fallback (fp32 gather) if workspace can't hold Xh
__global__ void k_spmm_f32(const float* __restrict__ X, const int* __restrict__ row_ptr,
                           const int2* __restrict__ ecv, float* __restrict__ AH) {
    int gid = blockIdx.x * 256 + threadIdx.x;
    int wave = gid >> 6, lane = gid & 63;
    if (wave >= T_ * N_) return;
    int t = wave / N_;
    int r = wave - t * N_;
    int s = row_ptr[(size_t)t * (N_ + 1) + r];
    int len = row_ptr[(size_t)t * (N_ + 1) + r + 1] - s;
    const float2* Xt = (const float2*)(X + (size_t)t * N_ * F0_);
    const int2* ev = ecv + (size_t)t * NNZ_;
    float2 acc = {0.f, 0.f};
    for (int base = 0; base < len; base += 64) {
        int nn = min(64, len - base);
        int2 my = {0, 0};
        if (base + lane < len) my = ev[s + base + lane];
        for (int q = 0; q < nn; q++) {
            int c = __shfl(my.x, q);
            float v = __int_as_float(__shfl(my.y, q));
            float2 x = Xt[(size_t)c * 64 + lane];
            acc.x += v * x.x;
            acc.y += v * x.y;
        }
    }
    ((float2*)AH)[(size_t)wave * 64 + lane] = acc;
}

// fp32 in-place fallback GEMM (AH -> PQ in place)
__global__ __launch_bounds__(256) void k_pq_f32(float* __restrict__ AH,
                                                const float* __restrict__ WU) {
    __shared__ float AT[32][36];
    __shared__ float WUc[32][128];
    int t = blockIdx.y;
    int rbase = blockIdx.x * 32;
    int tid = threadIdx.x;
    const float* wu = WU + (size_t)t * 16384;
    float* AHt = AH + (size_t)t * N_ * F0_;
    int cg = tid & 31;
    int rg = tid >> 5;
    float4 acc0 = {0.f, 0.f, 0.f, 0.f};
    float4 acc1 = {0.f, 0.f, 0.f, 0.f};
    float4 acc2 = {0.f, 0.f, 0.f, 0.f};
    float4 acc3 = {0.f, 0.f, 0.f, 0.f};
    int srow = tid >> 3;
    int sk4 = (tid & 7) * 4;
    for (int kc = 0; kc < 128; kc += 32) {
        {
            float4 v = {0.f, 0.f, 0.f, 0.f};
            int r = rbase + srow;
            if (r < N_) v = *(const float4*)(AHt + (size_t)r * F0_ + kc + sk4);
            AT[sk4 + 0][srow] = v.x;
            AT[sk4 + 1][srow] = v.y;
            AT[sk4 + 2][srow] = v.z;
            AT[sk4 + 3][srow] = v.w;
        }
        {
            const float4* src = (const float4*)(wu + (size_t)kc * 128);
            float4* dst = (float4*)&WUc[0][0];
            dst[tid] = src[tid];
            dst[tid + 256] = src[tid + 256];
            dst[tid + 512] = src[tid + 512];
            dst[tid + 768] = src[tid + 768];
        }
        __syncthreads();
#pragma unroll 4
        for (int kk = 0; kk < 32; kk++) {
            float4 a = *(const float4*)&AT[kk][rg * 4];
            float4 w = *(const float4*)&WUc[kk][cg * 4];
            acc0.x += a.x * w.x; acc0.y += a.x * w.y; acc0.z += a.x * w.z; acc0.w += a.x * w.w;
            acc1.x += a.y * w.x; acc1.y += a.y * w.y; acc1.z += a.y * w.z; acc1.w += a.y * w.w;
            acc2.x += a.z * w.x; acc2.y += a.z * w.y; acc2.z += a.z * w.z; acc2.w += a.z * w.w;
            acc3.x += a.w * w.x; acc3.y += a.w * w.y; acc3.z += a.w * w.z; acc3.w += a.w * w.w;
        }
        __syncthreads();
    }
    int r0 = rbase + rg * 4;
    if (r0 + 0 < N_) *(float4*)(AHt + (size_t)(r0 + 0) * F0_ + cg * 4) = acc0;
    if (r0 + 1 < N_) *(float4*)(AHt + (size_t)(r0 + 1) * F0_ + cg * 4) = acc1;
    if (r0 + 2 < N_) *(float4*)(AHt + (size_t)(r0 + 2) * F0_ + cg * 4) = acc2;
    if (r0 + 3 < N_) *(float4*)(AHt + (size_t)(r0 + 3) * F0_ + cg * 4) = acc3;
}

// ---------- out[e] = P[flat_src] + Q[flat_trg]  (bf16 PQh, NT store) ----------
__global__ void k_final(const unsigned* __restrict__ PQh, const int* __restrict__ et,
                        const int* __restrict__ es, const int* __restrict__ eg,
                        float* __restrict__ out) {
    int gid = blockIdx.x * 256 + threadIdx.x;  // e*16 + q
    if (gid >= E_ * 16) return;
    int e = gid >> 4, q = gid & 15;
    int t = et[e];
    const uint2 a = *(const uint2*)(PQh + ((size_t)(t * N_ + es[e])) * 64 + q * 2);
    const uint2 b = *(const uint2*)(PQh + ((size_t)(t * N_ + eg[e])) * 64 + 32 + q * 2);
    nf4 o;
    o.x = bflo(a.x) + bflo(b.x);
    o.y = bfhi(a.x) + bfhi(b.x);
    o.z = bflo(a.y) + bflo(b.y);
    o.w = bfhi(a.y) + bfhi(b.y);
    __builtin_nontemporal_store(o, (nf4*)(out + (size_t)e * 64 + q * 4));
}

__global__ void k_final_f32(const float* __restrict__ PQ, const int* __restrict__ et,
                            const int* __restrict__ es, const int* __restrict__ eg,
                            float* __restrict__ out) {
    int gid = blockIdx.x * 256 + threadIdx.x;  // e*16 + q
    if (gid >= E_ * 16) return;
    int e = gid >> 4, q = gid & 15;
    int t = et[e];
    const float4 a = *(const float4*)(PQ + ((size_t)(t * N_ + es[e])) * 128 + q * 4);
    const float4 b = *(const float4*)(PQ + ((size_t)(t * N_ + eg[e])) * 128 + 64 + q * 4);
    nf4 o = {a.x + b.x, a.y + b.y, a.z + b.z, a.w + b.w};
    __builtin_nontemporal_store(o, (nf4*)(out + (size_t)e * 64 + q * 4));
}

// W_fin[k][m] = WT[7][m][k]
__global__ void k_wfin(const float* __restrict__ WT, float* __restrict__ out) {
    int gid = blockIdx.x * 256 + threadIdx.x;  // k*128 + m
    int k = gid >> 7, m = gid & 127;
    out[(size_t)E_ * 64 + gid] = WT[(size_t)7 * 16384 + m * 128 + k];
}

// ---------- launch ----------
extern "C" void kernel_launch(void* const* d_in, const int* in_sizes, int n_in,
                              void* d_out, int out_size, void* d_ws, size_t ws_size,
                              hipStream_t stream) {
    const float* X = (const float*)d_in[0];
    const int* A_rows = (const int*)d_in[1];
    const int* A_cols = (const int*)d_in[2];
    const float* A_val = (const float*)d_in[3];
    const int* edge_time = (const int*)d_in[4];
    const int* edge_src = (const int*)d_in[5];
    const int* edge_trg = (const int*)d_in[6];
    const float* p = (const float*)d_in[7];
    const float* W_Z = (const float*)d_in[8];
    const float* U_Z = (const float*)d_in[9];
    const float* B_Z = (const float*)d_in[10];
    const float* W_R = (const float*)d_in[11];
    const float* U_R = (const float*)d_in[12];
    const float* B_R = (const float*)d_in[13];
    const float* W_H = (const float*)d_in[14];
    const float* U_H = (const float*)d_in[15];
    const float* B_H = (const float*)d_in[16];
    const float* W_init = (const float*)d_in[17];
    const float* U = (const float*)d_in[18];
    float* out = (float*)d_out;

    char* ws = (char*)d_ws;
    size_t off = 0;
    auto take = [&](size_t bytes) {
        char* ptr = ws + off;
        off = (off + bytes + 255) & ~(size_t)255;
        return (void*)ptr;
    };
    float* AHreg = (float*)take((size_t)T_ * N_ * F0_ * 4);  // 204.8 MB: ebuck / XWU+PQh / AH(fallback)
    int2* ecv = (int2*)take((size_t)T_ * NNZ_ * 8);          // 51.2 MB final CSR
    float* yv = (float*)take((size_t)T_ * N_ * 4);
    int* row_ptr = (int*)take((size_t)T_ * (N_ + 1) * 4);
    int* bcnt = (int*)take((size_t)T_ * NB * 4);
    int* bbase = (int*)take((size_t)T_ * NB * 4);
    int* bfill = (int*)take((size_t)T_ * NB * 4);
    float* p_hat = (float*)take(512);
    float* topv = (float*)take((size_t)T_ * K_ * 4);
    int* topidx = (int*)take((size_t)T_ * K_ * 4);
    float* Z = (float*)take((size_t)T_ * F0_ * K_ * 4);
    float* AZb = (float*)take((size_t)T_ * 16384 * 4);
    float* ARb = (float*)take((size_t)T_ * 16384 * 4);
    float* AHb = (float*)take((size_t)T_ * 16384 * 4);
    float* WT = (float*)take((size_t)T_ * 16384 * 4);  // W_seq transposed [t][j][k]
    float* WU = (float*)take((size_t)T_ * 16384 * 4);
    unsigned* Xh = (unsigned*)take((size_t)T_ * N_ * 64 * 4);  // 102.4 MB bf16 X
    bool use_bf16 = (off <= ws_size);
    int2* ebuck = (int2*)AHreg;                 // dead after k_bsort
    unsigned* XWU = (unsigned*)AHreg;           // first 102.4 MB
    unsigned* PQh = XWU + (size_t)T_ * N_ * 64; // second 102.4 MB

    hipMemsetAsync(bcnt, 0, (size_t)T_ * NB * 4, stream);
    hipMemsetAsync(bfill, 0, (size_t)T_ * NB * 4, stream);

    k_phat<<<1, 128, 0, stream>>>(p, p_hat);
    k_y<<<(T_ * N_ * 64) / 256, 256, 0, stream>>>(X, p_hat, yv, use_bf16 ? Xh : nullptr);
    k_topk<<<T_, 1024, 0, stream>>>(yv, topv, topidx);
    k_z<<<(T_ * F0_ * K_) / 256, 256, 0, stream>>>(X, topv, topidx, Z);
    k_az<<<(3 * T_ * 16384) / 256, 256, 0, stream>>>(W_Z, W_R, W_H, B_Z, B_R, B_H, Z,
                                                     AZb, ARb, AHb);
    {
        dim3 gA((NNZ_ + BCH - 1) / BCH, T_);  // 98 x 8
        k_cnt<<<gA, 512, 0, stream>>>(A_rows, bcnt);
        k_bscan<<<T_, 512, 0, stream>>>(bcnt, bbase);
        k_binA<<<gA, 512, 0, stream>>>(A_rows, A_cols, A_val, bbase, bfill, ebuck);
        dim3 gB(NB, T_);                      // 391 x 8
        k_bsort<<<gB, 256, 0, stream>>>(bbase, bcnt, ebuck, ecv, row_ptr);
    }
    k_gru8<<<64, 256, 0, stream>>>(AZb, ARb, AHb, U_Z, U_R, U_H, W_init, WT);
    k_wu<<<T_ * 128, 128, 0, stream>>>(WT, U, WU);
    if (use_bf16) {
        dim3 g((N_ + 31) / 32, T_);
        k_xwu<<<g, 256, 0, stream>>>(Xh, WU, XWU);
        k_spmm2<<<(T_ * N_ * 64) / 256, 256, 0, stream>>>(XWU, row_ptr, ecv, PQh);
        k_final<<<(E_ * 16) / 256, 256, 0, stream>>>(PQh, edge_time, edge_src,
                                                     edge_trg, out);
    } else {
        float* AH = AHreg;
        k_spmm_f32<<<(T_ * N_ * 64) / 256, 256, 0, stream>>>(X, row_ptr, ecv, AH);
        dim3 g((N_ + 31) / 32, T_);
        k_pq_f32<<<g, 256, 0, stream>>>(AH, WU);
        k_final_f32<<<(E_ * 16) / 256, 256, 0, stream>>>(AH, edge_time, edge_src,
                                                         edge_trg, out);
    }
    k_wfin<<<(F0_ * H0_) / 256, 256, 0, stream>>>(WT, out);
}